// Round 7
// baseline (5054487.891 us; speedup 1.0000x reference)
//
#include <hip/hip_runtime.h>
#include <math.h>

// B=16, T=512, F=512, H=8, D=64; rows = B*T = 8192
#define GRID_WGS 128   // launched WGs for GRU; 8 elected (same XCD) participate

typedef __attribute__((ext_vector_type(8))) short bf16x8;
typedef __attribute__((ext_vector_type(4))) float f32x4;
typedef __attribute__((ext_vector_type(4))) unsigned short us4;
typedef __attribute__((ext_vector_type(4))) unsigned int u32x4;

static __device__ __forceinline__ float sigmoidf_(float x) {
    return 1.0f / (1.0f + __expf(-x));
}
static __device__ __forceinline__ unsigned short f2bf(float f) {
    unsigned int u = __float_as_uint(f);
    u += 0x7fffu + ((u >> 16) & 1u);
    return (unsigned short)(u >> 16);
}
static __device__ __forceinline__ float bf2f(unsigned short b) {
    return __uint_as_float(((unsigned int)b) << 16);
}
static __device__ __forceinline__ void gload_lds16(const void* g, void* l) {
    __builtin_amdgcn_global_load_lds(
        (const __attribute__((address_space(1))) unsigned int*)g,
        (__attribute__((address_space(3))) unsigned int*)l, 16, 0, 0);
}

// ---------------- fp32 -> bf16 convert --------------------------------------------------------
__global__ __launch_bounds__(256)
void f2bf_kernel(const float* __restrict__ in, unsigned short* __restrict__ out)
{
    const int i = (blockIdx.x * 256 + threadIdx.x) * 4;
    const float4 v = *(const float4*)(in + i);
    const us4 o = {f2bf(v.x), f2bf(v.y), f2bf(v.z), f2bf(v.w)};
    *(us4*)(out + i) = o;
}

// ---------------- transpose+convert: in [K][N] f32 -> out [N][K] bf16 -------------------------
__global__ __launch_bounds__(256)
void transpose_bf16(const float* __restrict__ in, unsigned short* __restrict__ out,
                    int K, int N)
{
    __shared__ float tile[32][33];
    const int n0 = blockIdx.x * 32, k0 = blockIdx.y * 32;
    const int c = threadIdx.x & 31, r8 = threadIdx.x >> 5;
#pragma unroll
    for (int i = 0; i < 4; ++i) {
        const int k = r8 + i * 8;
        tile[k][c] = in[(size_t)(k0 + k) * N + n0 + c];
    }
    __syncthreads();
#pragma unroll
    for (int i = 0; i < 4; ++i) {
        const int n = r8 + i * 8;
        out[(size_t)(n0 + n) * K + k0 + c] = f2bf(tile[c][n]);
    }
}

// ---------------- bf16 MFMA GEMM: C=A@Bt (+bias)(+resid); f32 C and/or bf16 Cb outputs --------
__global__ __launch_bounds__(256)
void gemm_bf16(const unsigned short* __restrict__ A, const unsigned short* __restrict__ Bt,
               const float* __restrict__ bias, const float* __restrict__ resid,
               float* __restrict__ C, unsigned short* __restrict__ Cb,
               int M, int N, int K)
{
    __shared__ unsigned short As[128 * 64];
    __shared__ unsigned short Bs[128 * 64];
    const int tid = threadIdx.x;
    const int wave = tid >> 6, lane = tid & 63;
    const int bm = blockIdx.x * 128, bn = blockIdx.y * 128;
    const int wr = wave >> 1, wc = wave & 1;
    const int stR = lane >> 3;
    const int stC = (lane & 7) * 8;

    const unsigned short* Abase = A + (size_t)(bm + wave * 32 + stR) * K + stC;
    const unsigned short* Bbase = Bt + (size_t)(bn + wave * 32 + stR) * K + stC;
    unsigned short* AsW = As + wave * 2048;
    unsigned short* BsW = Bs + wave * 2048;

    f32x4 acc[4][4] = {};
    const int fr = lane & 15;
    const int fko = (lane >> 4) * 8;

    for (int k0 = 0; k0 < K; k0 += 64) {
#pragma unroll
        for (int i = 0; i < 4; ++i) {
            gload_lds16(Abase + (size_t)i * 8 * K + k0, AsW + i * 512);
            gload_lds16(Bbase + (size_t)i * 8 * K + k0, BsW + i * 512);
        }
        __syncthreads();
        bf16x8 af[4][2], bfr[4][2];
#pragma unroll
        for (int m = 0; m < 4; ++m) {
            const unsigned short* ap = As + (wr * 64 + m * 16 + fr) * 64 + fko;
            af[m][0] = *(const bf16x8*)(ap);
            af[m][1] = *(const bf16x8*)(ap + 32);
        }
#pragma unroll
        for (int n = 0; n < 4; ++n) {
            const unsigned short* bp = Bs + (wc * 64 + n * 16 + fr) * 64 + fko;
            bfr[n][0] = *(const bf16x8*)(bp);
            bfr[n][1] = *(const bf16x8*)(bp + 32);
        }
#pragma unroll
        for (int m = 0; m < 4; ++m)
#pragma unroll
            for (int n = 0; n < 4; ++n) {
                acc[m][n] = __builtin_amdgcn_mfma_f32_16x16x32_bf16(af[m][0], bfr[n][0], acc[m][n], 0, 0, 0);
                acc[m][n] = __builtin_amdgcn_mfma_f32_16x16x32_bf16(af[m][1], bfr[n][1], acc[m][n], 0, 0, 0);
            }
        __syncthreads();
    }
    const int fq = lane >> 4;
#pragma unroll
    for (int n = 0; n < 4; ++n) {
        const int col = bn + wc * 64 + n * 16 + fr;
        const float bv = bias ? bias[col] : 0.f;
#pragma unroll
        for (int m = 0; m < 4; ++m) {
#pragma unroll
            for (int j = 0; j < 4; ++j) {
                const int row = bm + wr * 64 + m * 16 + fq * 4 + j;
                float v = acc[m][n][j] + bv;
                if (resid) v += resid[(size_t)row * N + col];
                if (C)  C[(size_t)row * N + col] = v;
                if (Cb) Cb[(size_t)row * N + col] = f2bf(v);
            }
        }
    }
}

// ---------------- fused attention per (b, h, 64-row q tile); writes ctx as bf16 ---------------
__global__ __launch_bounds__(256)
void attn_f32(const float* __restrict__ q, const float* __restrict__ k,
              const float* __restrict__ v, unsigned short* __restrict__ ctxb)
{
    __shared__ float S[64][512];
    __shared__ float KV[64][68];
    const int tid = threadIdx.x;
    const int wg = blockIdx.x;
    const int qt = wg & 7, h = (wg >> 3) & 7, b = wg >> 6;
    const int r = tid >> 2, quad = tid & 3;
    const int t0 = qt * 64;

    float4 qreg[16];
    {
        const float* qrow = q + ((size_t)(b * 512 + t0 + r) * 512) + h * 64;
#pragma unroll
        for (int i = 0; i < 16; ++i) {
            float4 t = *(const float4*)(qrow + i * 4);
            t.x *= 0.125f; t.y *= 0.125f; t.z *= 0.125f; t.w *= 0.125f;
            qreg[i] = t;
        }
    }
    for (int st = 0; st < 8; ++st) {
        {
            const int s = tid >> 2, d0 = quad * 16;
            const float* krow = k + ((size_t)(b * 512 + st * 64 + s) * 512) + h * 64 + d0;
#pragma unroll
            for (int j = 0; j < 4; ++j)
                *(float4*)&KV[s][d0 + j * 4] = *(const float4*)(krow + j * 4);
        }
        __syncthreads();
        const int sbase = quad * 16;
#pragma unroll 4
        for (int sp = 0; sp < 16; ++sp) {
            const int s = sbase + sp;
            float accd = 0.f;
#pragma unroll
            for (int kk = 0; kk < 16; ++kk) {
                const float4 kv = *(const float4*)&KV[s][kk * 4];
                accd += qreg[kk].x * kv.x + qreg[kk].y * kv.y +
                        qreg[kk].z * kv.z + qreg[kk].w * kv.w;
            }
            S[r][st * 64 + s] = accd;
        }
        __syncthreads();
    }
    const int c0 = quad * 128;
    float mx = -1e30f;
    for (int c4 = 0; c4 < 32; ++c4) {
        const float4 sv = *(const float4*)&S[r][c0 + c4 * 4];
        mx = fmaxf(mx, fmaxf(fmaxf(sv.x, sv.y), fmaxf(sv.z, sv.w)));
    }
    mx = fmaxf(mx, __shfl_xor(mx, 1));
    mx = fmaxf(mx, __shfl_xor(mx, 2));
    float sum = 0.f;
    for (int c4 = 0; c4 < 32; ++c4) {
        float4 sv = *(const float4*)&S[r][c0 + c4 * 4];
        sv.x = __expf(sv.x - mx); sv.y = __expf(sv.y - mx);
        sv.z = __expf(sv.z - mx); sv.w = __expf(sv.w - mx);
        sum += sv.x + sv.y + sv.z + sv.w;
        *(float4*)&S[r][c0 + c4 * 4] = sv;
    }
    sum += __shfl_xor(sum, 1);
    sum += __shfl_xor(sum, 2);
    const float inv = 1.0f / sum;
    __syncthreads();
    float o[16] = {};
    const int d0 = quad * 16;
    for (int st = 0; st < 8; ++st) {
        {
            const int s = tid >> 2;
            const float* vrow = v + ((size_t)(b * 512 + st * 64 + s) * 512) + h * 64 + d0;
#pragma unroll
            for (int j = 0; j < 4; ++j)
                *(float4*)&KV[s][d0 + j * 4] = *(const float4*)(vrow + j * 4);
        }
        __syncthreads();
        for (int s4 = 0; s4 < 16; ++s4) {
            const float4 p = *(const float4*)&S[r][st * 64 + s4 * 4];
            const float pv[4] = {p.x, p.y, p.z, p.w};
#pragma unroll
            for (int jj = 0; jj < 4; ++jj) {
                const int s = s4 * 4 + jj;
#pragma unroll
                for (int i = 0; i < 4; ++i) {
                    const float4 vv = *(const float4*)&KV[s][d0 + i * 4];
                    o[i * 4 + 0] = fmaf(pv[jj], vv.x, o[i * 4 + 0]);
                    o[i * 4 + 1] = fmaf(pv[jj], vv.y, o[i * 4 + 1]);
                    o[i * 4 + 2] = fmaf(pv[jj], vv.z, o[i * 4 + 2]);
                    o[i * 4 + 3] = fmaf(pv[jj], vv.w, o[i * 4 + 3]);
                }
            }
        }
        __syncthreads();
    }
    unsigned short* crow = ctxb + ((size_t)(b * 512 + t0 + r) * 512) + h * 64 + d0;
#pragma unroll
    for (int i = 0; i < 4; ++i) {
        const us4 t = {f2bf(o[i * 4 + 0] * inv), f2bf(o[i * 4 + 1] * inv),
                       f2bf(o[i * 4 + 2] * inv), f2bf(o[i * 4 + 3] * inv)};
        *(us4*)(crow + i * 4) = t;
    }
}

// ---------------- layernorm (rows of 512), optional bf16 side output --------------------------
__global__ __launch_bounds__(256)
void ln_f32(const float* __restrict__ in, float* __restrict__ out,
            const float* __restrict__ g, const float* __restrict__ bb,
            unsigned short* __restrict__ outb)
{
    const int lane = threadIdx.x & 63;
    const int row = blockIdx.x * 4 + (threadIdx.x >> 6);
    const float* x = in + (size_t)row * 512;
    const float4 a = *(const float4*)(x + lane * 4);
    const float4 c = *(const float4*)(x + 256 + lane * 4);
    float s = a.x + a.y + a.z + a.w + c.x + c.y + c.z + c.w;
#pragma unroll
    for (int off = 1; off < 64; off <<= 1) s += __shfl_xor(s, off);
    const float mu = s * (1.0f / 512.0f);
    float vs = 0.f;
    vs += (a.x - mu) * (a.x - mu) + (a.y - mu) * (a.y - mu);
    vs += (a.z - mu) * (a.z - mu) + (a.w - mu) * (a.w - mu);
    vs += (c.x - mu) * (c.x - mu) + (c.y - mu) * (c.y - mu);
    vs += (c.z - mu) * (c.z - mu) + (c.w - mu) * (c.w - mu);
#pragma unroll
    for (int off = 1; off < 64; off <<= 1) vs += __shfl_xor(vs, off);
    const float rstd = rsqrtf(vs * (1.0f / 512.0f) + 1e-3f);
    const float4 g1 = *(const float4*)(g + lane * 4);
    const float4 g2 = *(const float4*)(g + 256 + lane * 4);
    const float4 b1 = *(const float4*)(bb + lane * 4);
    const float4 b2 = *(const float4*)(bb + 256 + lane * 4);
    float* y = out + (size_t)row * 512;
    const float4 o1 = {(a.x - mu) * rstd * g1.x + b1.x, (a.y - mu) * rstd * g1.y + b1.y,
                       (a.z - mu) * rstd * g1.z + b1.z, (a.w - mu) * rstd * g1.w + b1.w};
    const float4 o2 = {(c.x - mu) * rstd * g2.x + b2.x, (c.y - mu) * rstd * g2.y + b2.y,
                       (c.z - mu) * rstd * g2.z + b2.z, (c.w - mu) * rstd * g2.w + b2.w};
    *(float4*)(y + lane * 4) = o1;
    *(float4*)(y + 256 + lane * 4) = o2;
    if (outb) {
        unsigned short* yb = outb + (size_t)row * 512;
        const us4 p1 = {f2bf(o1.x), f2bf(o1.y), f2bf(o1.z), f2bf(o1.w)};
        const us4 p2 = {f2bf(o2.x), f2bf(o2.y), f2bf(o2.z), f2bf(o2.w)};
        *(us4*)(yb + lane * 4) = p1;
        *(us4*)(yb + 256 + lane * 4) = p2;
    }
}

// ---------------- persistent GRU, XCD-pinned: 8 WGs / 32 waves on ONE XCD --------------------
// Election (proven r4-r6). Hot-loop sync (r7): NO counter, NO L3 atomics, NO intra-WG barrier.
// Each wave: drain own h-stores (vmcnt) -> plain byte store flags[wave]=(t+1)&0xff (L2).
// Every wave polls all 32 flag bytes with two 16B sc0 loads (L2, ~200cyc) and proceeds when
// all equal. Same-XCD L2 store->sc0-load visibility is the r5/r6-proven h-exchange mechanism.
// xp consumed as bf16 (half the stream). xp prefetch issued before the poll so its HBM latency
// overlaps the barrier wait.
__global__ __launch_bounds__(256, 1)
void gru_persist(const float* __restrict__ rk,      // gru_rk [512][1536] fp32
                 const unsigned short* __restrict__ xpb, // [8192][1536] bf16 (bias0 included)
                 const float* __restrict__ rb,      // recurrent bias [1536]
                 unsigned short* __restrict__ hbuf, // [2][16*512] bf16 (zeroed)
                 unsigned short* __restrict__ goutb,// [8192][512] bf16
                 unsigned char* __restrict__ flags, // [32] per-wave step flags (zeroed)
                 unsigned int* __restrict__ ctl)    // [16]: per-XCD rank + started (zeroed)
{
    __shared__ int sh_part, sh_memb;
    const int tid = threadIdx.x;

    if (tid == 0) {
        unsigned int xcc;
        asm("s_getreg_b32 %0, hwreg(HW_REG_XCC_ID)" : "=s"(xcc));
        xcc &= 7u;
        const unsigned int rank =
            __hip_atomic_fetch_add(&ctl[xcc], 1u, __ATOMIC_RELAXED, __HIP_MEMORY_SCOPE_AGENT);
        __hip_atomic_fetch_add(&ctl[8], 1u, __ATOMIC_ACQ_REL, __HIP_MEMORY_SCOPE_AGENT);
        unsigned int spins = 0;
        while (__hip_atomic_load(&ctl[8], __ATOMIC_ACQUIRE, __HIP_MEMORY_SCOPE_AGENT)
               < (unsigned)GRID_WGS) {
            __builtin_amdgcn_s_sleep(1);
            if (++spins > (1u << 20)) break;
        }
        unsigned int cnt[8];
#pragma unroll
        for (int i = 0; i < 8; ++i)
            cnt[i] = __hip_atomic_load(&ctl[i], __ATOMIC_ACQUIRE, __HIP_MEMORY_SCOPE_AGENT);
        int best = 0;
#pragma unroll
        for (int i = 1; i < 8; ++i)
            if (cnt[i] > cnt[best]) best = i;
        sh_part = (xcc == (unsigned)best && rank < 8u) ? 1 : 0;
        sh_memb = (int)rank;
    }
    __syncthreads();
    if (!sh_part) return;
    const int member = sh_memb;          // 0..7

    const int wv = tid >> 6, l = tid & 63;
    const int wgi = member * 4 + wv;     // global wave index 0..31
    const int lo16 = l & 15;
    const int hi4 = l >> 4;              // 0..3
    const int gc = wgi * 16 + lo16;      // this lane's output h-col

    // ---- preload B fragments: B[g][kt], lane slot j <-> k = kt*32 + hi4*8 + j
    bf16x8 B[3][16];
#pragma unroll
    for (int g = 0; g < 3; ++g)
#pragma unroll
        for (int kt = 0; kt < 16; ++kt) {
            bf16x8 bv;
#pragma unroll
            for (int j = 0; j < 8; ++j) {
                const int k = kt * 32 + hi4 * 8 + j;
                bv[j] = (short)f2bf(rk[(size_t)k * 1536 + g * 512 + gc]);
            }
            B[g][kt] = bv;
        }
    const float rbz = rb[gc], rbr = rb[512 + gc], rbh = rb[1024 + gc];
    float hst[4] = {0.f, 0.f, 0.f, 0.f};

    // prefetch xp (bf16) for t=0
    float xzv[4], xrv[4], xhv[4];
#pragma unroll
    for (int j = 0; j < 4; ++j) {
        const unsigned short* xrow = xpb + ((size_t)((hi4 * 4 + j) * 512)) * 1536 + gc;
        xzv[j] = bf2f(xrow[0]); xrv[j] = bf2f(xrow[512]); xhv[j] = bf2f(xrow[1024]);
    }

    for (int t = 0; t < 512; ++t) {
        const unsigned short* hr = hbuf + (size_t)(t & 1) * (16 * 512);
        unsigned short* hw = hbuf + (size_t)((t + 1) & 1) * (16 * 512);
        // A frags via sc0 loads (L1 bypass -> shared XCD L2 holds peers' stores)
        bf16x8 A[16];
#pragma unroll
        for (int kt = 0; kt < 16; ++kt) {
            const unsigned short* ap = hr + lo16 * 512 + kt * 32 + hi4 * 8;
            asm volatile("global_load_dwordx4 %0, %1, off sc0"
                         : "=v"(A[kt]) : "v"(ap) : "memory");
        }
        asm volatile("s_waitcnt vmcnt(0)" ::: "memory");
        __builtin_amdgcn_sched_barrier(0);

        f32x4 accz = {0.f, 0.f, 0.f, 0.f};
        f32x4 accr = {0.f, 0.f, 0.f, 0.f};
        f32x4 acch = {0.f, 0.f, 0.f, 0.f};
#pragma unroll
        for (int kt = 0; kt < 16; ++kt) {
            accz = __builtin_amdgcn_mfma_f32_16x16x32_bf16(A[kt], B[0][kt], accz, 0, 0, 0);
            accr = __builtin_amdgcn_mfma_f32_16x16x32_bf16(A[kt], B[1][kt], accr, 0, 0, 0);
            acch = __builtin_amdgcn_mfma_f32_16x16x32_bf16(A[kt], B[2][kt], acch, 0, 0, 0);
        }
        // gates + state update; D layout: row b = hi4*4 + j, col = lo16
        float hn[4];
#pragma unroll
        for (int j = 0; j < 4; ++j) {
            const int b = hi4 * 4 + j;
            const float z = sigmoidf_(xzv[j] + accz[j] + rbz);
            const float r = sigmoidf_(xrv[j] + accr[j] + rbr);
            const float hh = fmaxf(xhv[j] + r * (acch[j] + rbh), 0.f);
            const float hnew = z * hst[j] + (1.f - z) * hh;
            hst[j] = hnew; hn[j] = hnew;
            hw[b * 512 + gc] = f2bf(hnew);   // plain store: write-through -> shared XCD L2
        }
        const unsigned int tb = (unsigned int)((t + 1) & 0xff);
        // drain own h stores, then publish this wave's flag (plain byte store to L2)
        asm volatile("s_waitcnt vmcnt(0)" ::: "memory");
        if (l == 0) flags[wgi] = (unsigned char)tb;
        // deferred off critical path: gout stores, then xp prefetch (overlaps the poll)
#pragma unroll
        for (int j = 0; j < 4; ++j)
            goutb[((size_t)((hi4 * 4 + j) * 512 + t)) * 512 + gc] = f2bf(hn[j]);
        if (t < 511) {
#pragma unroll
            for (int j = 0; j < 4; ++j) {
                const unsigned short* xrow =
                    xpb + ((size_t)((hi4 * 4 + j) * 512 + t + 1)) * 1536 + gc;
                xzv[j] = bf2f(xrow[0]); xrv[j] = bf2f(xrow[512]); xhv[j] = bf2f(xrow[1024]);
            }
            // poll all 32 flag bytes via two 16B sc0 loads from L2
            const unsigned int pat = tb * 0x01010101u;
            u32x4 f0, f1;
            unsigned int it = 0;
            while (true) {
                asm volatile("global_load_dwordx4 %0, %2, off sc0\n\t"
                             "global_load_dwordx4 %1, %2, off offset:16 sc0\n\t"
                             "s_waitcnt vmcnt(0)"
                             : "=&v"(f0), "=&v"(f1) : "v"(flags) : "memory");
                if (f0[0] == pat && f0[1] == pat && f0[2] == pat && f0[3] == pat &&
                    f1[0] == pat && f1[1] == pat && f1[2] == pat && f1[3] == pat) break;
                if (++it > (1u << 16)) break;
            }
            __builtin_amdgcn_sched_barrier(0);
        }
    }
}

extern "C" void kernel_launch(void* const* d_in, const int* in_sizes, int n_in,
                              void* d_out, int out_size, void* d_ws, size_t ws_size,
                              hipStream_t stream)
{
    const float* x     = (const float*)d_in[0];
    const float* Wq    = (const float*)d_in[1];
    const float* bq    = (const float*)d_in[2];
    const float* Wk    = (const float*)d_in[3];
    const float* bk    = (const float*)d_in[4];
    const float* Wv    = (const float*)d_in[5];
    const float* bv    = (const float*)d_in[6];
    const float* Wo    = (const float*)d_in[7];
    const float* bo    = (const float*)d_in[8];
    const float* ln1g  = (const float*)d_in[9];
    const float* ln1b  = (const float*)d_in[10];
    const float* gruk  = (const float*)d_in[11];
    const float* grurk = (const float*)d_in[12];
    const float* grub  = (const float*)d_in[13];
    const float* Wd    = (const float*)d_in[14];
    const float* bd    = (const float*)d_in[15];
    const float* ln2g  = (const float*)d_in[16];
    const float* ln2b  = (const float*)d_in[17];
    float* out = (float*)d_out;

    char* base = (char*)d_ws;
    const size_t MB = 1024 * 1024;
    float*          Q0   = (float*)base;                      // 48 MB: q/k/v -> xpb -> dense-out
    float*          R4   = (float*)(base + 48 * MB);          // 16 MB: x1
    unsigned short* S1   = (unsigned short*)(base + 64 * MB); // 8 MB: xb -> ctxb -> x1b -> goutb
    unsigned short* WT   = (unsigned short*)(base + 72 * MB); // 4 MB weights
    unsigned short* wqT  = WT;
    unsigned short* wkT  = WT + 256 * 1024;
    unsigned short* wvT  = WT + 512 * 1024;
    unsigned short* woT  = WT + 768 * 1024;
    unsigned short* gkT  = WT + 1024 * 1024;    // 1536x512
    unsigned short* wdT  = WT + 1792 * 1024;
    unsigned short* hbuf = (unsigned short*)(base + 76 * MB); // 2*16*512 bf16 = 32 KB
    unsigned int*   barz = (unsigned int*)(base + 76 * MB + 64 * 1024);   // memset region base
    unsigned int*   ctl  = (unsigned int*)(base + 76 * MB + 64 * 1024 + 128);
    unsigned char*  flg  = (unsigned char*)(base + 76 * MB + 64 * 1024 + 256);

    float* q = Q0;
    float* k = Q0 + (size_t)4 * MB;
    float* v = Q0 + (size_t)8 * MB;
    unsigned short* xpb = (unsigned short*)Q0;   // 8192x1536 bf16 = 24 MB (after q/k/v dead)
    float* dout  = (float*)(base + 24 * MB);     // 8192x512 f32 (after q/k/v dead, above xpb)

    const dim3 blk(256);
    const dim3 g512(8192 / 128, 512 / 128);
    const dim3 g1536(8192 / 128, 1536 / 128);

    f2bf_kernel<<<dim3(4096), blk, 0, stream>>>(x, S1);
    transpose_bf16<<<dim3(16, 16), blk, 0, stream>>>(Wq, wqT, 512, 512);
    transpose_bf16<<<dim3(16, 16), blk, 0, stream>>>(Wk, wkT, 512, 512);
    transpose_bf16<<<dim3(16, 16), blk, 0, stream>>>(Wv, wvT, 512, 512);
    transpose_bf16<<<dim3(16, 16), blk, 0, stream>>>(Wo, woT, 512, 512);
    transpose_bf16<<<dim3(48, 16), blk, 0, stream>>>(gruk, gkT, 512, 1536);
    transpose_bf16<<<dim3(16, 16), blk, 0, stream>>>(Wd, wdT, 512, 512);
    gemm_bf16<<<g512, blk, 0, stream>>>(S1, wqT, bq, nullptr, q, nullptr, 8192, 512, 512);
    gemm_bf16<<<g512, blk, 0, stream>>>(S1, wkT, bk, nullptr, k, nullptr, 8192, 512, 512);
    gemm_bf16<<<g512, blk, 0, stream>>>(S1, wvT, bv, nullptr, v, nullptr, 8192, 512, 512);
    attn_f32<<<dim3(1024), blk, 0, stream>>>(q, k, v, S1);
    gemm_bf16<<<g512, blk, 0, stream>>>(S1, woT, bo, x, R4, nullptr, 8192, 512, 512);
    ln_f32<<<dim3(2048), blk, 0, stream>>>(R4, R4, ln1g, ln1b, S1);
    // xp = x1 @ gru_k + gru_b[0], bf16-only output
    gemm_bf16<<<g1536, blk, 0, stream>>>(S1, gkT, grub, nullptr, nullptr, xpb, 8192, 1536, 512);
    // persistent GRU (XCD-pinned, L2-flag barrier)
    hipMemsetAsync(hbuf, 0, 2 * 16 * 512 * sizeof(unsigned short), stream);
    hipMemsetAsync(barz, 0, 512, stream);   // covers ctl + flags
    gru_persist<<<dim3(GRID_WGS), blk, 0, stream>>>(grurk, xpb, grub + 1536, hbuf, S1, flg, ctl);
    gemm_bf16<<<g512, blk, 0, stream>>>(S1, wdT, bd, R4, dout, nullptr, 8192, 512, 512);
    ln_f32<<<dim3(2048), blk, 0, stream>>>(dout, out, ln2g, ln2b, nullptr);
}

// Round 8
// 146304.822 us; speedup vs baseline: 34.5477x; 34.5477x over previous
//
#include <hip/hip_runtime.h>
#include <math.h>

// B=16, T=512, F=512, H=8, D=64; rows = B*T = 8192
#define GRID_WGS 128   // launched WGs for GRU; 8 elected (same XCD) participate

typedef __attribute__((ext_vector_type(8))) short bf16x8;
typedef __attribute__((ext_vector_type(4))) float f32x4;
typedef __attribute__((ext_vector_type(4))) unsigned short us4;
typedef __attribute__((ext_vector_type(4))) unsigned int u32x4;

static __device__ __forceinline__ float sigmoidf_(float x) {
    return 1.0f / (1.0f + __expf(-x));
}
static __device__ __forceinline__ unsigned short f2bf(float f) {
    unsigned int u = __float_as_uint(f);
    u += 0x7fffu + ((u >> 16) & 1u);
    return (unsigned short)(u >> 16);
}
static __device__ __forceinline__ float bf2f(unsigned short b) {
    return __uint_as_float(((unsigned int)b) << 16);
}
static __device__ __forceinline__ void gload_lds16(const void* g, void* l) {
    __builtin_amdgcn_global_load_lds(
        (const __attribute__((address_space(1))) unsigned int*)g,
        (__attribute__((address_space(3))) unsigned int*)l, 16, 0, 0);
}

// ---------------- fp32 -> bf16 convert --------------------------------------------------------
__global__ __launch_bounds__(256)
void f2bf_kernel(const float* __restrict__ in, unsigned short* __restrict__ out)
{
    const int i = (blockIdx.x * 256 + threadIdx.x) * 4;
    const float4 v = *(const float4*)(in + i);
    const us4 o = {f2bf(v.x), f2bf(v.y), f2bf(v.z), f2bf(v.w)};
    *(us4*)(out + i) = o;
}

// ---------------- transpose+convert: in [K][N] f32 -> out [N][K] bf16 -------------------------
__global__ __launch_bounds__(256)
void transpose_bf16(const float* __restrict__ in, unsigned short* __restrict__ out,
                    int K, int N)
{
    __shared__ float tile[32][33];
    const int n0 = blockIdx.x * 32, k0 = blockIdx.y * 32;
    const int c = threadIdx.x & 31, r8 = threadIdx.x >> 5;
#pragma unroll
    for (int i = 0; i < 4; ++i) {
        const int k = r8 + i * 8;
        tile[k][c] = in[(size_t)(k0 + k) * N + n0 + c];
    }
    __syncthreads();
#pragma unroll
    for (int i = 0; i < 4; ++i) {
        const int n = r8 + i * 8;
        out[(size_t)(n0 + n) * K + k0 + c] = f2bf(tile[c][n]);
    }
}

// ---------------- bf16 MFMA GEMM: C=A@Bt (+bias)(+resid); f32 C and/or bf16 Cb outputs --------
__global__ __launch_bounds__(256)
void gemm_bf16(const unsigned short* __restrict__ A, const unsigned short* __restrict__ Bt,
               const float* __restrict__ bias, const float* __restrict__ resid,
               float* __restrict__ C, unsigned short* __restrict__ Cb,
               int M, int N, int K)
{
    __shared__ unsigned short As[128 * 64];
    __shared__ unsigned short Bs[128 * 64];
    const int tid = threadIdx.x;
    const int wave = tid >> 6, lane = tid & 63;
    const int bm = blockIdx.x * 128, bn = blockIdx.y * 128;
    const int wr = wave >> 1, wc = wave & 1;
    const int stR = lane >> 3;
    const int stC = (lane & 7) * 8;

    const unsigned short* Abase = A + (size_t)(bm + wave * 32 + stR) * K + stC;
    const unsigned short* Bbase = Bt + (size_t)(bn + wave * 32 + stR) * K + stC;
    unsigned short* AsW = As + wave * 2048;
    unsigned short* BsW = Bs + wave * 2048;

    f32x4 acc[4][4] = {};
    const int fr = lane & 15;
    const int fko = (lane >> 4) * 8;

    for (int k0 = 0; k0 < K; k0 += 64) {
#pragma unroll
        for (int i = 0; i < 4; ++i) {
            gload_lds16(Abase + (size_t)i * 8 * K + k0, AsW + i * 512);
            gload_lds16(Bbase + (size_t)i * 8 * K + k0, BsW + i * 512);
        }
        __syncthreads();
        bf16x8 af[4][2], bfr[4][2];
#pragma unroll
        for (int m = 0; m < 4; ++m) {
            const unsigned short* ap = As + (wr * 64 + m * 16 + fr) * 64 + fko;
            af[m][0] = *(const bf16x8*)(ap);
            af[m][1] = *(const bf16x8*)(ap + 32);
        }
#pragma unroll
        for (int n = 0; n < 4; ++n) {
            const unsigned short* bp = Bs + (wc * 64 + n * 16 + fr) * 64 + fko;
            bfr[n][0] = *(const bf16x8*)(bp);
            bfr[n][1] = *(const bf16x8*)(bp + 32);
        }
#pragma unroll
        for (int m = 0; m < 4; ++m)
#pragma unroll
            for (int n = 0; n < 4; ++n) {
                acc[m][n] = __builtin_amdgcn_mfma_f32_16x16x32_bf16(af[m][0], bfr[n][0], acc[m][n], 0, 0, 0);
                acc[m][n] = __builtin_amdgcn_mfma_f32_16x16x32_bf16(af[m][1], bfr[n][1], acc[m][n], 0, 0, 0);
            }
        __syncthreads();
    }
    const int fq = lane >> 4;
#pragma unroll
    for (int n = 0; n < 4; ++n) {
        const int col = bn + wc * 64 + n * 16 + fr;
        const float bv = bias ? bias[col] : 0.f;
#pragma unroll
        for (int m = 0; m < 4; ++m) {
#pragma unroll
            for (int j = 0; j < 4; ++j) {
                const int row = bm + wr * 64 + m * 16 + fq * 4 + j;
                float v = acc[m][n][j] + bv;
                if (resid) v += resid[(size_t)row * N + col];
                if (C)  C[(size_t)row * N + col] = v;
                if (Cb) Cb[(size_t)row * N + col] = f2bf(v);
            }
        }
    }
}

// ---------------- fused attention per (b, h, 64-row q tile); writes ctx as bf16 ---------------
__global__ __launch_bounds__(256)
void attn_f32(const float* __restrict__ q, const float* __restrict__ k,
              const float* __restrict__ v, unsigned short* __restrict__ ctxb)
{
    __shared__ float S[64][512];
    __shared__ float KV[64][68];
    const int tid = threadIdx.x;
    const int wg = blockIdx.x;
    const int qt = wg & 7, h = (wg >> 3) & 7, b = wg >> 6;
    const int r = tid >> 2, quad = tid & 3;
    const int t0 = qt * 64;

    float4 qreg[16];
    {
        const float* qrow = q + ((size_t)(b * 512 + t0 + r) * 512) + h * 64;
#pragma unroll
        for (int i = 0; i < 16; ++i) {
            float4 t = *(const float4*)(qrow + i * 4);
            t.x *= 0.125f; t.y *= 0.125f; t.z *= 0.125f; t.w *= 0.125f;
            qreg[i] = t;
        }
    }
    for (int st = 0; st < 8; ++st) {
        {
            const int s = tid >> 2, d0 = quad * 16;
            const float* krow = k + ((size_t)(b * 512 + st * 64 + s) * 512) + h * 64 + d0;
#pragma unroll
            for (int j = 0; j < 4; ++j)
                *(float4*)&KV[s][d0 + j * 4] = *(const float4*)(krow + j * 4);
        }
        __syncthreads();
        const int sbase = quad * 16;
#pragma unroll 4
        for (int sp = 0; sp < 16; ++sp) {
            const int s = sbase + sp;
            float accd = 0.f;
#pragma unroll
            for (int kk = 0; kk < 16; ++kk) {
                const float4 kv = *(const float4*)&KV[s][kk * 4];
                accd += qreg[kk].x * kv.x + qreg[kk].y * kv.y +
                        qreg[kk].z * kv.z + qreg[kk].w * kv.w;
            }
            S[r][st * 64 + s] = accd;
        }
        __syncthreads();
    }
    const int c0 = quad * 128;
    float mx = -1e30f;
    for (int c4 = 0; c4 < 32; ++c4) {
        const float4 sv = *(const float4*)&S[r][c0 + c4 * 4];
        mx = fmaxf(mx, fmaxf(fmaxf(sv.x, sv.y), fmaxf(sv.z, sv.w)));
    }
    mx = fmaxf(mx, __shfl_xor(mx, 1));
    mx = fmaxf(mx, __shfl_xor(mx, 2));
    float sum = 0.f;
    for (int c4 = 0; c4 < 32; ++c4) {
        float4 sv = *(const float4*)&S[r][c0 + c4 * 4];
        sv.x = __expf(sv.x - mx); sv.y = __expf(sv.y - mx);
        sv.z = __expf(sv.z - mx); sv.w = __expf(sv.w - mx);
        sum += sv.x + sv.y + sv.z + sv.w;
        *(float4*)&S[r][c0 + c4 * 4] = sv;
    }
    sum += __shfl_xor(sum, 1);
    sum += __shfl_xor(sum, 2);
    const float inv = 1.0f / sum;
    __syncthreads();
    float o[16] = {};
    const int d0 = quad * 16;
    for (int st = 0; st < 8; ++st) {
        {
            const int s = tid >> 2;
            const float* vrow = v + ((size_t)(b * 512 + st * 64 + s) * 512) + h * 64 + d0;
#pragma unroll
            for (int j = 0; j < 4; ++j)
                *(float4*)&KV[s][d0 + j * 4] = *(const float4*)(vrow + j * 4);
        }
        __syncthreads();
        for (int s4 = 0; s4 < 16; ++s4) {
            const float4 p = *(const float4*)&S[r][st * 64 + s4 * 4];
            const float pv[4] = {p.x, p.y, p.z, p.w};
#pragma unroll
            for (int jj = 0; jj < 4; ++jj) {
                const int s = s4 * 4 + jj;
#pragma unroll
                for (int i = 0; i < 4; ++i) {
                    const float4 vv = *(const float4*)&KV[s][d0 + i * 4];
                    o[i * 4 + 0] = fmaf(pv[jj], vv.x, o[i * 4 + 0]);
                    o[i * 4 + 1] = fmaf(pv[jj], vv.y, o[i * 4 + 1]);
                    o[i * 4 + 2] = fmaf(pv[jj], vv.z, o[i * 4 + 2]);
                    o[i * 4 + 3] = fmaf(pv[jj], vv.w, o[i * 4 + 3]);
                }
            }
        }
        __syncthreads();
    }
    unsigned short* crow = ctxb + ((size_t)(b * 512 + t0 + r) * 512) + h * 64 + d0;
#pragma unroll
    for (int i = 0; i < 4; ++i) {
        const us4 t = {f2bf(o[i * 4 + 0] * inv), f2bf(o[i * 4 + 1] * inv),
                       f2bf(o[i * 4 + 2] * inv), f2bf(o[i * 4 + 3] * inv)};
        *(us4*)(crow + i * 4) = t;
    }
}

// ---------------- layernorm (rows of 512), optional bf16 side output --------------------------
__global__ __launch_bounds__(256)
void ln_f32(const float* __restrict__ in, float* __restrict__ out,
            const float* __restrict__ g, const float* __restrict__ bb,
            unsigned short* __restrict__ outb)
{
    const int lane = threadIdx.x & 63;
    const int row = blockIdx.x * 4 + (threadIdx.x >> 6);
    const float* x = in + (size_t)row * 512;
    const float4 a = *(const float4*)(x + lane * 4);
    const float4 c = *(const float4*)(x + 256 + lane * 4);
    float s = a.x + a.y + a.z + a.w + c.x + c.y + c.z + c.w;
#pragma unroll
    for (int off = 1; off < 64; off <<= 1) s += __shfl_xor(s, off);
    const float mu = s * (1.0f / 512.0f);
    float vs = 0.f;
    vs += (a.x - mu) * (a.x - mu) + (a.y - mu) * (a.y - mu);
    vs += (a.z - mu) * (a.z - mu) + (a.w - mu) * (a.w - mu);
    vs += (c.x - mu) * (c.x - mu) + (c.y - mu) * (c.y - mu);
    vs += (c.z - mu) * (c.z - mu) + (c.w - mu) * (c.w - mu);
#pragma unroll
    for (int off = 1; off < 64; off <<= 1) vs += __shfl_xor(vs, off);
    const float rstd = rsqrtf(vs * (1.0f / 512.0f) + 1e-3f);
    const float4 g1 = *(const float4*)(g + lane * 4);
    const float4 g2 = *(const float4*)(g + 256 + lane * 4);
    const float4 b1 = *(const float4*)(bb + lane * 4);
    const float4 b2 = *(const float4*)(bb + 256 + lane * 4);
    float* y = out + (size_t)row * 512;
    const float4 o1 = {(a.x - mu) * rstd * g1.x + b1.x, (a.y - mu) * rstd * g1.y + b1.y,
                       (a.z - mu) * rstd * g1.z + b1.z, (a.w - mu) * rstd * g1.w + b1.w};
    const float4 o2 = {(c.x - mu) * rstd * g2.x + b2.x, (c.y - mu) * rstd * g2.y + b2.y,
                       (c.z - mu) * rstd * g2.z + b2.z, (c.w - mu) * rstd * g2.w + b2.w};
    *(float4*)(y + lane * 4) = o1;
    *(float4*)(y + 256 + lane * 4) = o2;
    if (outb) {
        unsigned short* yb = outb + (size_t)row * 512;
        const us4 p1 = {f2bf(o1.x), f2bf(o1.y), f2bf(o1.z), f2bf(o1.w)};
        const us4 p2 = {f2bf(o2.x), f2bf(o2.y), f2bf(o2.z), f2bf(o2.w)};
        *(us4*)(yb + lane * 4) = p1;
        *(us4*)(yb + 256 + lane * 4) = p2;
    }
}

// ---------------- persistent GRU, XCD-pinned: 8 WGs / 32 independent waves on ONE XCD --------
// Election (proven r4-r7). Hot loop (r8): NO __syncthreads, waves fully decoupled.
// Arrive: drain own h-stores (vmcnt0) -> plain byte flags[wave]=(t+1)&0xff (write-through L2)
//         + fire-and-forget relaxed agent fetch_add on bar (fallback counter).
// Poll:   buffer_inv (L1 flash invalidate; r7 proved sc0 loads alone re-hit stale L1) then two
//         16B sc0 loads of all 32 flags from shared XCD L2 (~250cy). After 2048 failures, lane0
//         falls back to r5's PROVEN L3 RMW poll of bar (target 32*(t+1)).
// h-loads after a successful poll are post-inv -> deterministically fresh from L2.
__global__ __launch_bounds__(256, 1)
void gru_persist(const float* __restrict__ rk,      // gru_rk [512][1536] fp32
                 const unsigned short* __restrict__ xpb, // [8192][1536] bf16 (bias0 included)
                 const float* __restrict__ rb,      // recurrent bias [1536]
                 unsigned short* __restrict__ hbuf, // [2][16*512] bf16 (zeroed)
                 unsigned short* __restrict__ goutb,// [8192][512] bf16
                 unsigned char* __restrict__ flags, // [32] per-wave step flags (zeroed)
                 unsigned int* __restrict__ bar,    // fallback arrival counter (zeroed)
                 unsigned int* __restrict__ ctl)    // [16]: per-XCD rank + started (zeroed)
{
    __shared__ int sh_part, sh_memb;
    const int tid = threadIdx.x;

    if (tid == 0) {
        unsigned int xcc;
        asm("s_getreg_b32 %0, hwreg(HW_REG_XCC_ID)" : "=s"(xcc));
        xcc &= 7u;
        const unsigned int rank =
            __hip_atomic_fetch_add(&ctl[xcc], 1u, __ATOMIC_RELAXED, __HIP_MEMORY_SCOPE_AGENT);
        __hip_atomic_fetch_add(&ctl[8], 1u, __ATOMIC_ACQ_REL, __HIP_MEMORY_SCOPE_AGENT);
        unsigned int spins = 0;
        while (__hip_atomic_load(&ctl[8], __ATOMIC_ACQUIRE, __HIP_MEMORY_SCOPE_AGENT)
               < (unsigned)GRID_WGS) {
            __builtin_amdgcn_s_sleep(1);
            if (++spins > (1u << 20)) break;
        }
        unsigned int cnt[8];
#pragma unroll
        for (int i = 0; i < 8; ++i)
            cnt[i] = __hip_atomic_load(&ctl[i], __ATOMIC_ACQUIRE, __HIP_MEMORY_SCOPE_AGENT);
        int best = 0;
#pragma unroll
        for (int i = 1; i < 8; ++i)
            if (cnt[i] > cnt[best]) best = i;
        sh_part = (xcc == (unsigned)best && rank < 8u) ? 1 : 0;
        sh_memb = (int)rank;
    }
    __syncthreads();
    if (!sh_part) return;
    const int member = sh_memb;          // 0..7

    const int wv = tid >> 6, l = tid & 63;
    const int wgi = member * 4 + wv;     // global wave index 0..31
    const int lo16 = l & 15;
    const int hi4 = l >> 4;              // 0..3
    const int gc = wgi * 16 + lo16;      // this lane's output h-col

    // ---- preload B fragments: B[g][kt], lane slot j <-> k = kt*32 + hi4*8 + j
    bf16x8 B[3][16];
#pragma unroll
    for (int g = 0; g < 3; ++g)
#pragma unroll
        for (int kt = 0; kt < 16; ++kt) {
            bf16x8 bv;
#pragma unroll
            for (int j = 0; j < 8; ++j) {
                const int k = kt * 32 + hi4 * 8 + j;
                bv[j] = (short)f2bf(rk[(size_t)k * 1536 + g * 512 + gc]);
            }
            B[g][kt] = bv;
        }
    const float rbz = rb[gc], rbr = rb[512 + gc], rbh = rb[1024 + gc];
    float hst[4] = {0.f, 0.f, 0.f, 0.f};

    // prefetch xp (bf16) for t=0
    float xzv[4], xrv[4], xhv[4];
#pragma unroll
    for (int j = 0; j < 4; ++j) {
        const unsigned short* xrow = xpb + ((size_t)((hi4 * 4 + j) * 512)) * 1536 + gc;
        xzv[j] = bf2f(xrow[0]); xrv[j] = bf2f(xrow[512]); xhv[j] = bf2f(xrow[1024]);
    }

    for (int t = 0; t < 512; ++t) {
        const unsigned short* hr = hbuf + (size_t)(t & 1) * (16 * 512);
        unsigned short* hw = hbuf + (size_t)((t + 1) & 1) * (16 * 512);
        // A frags via sc0 loads; L1 was flash-invalidated during the poll -> L2-fresh
        bf16x8 A[16];
#pragma unroll
        for (int kt = 0; kt < 16; ++kt) {
            const unsigned short* ap = hr + lo16 * 512 + kt * 32 + hi4 * 8;
            asm volatile("global_load_dwordx4 %0, %1, off sc0"
                         : "=v"(A[kt]) : "v"(ap) : "memory");
        }
        asm volatile("s_waitcnt vmcnt(0)" ::: "memory");
        __builtin_amdgcn_sched_barrier(0);

        f32x4 accz = {0.f, 0.f, 0.f, 0.f};
        f32x4 accr = {0.f, 0.f, 0.f, 0.f};
        f32x4 acch = {0.f, 0.f, 0.f, 0.f};
#pragma unroll
        for (int kt = 0; kt < 16; ++kt) {
            accz = __builtin_amdgcn_mfma_f32_16x16x32_bf16(A[kt], B[0][kt], accz, 0, 0, 0);
            accr = __builtin_amdgcn_mfma_f32_16x16x32_bf16(A[kt], B[1][kt], accr, 0, 0, 0);
            acch = __builtin_amdgcn_mfma_f32_16x16x32_bf16(A[kt], B[2][kt], acch, 0, 0, 0);
        }
        // gates + state update; D layout: row b = hi4*4 + j, col = lo16
        float hn[4];
#pragma unroll
        for (int j = 0; j < 4; ++j) {
            const int b = hi4 * 4 + j;
            const float z = sigmoidf_(xzv[j] + accz[j] + rbz);
            const float r = sigmoidf_(xrv[j] + accr[j] + rbr);
            const float hh = fmaxf(xhv[j] + r * (acch[j] + rbh), 0.f);
            const float hnew = z * hst[j] + (1.f - z) * hh;
            hst[j] = hnew; hn[j] = hnew;
            hw[b * 512 + gc] = f2bf(hnew);   // plain store: write-through -> shared XCD L2
        }
        // drain own h stores, then publish: flag byte (fast path) + counter arrive (fallback)
        asm volatile("s_waitcnt vmcnt(0)" ::: "memory");
        const unsigned int tb = (unsigned int)((t + 1) & 0xff);
        if (l == 0) {
            flags[wgi] = (unsigned char)tb;
            __hip_atomic_fetch_add(bar, 1u, __ATOMIC_RELAXED, __HIP_MEMORY_SCOPE_AGENT);
        }
        // deferred off critical path: gout stores, then xp prefetch (overlaps the poll)
#pragma unroll
        for (int j = 0; j < 4; ++j)
            goutb[((size_t)((hi4 * 4 + j) * 512 + t)) * 512 + gc] = f2bf(hn[j]);
        if (t < 511) {
#pragma unroll
            for (int j = 0; j < 4; ++j) {
                const unsigned short* xrow =
                    xpb + ((size_t)((hi4 * 4 + j) * 512 + t + 1)) * 1536 + gc;
                xzv[j] = bf2f(xrow[0]); xrv[j] = bf2f(xrow[512]); xhv[j] = bf2f(xrow[1024]);
            }
            // fast poll: L1 flash-invalidate + two 16B sc0 loads of all 32 flags (L2)
            const unsigned int pat = tb * 0x01010101u;
            u32x4 f0, f1;
            unsigned int it = 0;
            bool ok = false;
            while (it <= 2048u) {
                asm volatile("buffer_inv\n\t"
                             "global_load_dwordx4 %0, %2, off sc0\n\t"
                             "global_load_dwordx4 %1, %2, off offset:16 sc0\n\t"
                             "s_waitcnt vmcnt(0)"
                             : "=&v"(f0), "=&v"(f1) : "v"(flags) : "memory");
                if (f0[0] == pat && f0[1] == pat && f0[2] == pat && f0[3] == pat &&
                    f1[0] == pat && f1[1] == pat && f1[2] == pat && f1[3] == pat) {
                    ok = true; break;
                }
                ++it;
            }
            if (!ok && l == 0) {
                // fallback: r5's proven RMW poll at the L3 atomic point
                const unsigned int target = 32u * (unsigned int)(t + 1);
                unsigned int cur = 0, it2 = 0;
                do {
                    asm volatile("global_atomic_add %0, %1, %2, off sc0\n\t"
                                 "s_waitcnt vmcnt(0)"
                                 : "=v"(cur) : "v"(bar), "v"(0u) : "memory");
                    if (++it2 > (1u << 15)) break;
                } while (cur < target);
            }
            __builtin_amdgcn_sched_barrier(0);
        }
    }
}

extern "C" void kernel_launch(void* const* d_in, const int* in_sizes, int n_in,
                              void* d_out, int out_size, void* d_ws, size_t ws_size,
                              hipStream_t stream)
{
    const float* x     = (const float*)d_in[0];
    const float* Wq    = (const float*)d_in[1];
    const float* bq    = (const float*)d_in[2];
    const float* Wk    = (const float*)d_in[3];
    const float* bk    = (const float*)d_in[4];
    const float* Wv    = (const float*)d_in[5];
    const float* bv    = (const float*)d_in[6];
    const float* Wo    = (const float*)d_in[7];
    const float* bo    = (const float*)d_in[8];
    const float* ln1g  = (const float*)d_in[9];
    const float* ln1b  = (const float*)d_in[10];
    const float* gruk  = (const float*)d_in[11];
    const float* grurk = (const float*)d_in[12];
    const float* grub  = (const float*)d_in[13];
    const float* Wd    = (const float*)d_in[14];
    const float* bd    = (const float*)d_in[15];
    const float* ln2g  = (const float*)d_in[16];
    const float* ln2b  = (const float*)d_in[17];
    float* out = (float*)d_out;

    char* base = (char*)d_ws;
    const size_t MB = 1024 * 1024;
    float*          Q0   = (float*)base;                      // 48 MB: q/k/v -> xpb -> dense-out
    float*          R4   = (float*)(base + 48 * MB);          // 16 MB: x1
    unsigned short* S1   = (unsigned short*)(base + 64 * MB); // 8 MB: xb -> ctxb -> x1b -> goutb
    unsigned short* WT   = (unsigned short*)(base + 72 * MB); // 4 MB weights
    unsigned short* wqT  = WT;
    unsigned short* wkT  = WT + 256 * 1024;
    unsigned short* wvT  = WT + 512 * 1024;
    unsigned short* woT  = WT + 768 * 1024;
    unsigned short* gkT  = WT + 1024 * 1024;    // 1536x512
    unsigned short* wdT  = WT + 1792 * 1024;
    unsigned short* hbuf = (unsigned short*)(base + 76 * MB); // 2*16*512 bf16 = 32 KB
    unsigned int*   barz = (unsigned int*)(base + 76 * MB + 64 * 1024);   // memset region base
    unsigned int*   ctl  = (unsigned int*)(base + 76 * MB + 64 * 1024 + 128);
    unsigned char*  flg  = (unsigned char*)(base + 76 * MB + 64 * 1024 + 256);

    float* q = Q0;
    float* k = Q0 + (size_t)4 * MB;
    float* v = Q0 + (size_t)8 * MB;
    unsigned short* xpb = (unsigned short*)Q0;   // 8192x1536 bf16 = 24 MB (after q/k/v dead)
    float* dout  = (float*)(base + 24 * MB);     // 8192x512 f32 (after q/k/v dead, above xpb)

    const dim3 blk(256);
    const dim3 g512(8192 / 128, 512 / 128);
    const dim3 g1536(8192 / 128, 1536 / 128);

    f2bf_kernel<<<dim3(4096), blk, 0, stream>>>(x, S1);
    transpose_bf16<<<dim3(16, 16), blk, 0, stream>>>(Wq, wqT, 512, 512);
    transpose_bf16<<<dim3(16, 16), blk, 0, stream>>>(Wk, wkT, 512, 512);
    transpose_bf16<<<dim3(16, 16), blk, 0, stream>>>(Wv, wvT, 512, 512);
    transpose_bf16<<<dim3(16, 16), blk, 0, stream>>>(Wo, woT, 512, 512);
    transpose_bf16<<<dim3(48, 16), blk, 0, stream>>>(gruk, gkT, 512, 1536);
    transpose_bf16<<<dim3(16, 16), blk, 0, stream>>>(Wd, wdT, 512, 512);
    gemm_bf16<<<g512, blk, 0, stream>>>(S1, wqT, bq, nullptr, q, nullptr, 8192, 512, 512);
    gemm_bf16<<<g512, blk, 0, stream>>>(S1, wkT, bk, nullptr, k, nullptr, 8192, 512, 512);
    gemm_bf16<<<g512, blk, 0, stream>>>(S1, wvT, bv, nullptr, v, nullptr, 8192, 512, 512);
    attn_f32<<<dim3(1024), blk, 0, stream>>>(q, k, v, S1);
    gemm_bf16<<<g512, blk, 0, stream>>>(S1, woT, bo, x, R4, nullptr, 8192, 512, 512);
    ln_f32<<<dim3(2048), blk, 0, stream>>>(R4, R4, ln1g, ln1b, S1);
    // xp = x1 @ gru_k + gru_b[0], bf16-only output
    gemm_bf16<<<g1536, blk, 0, stream>>>(S1, gkT, grub, nullptr, nullptr, xpb, 8192, 1536, 512);
    // persistent GRU (XCD-pinned, L2-flag barrier + L1 invalidate, counter fallback)
    hipMemsetAsync(hbuf, 0, 2 * 16 * 512 * sizeof(unsigned short), stream);
    hipMemsetAsync(barz, 0, 512, stream);   // covers bar + ctl + flags
    gru_persist<<<dim3(GRID_WGS), blk, 0, stream>>>(grurk, xpb, grub + 1536, hbuf, S1,
                                                    flg, barz, ctl);
    gemm_bf16<<<g512, blk, 0, stream>>>(S1, wdT, bd, R4, dout, nullptr, 8192, 512, 512);
    ln_f32<<<dim3(2048), blk, 0, stream>>>(dout, out, ln2g, ln2b, nullptr);
}

// Round 9
// 2697.220 us; speedup vs baseline: 1873.9623x; 54.2428x over previous
//
#include <hip/hip_runtime.h>
#include <math.h>

// B=16, T=512, F=512, H=8, D=64; rows = B*T = 8192
#define GRID_WGS 128   // launched WGs for GRU; 8 elected (same XCD) participate

typedef __attribute__((ext_vector_type(8))) short bf16x8;
typedef __attribute__((ext_vector_type(4))) float f32x4;
typedef __attribute__((ext_vector_type(4))) unsigned short us4;

static __device__ __forceinline__ float sigmoidf_(float x) {
    return 1.0f / (1.0f + __expf(-x));
}
static __device__ __forceinline__ unsigned short f2bf(float f) {
    unsigned int u = __float_as_uint(f);
    u += 0x7fffu + ((u >> 16) & 1u);
    return (unsigned short)(u >> 16);
}
static __device__ __forceinline__ float bf2f(unsigned short b) {
    return __uint_as_float(((unsigned int)b) << 16);
}
static __device__ __forceinline__ void gload_lds16(const void* g, void* l) {
    __builtin_amdgcn_global_load_lds(
        (const __attribute__((address_space(1))) unsigned int*)g,
        (__attribute__((address_space(3))) unsigned int*)l, 16, 0, 0);
}

// ---------------- fp32 -> bf16 convert --------------------------------------------------------
__global__ __launch_bounds__(256)
void f2bf_kernel(const float* __restrict__ in, unsigned short* __restrict__ out)
{
    const int i = (blockIdx.x * 256 + threadIdx.x) * 4;
    const float4 v = *(const float4*)(in + i);
    const us4 o = {f2bf(v.x), f2bf(v.y), f2bf(v.z), f2bf(v.w)};
    *(us4*)(out + i) = o;
}

// ---------------- concat 3x512 bias vectors into one [1536] -----------------------------------
__global__ __launch_bounds__(256)
void concat3(const float* __restrict__ a, const float* __restrict__ b,
             const float* __restrict__ c, float* __restrict__ o)
{
    const int i = blockIdx.x * 256 + threadIdx.x;   // grid 6 -> 1536
    o[i] = (i < 512) ? a[i] : ((i < 1024) ? b[i - 512] : c[i - 1024]);
}

// ---------------- transpose+convert: in [K][N] f32 -> out [N][K] bf16 -------------------------
__global__ __launch_bounds__(256)
void transpose_bf16(const float* __restrict__ in, unsigned short* __restrict__ out,
                    int K, int N)
{
    __shared__ float tile[32][33];
    const int n0 = blockIdx.x * 32, k0 = blockIdx.y * 32;
    const int c = threadIdx.x & 31, r8 = threadIdx.x >> 5;
#pragma unroll
    for (int i = 0; i < 4; ++i) {
        const int k = r8 + i * 8;
        tile[k][c] = in[(size_t)(k0 + k) * N + n0 + c];
    }
    __syncthreads();
#pragma unroll
    for (int i = 0; i < 4; ++i) {
        const int n = r8 + i * 8;
        out[(size_t)(n0 + n) * K + k0 + c] = f2bf(tile[c][n]);
    }
}

// ---------------- bf16 MFMA GEMM: C=A@Bt (+bias)(+resid); f32 C and/or bf16 Cb outputs --------
__global__ __launch_bounds__(256)
void gemm_bf16(const unsigned short* __restrict__ A, const unsigned short* __restrict__ Bt,
               const float* __restrict__ bias, const float* __restrict__ resid,
               float* __restrict__ C, unsigned short* __restrict__ Cb,
               int M, int N, int K)
{
    __shared__ unsigned short As[128 * 64];
    __shared__ unsigned short Bs[128 * 64];
    const int tid = threadIdx.x;
    const int wave = tid >> 6, lane = tid & 63;
    const int bm = blockIdx.x * 128, bn = blockIdx.y * 128;
    const int wr = wave >> 1, wc = wave & 1;
    const int stR = lane >> 3;
    const int stC = (lane & 7) * 8;

    const unsigned short* Abase = A + (size_t)(bm + wave * 32 + stR) * K + stC;
    const unsigned short* Bbase = Bt + (size_t)(bn + wave * 32 + stR) * K + stC;
    unsigned short* AsW = As + wave * 2048;
    unsigned short* BsW = Bs + wave * 2048;

    f32x4 acc[4][4] = {};
    const int fr = lane & 15;
    const int fko = (lane >> 4) * 8;

    for (int k0 = 0; k0 < K; k0 += 64) {
#pragma unroll
        for (int i = 0; i < 4; ++i) {
            gload_lds16(Abase + (size_t)i * 8 * K + k0, AsW + i * 512);
            gload_lds16(Bbase + (size_t)i * 8 * K + k0, BsW + i * 512);
        }
        __syncthreads();
        bf16x8 af[4][2], bfr[4][2];
#pragma unroll
        for (int m = 0; m < 4; ++m) {
            const unsigned short* ap = As + (wr * 64 + m * 16 + fr) * 64 + fko;
            af[m][0] = *(const bf16x8*)(ap);
            af[m][1] = *(const bf16x8*)(ap + 32);
        }
#pragma unroll
        for (int n = 0; n < 4; ++n) {
            const unsigned short* bp = Bs + (wc * 64 + n * 16 + fr) * 64 + fko;
            bfr[n][0] = *(const bf16x8*)(bp);
            bfr[n][1] = *(const bf16x8*)(bp + 32);
        }
#pragma unroll
        for (int m = 0; m < 4; ++m)
#pragma unroll
            for (int n = 0; n < 4; ++n) {
                acc[m][n] = __builtin_amdgcn_mfma_f32_16x16x32_bf16(af[m][0], bfr[n][0], acc[m][n], 0, 0, 0);
                acc[m][n] = __builtin_amdgcn_mfma_f32_16x16x32_bf16(af[m][1], bfr[n][1], acc[m][n], 0, 0, 0);
            }
        __syncthreads();
    }
    const int fq = lane >> 4;
#pragma unroll
    for (int n = 0; n < 4; ++n) {
        const int col = bn + wc * 64 + n * 16 + fr;
        const float bv = bias ? bias[col] : 0.f;
#pragma unroll
        for (int m = 0; m < 4; ++m) {
#pragma unroll
            for (int j = 0; j < 4; ++j) {
                const int row = bm + wr * 64 + m * 16 + fq * 4 + j;
                float v = acc[m][n][j] + bv;
                if (resid) v += resid[(size_t)row * N + col];
                if (C)  C[(size_t)row * N + col] = v;
                if (Cb) Cb[(size_t)row * N + col] = f2bf(v);
            }
        }
    }
}

// ---------------- fused attention per (b, h, 64-row q tile); qkv fused buffer stride 1536 -----
__global__ __launch_bounds__(256)
void attn_f32(const float* __restrict__ qkv, unsigned short* __restrict__ ctxb)
{
    __shared__ float S[64][512];
    __shared__ float KV[64][68];
    const int tid = threadIdx.x;
    const int wg = blockIdx.x;
    const int qt = wg & 7, h = (wg >> 3) & 7, b = wg >> 6;
    const int r = tid >> 2, quad = tid & 3;
    const int t0 = qt * 64;

    float4 qreg[16];
    {
        const float* qrow = qkv + ((size_t)(b * 512 + t0 + r) * 1536) + h * 64;
#pragma unroll
        for (int i = 0; i < 16; ++i) {
            float4 t = *(const float4*)(qrow + i * 4);
            t.x *= 0.125f; t.y *= 0.125f; t.z *= 0.125f; t.w *= 0.125f;
            qreg[i] = t;
        }
    }
    for (int st = 0; st < 8; ++st) {
        {
            const int s = tid >> 2, d0 = quad * 16;
            const float* krow = qkv + ((size_t)(b * 512 + st * 64 + s) * 1536) + 512 + h * 64 + d0;
#pragma unroll
            for (int j = 0; j < 4; ++j)
                *(float4*)&KV[s][d0 + j * 4] = *(const float4*)(krow + j * 4);
        }
        __syncthreads();
        const int sbase = quad * 16;
#pragma unroll 4
        for (int sp = 0; sp < 16; ++sp) {
            const int s = sbase + sp;
            float accd = 0.f;
#pragma unroll
            for (int kk = 0; kk < 16; ++kk) {
                const float4 kv = *(const float4*)&KV[s][kk * 4];
                accd += qreg[kk].x * kv.x + qreg[kk].y * kv.y +
                        qreg[kk].z * kv.z + qreg[kk].w * kv.w;
            }
            S[r][st * 64 + s] = accd;
        }
        __syncthreads();
    }
    const int c0 = quad * 128;
    float mx = -1e30f;
    for (int c4 = 0; c4 < 32; ++c4) {
        const float4 sv = *(const float4*)&S[r][c0 + c4 * 4];
        mx = fmaxf(mx, fmaxf(fmaxf(sv.x, sv.y), fmaxf(sv.z, sv.w)));
    }
    mx = fmaxf(mx, __shfl_xor(mx, 1));
    mx = fmaxf(mx, __shfl_xor(mx, 2));
    float sum = 0.f;
    for (int c4 = 0; c4 < 32; ++c4) {
        float4 sv = *(const float4*)&S[r][c0 + c4 * 4];
        sv.x = __expf(sv.x - mx); sv.y = __expf(sv.y - mx);
        sv.z = __expf(sv.z - mx); sv.w = __expf(sv.w - mx);
        sum += sv.x + sv.y + sv.z + sv.w;
        *(float4*)&S[r][c0 + c4 * 4] = sv;
    }
    sum += __shfl_xor(sum, 1);
    sum += __shfl_xor(sum, 2);
    const float inv = 1.0f / sum;
    __syncthreads();
    float o[16] = {};
    const int d0 = quad * 16;
    for (int st = 0; st < 8; ++st) {
        {
            const int s = tid >> 2;
            const float* vrow = qkv + ((size_t)(b * 512 + st * 64 + s) * 1536) + 1024 + h * 64 + d0;
#pragma unroll
            for (int j = 0; j < 4; ++j)
                *(float4*)&KV[s][d0 + j * 4] = *(const float4*)(vrow + j * 4);
        }
        __syncthreads();
        for (int s4 = 0; s4 < 16; ++s4) {
            const float4 p = *(const float4*)&S[r][st * 64 + s4 * 4];
            const float pv[4] = {p.x, p.y, p.z, p.w};
#pragma unroll
            for (int jj = 0; jj < 4; ++jj) {
                const int s = s4 * 4 + jj;
#pragma unroll
                for (int i = 0; i < 4; ++i) {
                    const float4 vv = *(const float4*)&KV[s][d0 + i * 4];
                    o[i * 4 + 0] = fmaf(pv[jj], vv.x, o[i * 4 + 0]);
                    o[i * 4 + 1] = fmaf(pv[jj], vv.y, o[i * 4 + 1]);
                    o[i * 4 + 2] = fmaf(pv[jj], vv.z, o[i * 4 + 2]);
                    o[i * 4 + 3] = fmaf(pv[jj], vv.w, o[i * 4 + 3]);
                }
            }
        }
        __syncthreads();
    }
    unsigned short* crow = ctxb + ((size_t)(b * 512 + t0 + r) * 512) + h * 64 + d0;
#pragma unroll
    for (int i = 0; i < 4; ++i) {
        const us4 t = {f2bf(o[i * 4 + 0] * inv), f2bf(o[i * 4 + 1] * inv),
                       f2bf(o[i * 4 + 2] * inv), f2bf(o[i * 4 + 3] * inv)};
        *(us4*)(crow + i * 4) = t;
    }
}

// ---------------- layernorm (rows of 512), optional bf16 side output --------------------------
__global__ __launch_bounds__(256)
void ln_f32(const float* __restrict__ in, float* __restrict__ out,
            const float* __restrict__ g, const float* __restrict__ bb,
            unsigned short* __restrict__ outb)
{
    const int lane = threadIdx.x & 63;
    const int row = blockIdx.x * 4 + (threadIdx.x >> 6);
    const float* x = in + (size_t)row * 512;
    const float4 a = *(const float4*)(x + lane * 4);
    const float4 c = *(const float4*)(x + 256 + lane * 4);
    float s = a.x + a.y + a.z + a.w + c.x + c.y + c.z + c.w;
#pragma unroll
    for (int off = 1; off < 64; off <<= 1) s += __shfl_xor(s, off);
    const float mu = s * (1.0f / 512.0f);
    float vs = 0.f;
    vs += (a.x - mu) * (a.x - mu) + (a.y - mu) * (a.y - mu);
    vs += (a.z - mu) * (a.z - mu) + (a.w - mu) * (a.w - mu);
    vs += (c.x - mu) * (c.x - mu) + (c.y - mu) * (c.y - mu);
    vs += (c.z - mu) * (c.z - mu) + (c.w - mu) * (c.w - mu);
#pragma unroll
    for (int off = 1; off < 64; off <<= 1) vs += __shfl_xor(vs, off);
    const float rstd = rsqrtf(vs * (1.0f / 512.0f) + 1e-3f);
    const float4 g1 = *(const float4*)(g + lane * 4);
    const float4 g2 = *(const float4*)(g + 256 + lane * 4);
    const float4 b1 = *(const float4*)(bb + lane * 4);
    const float4 b2 = *(const float4*)(bb + 256 + lane * 4);
    float* y = out + (size_t)row * 512;
    const float4 o1 = {(a.x - mu) * rstd * g1.x + b1.x, (a.y - mu) * rstd * g1.y + b1.y,
                       (a.z - mu) * rstd * g1.z + b1.z, (a.w - mu) * rstd * g1.w + b1.w};
    const float4 o2 = {(c.x - mu) * rstd * g2.x + b2.x, (c.y - mu) * rstd * g2.y + b2.y,
                       (c.z - mu) * rstd * g2.z + b2.z, (c.w - mu) * rstd * g2.w + b2.w};
    *(float4*)(y + lane * 4) = o1;
    *(float4*)(y + 256 + lane * 4) = o2;
    if (outb) {
        unsigned short* yb = outb + (size_t)row * 512;
        const us4 p1 = {f2bf(o1.x), f2bf(o1.y), f2bf(o1.z), f2bf(o1.w)};
        const us4 p2 = {f2bf(o2.x), f2bf(o2.y), f2bf(o2.z), f2bf(o2.w)};
        *(us4*)(yb + lane * 4) = p1;
        *(us4*)(yb + 256 + lane * 4) = p2;
    }
}

// ---------------- persistent GRU, XCD-pinned: 8 WGs / 32 independent waves on ONE XCD --------
// Election (proven r4-r8). Hot loop (r9): every sync component individually PROVEN:
//  - arrive: L3 RMW fetch_add(+1) [proven r5/r6], now on PER-WAVE counters (32 x 128B-strided
//    lines) -> no RMW serialization on a shared line; fire-and-forget.
//  - poll: relaxed agent atomic load [proven r6 fast path observes L3 atomics]; lane i loads
//    counter (i&31); exit when __ballot(cur >= t+1) == all-ones. 32 loads pipeline in parallel.
//  - fallback after 256 fast iters: RMW add-0 poll [proven r5], bounded 2^15.
// h-exchange stays plain-store -> sc0-load via shared XCD L2 (bit-exact across r5-r8).
// No __syncthreads in the hot loop.
__global__ __launch_bounds__(256, 1)
void gru_persist(const float* __restrict__ rk,      // gru_rk [512][1536] fp32
                 const unsigned short* __restrict__ xpb, // [8192][1536] bf16 (bias0 included)
                 const float* __restrict__ rb,      // recurrent bias [1536]
                 unsigned short* __restrict__ hbuf, // [2][16*512] bf16 (zeroed)
                 unsigned short* __restrict__ goutb,// [8192][512] bf16
                 unsigned int* __restrict__ steps,  // 32 counters, 128B stride (zeroed)
                 unsigned int* __restrict__ ctl)    // [16]: per-XCD rank + started (zeroed)
{
    __shared__ int sh_part, sh_memb;
    const int tid = threadIdx.x;

    if (tid == 0) {
        unsigned int xcc;
        asm("s_getreg_b32 %0, hwreg(HW_REG_XCC_ID)" : "=s"(xcc));
        xcc &= 7u;
        const unsigned int rank =
            __hip_atomic_fetch_add(&ctl[xcc], 1u, __ATOMIC_RELAXED, __HIP_MEMORY_SCOPE_AGENT);
        __hip_atomic_fetch_add(&ctl[8], 1u, __ATOMIC_ACQ_REL, __HIP_MEMORY_SCOPE_AGENT);
        unsigned int spins = 0;
        while (__hip_atomic_load(&ctl[8], __ATOMIC_ACQUIRE, __HIP_MEMORY_SCOPE_AGENT)
               < (unsigned)GRID_WGS) {
            __builtin_amdgcn_s_sleep(1);
            if (++spins > (1u << 20)) break;
        }
        unsigned int cnt[8];
#pragma unroll
        for (int i = 0; i < 8; ++i)
            cnt[i] = __hip_atomic_load(&ctl[i], __ATOMIC_ACQUIRE, __HIP_MEMORY_SCOPE_AGENT);
        int best = 0;
#pragma unroll
        for (int i = 1; i < 8; ++i)
            if (cnt[i] > cnt[best]) best = i;
        sh_part = (xcc == (unsigned)best && rank < 8u) ? 1 : 0;
        sh_memb = (int)rank;
    }
    __syncthreads();
    if (!sh_part) return;
    const int member = sh_memb;          // 0..7

    const int wv = tid >> 6, l = tid & 63;
    const int wgi = member * 4 + wv;     // global wave index 0..31
    const int lo16 = l & 15;
    const int hi4 = l >> 4;              // 0..3
    const int gc = wgi * 16 + lo16;      // this lane's output h-col

    unsigned int* myctr   = steps + (size_t)wgi * 32;       // own arrival counter (128B line)
    unsigned int* pollctr = steps + (size_t)(l & 31) * 32;  // counter this lane polls

    // ---- preload B fragments: B[g][kt], lane slot j <-> k = kt*32 + hi4*8 + j
    bf16x8 B[3][16];
#pragma unroll
    for (int g = 0; g < 3; ++g)
#pragma unroll
        for (int kt = 0; kt < 16; ++kt) {
            bf16x8 bv;
#pragma unroll
            for (int j = 0; j < 8; ++j) {
                const int k = kt * 32 + hi4 * 8 + j;
                bv[j] = (short)f2bf(rk[(size_t)k * 1536 + g * 512 + gc]);
            }
            B[g][kt] = bv;
        }
    const float rbz = rb[gc], rbr = rb[512 + gc], rbh = rb[1024 + gc];
    float hst[4] = {0.f, 0.f, 0.f, 0.f};

    // prefetch xp (bf16) for t=0
    float xzv[4], xrv[4], xhv[4];
#pragma unroll
    for (int j = 0; j < 4; ++j) {
        const unsigned short* xrow = xpb + ((size_t)((hi4 * 4 + j) * 512)) * 1536 + gc;
        xzv[j] = bf2f(xrow[0]); xrv[j] = bf2f(xrow[512]); xhv[j] = bf2f(xrow[1024]);
    }

    for (int t = 0; t < 512; ++t) {
        const unsigned short* hr = hbuf + (size_t)(t & 1) * (16 * 512);
        unsigned short* hw = hbuf + (size_t)((t + 1) & 1) * (16 * 512);
        // A frags via sc0 loads from shared XCD L2
        bf16x8 A[16];
#pragma unroll
        for (int kt = 0; kt < 16; ++kt) {
            const unsigned short* ap = hr + lo16 * 512 + kt * 32 + hi4 * 8;
            asm volatile("global_load_dwordx4 %0, %1, off sc0"
                         : "=v"(A[kt]) : "v"(ap) : "memory");
        }
        asm volatile("s_waitcnt vmcnt(0)" ::: "memory");
        __builtin_amdgcn_sched_barrier(0);

        f32x4 accz = {0.f, 0.f, 0.f, 0.f};
        f32x4 accr = {0.f, 0.f, 0.f, 0.f};
        f32x4 acch = {0.f, 0.f, 0.f, 0.f};
#pragma unroll
        for (int kt = 0; kt < 16; ++kt) {
            accz = __builtin_amdgcn_mfma_f32_16x16x32_bf16(A[kt], B[0][kt], accz, 0, 0, 0);
            accr = __builtin_amdgcn_mfma_f32_16x16x32_bf16(A[kt], B[1][kt], accr, 0, 0, 0);
            acch = __builtin_amdgcn_mfma_f32_16x16x32_bf16(A[kt], B[2][kt], acch, 0, 0, 0);
        }
        // gates + state update; D layout: row b = hi4*4 + j, col = lo16
        float hn[4];
#pragma unroll
        for (int j = 0; j < 4; ++j) {
            const int b = hi4 * 4 + j;
            const float z = sigmoidf_(xzv[j] + accz[j] + rbz);
            const float r = sigmoidf_(xrv[j] + accr[j] + rbr);
            const float hh = fmaxf(xhv[j] + r * (acch[j] + rbh), 0.f);
            const float hnew = z * hst[j] + (1.f - z) * hh;
            hst[j] = hnew; hn[j] = hnew;
            hw[b * 512 + gc] = f2bf(hnew);   // plain store: write-through -> shared XCD L2
        }
        // drain own h stores, then arrive on OWN counter (L3 RMW, contention-free line)
        asm volatile("s_waitcnt vmcnt(0)" ::: "memory");
        if (l == 0)
            __hip_atomic_fetch_add(myctr, 1u, __ATOMIC_RELAXED, __HIP_MEMORY_SCOPE_AGENT);
        // deferred off critical path: gout stores, then xp prefetch (overlaps the poll)
#pragma unroll
        for (int j = 0; j < 4; ++j)
            goutb[((size_t)((hi4 * 4 + j) * 512 + t)) * 512 + gc] = f2bf(hn[j]);
        if (t < 511) {
#pragma unroll
            for (int j = 0; j < 4; ++j) {
                const unsigned short* xrow =
                    xpb + ((size_t)((hi4 * 4 + j) * 512 + t + 1)) * 1536 + gc;
                xzv[j] = bf2f(xrow[0]); xrv[j] = bf2f(xrow[512]); xhv[j] = bf2f(xrow[1024]);
            }
            const unsigned int target = (unsigned int)(t + 1);
            // fast poll: per-lane relaxed agent atomic load (proven L3-observing), ballot-joined
            unsigned int it = 0;
            bool ok = false;
            while (it <= 256u) {
                const unsigned int cur =
                    __hip_atomic_load(pollctr, __ATOMIC_RELAXED, __HIP_MEMORY_SCOPE_AGENT);
                if (__ballot(cur >= target) == ~0ULL) { ok = true; break; }
                ++it;
            }
            if (!ok) {
                // fallback: RMW add-0 poll at the L3 atomic point (proven r5)
                unsigned int it2 = 0;
                while (true) {
                    const unsigned int cur =
                        __hip_atomic_fetch_add(pollctr, 0u, __ATOMIC_RELAXED,
                                               __HIP_MEMORY_SCOPE_AGENT);
                    if (__ballot(cur >= target) == ~0ULL) break;
                    if (++it2 > (1u << 15)) break;
                }
            }
            __builtin_amdgcn_sched_barrier(0);
        }
    }
}

extern "C" void kernel_launch(void* const* d_in, const int* in_sizes, int n_in,
                              void* d_out, int out_size, void* d_ws, size_t ws_size,
                              hipStream_t stream)
{
    const float* x     = (const float*)d_in[0];
    const float* Wq    = (const float*)d_in[1];
    const float* bq    = (const float*)d_in[2];
    const float* Wk    = (const float*)d_in[3];
    const float* bk    = (const float*)d_in[4];
    const float* Wv    = (const float*)d_in[5];
    const float* bv    = (const float*)d_in[6];
    const float* Wo    = (const float*)d_in[7];
    const float* bo    = (const float*)d_in[8];
    const float* ln1g  = (const float*)d_in[9];
    const float* ln1b  = (const float*)d_in[10];
    const float* gruk  = (const float*)d_in[11];
    const float* grurk = (const float*)d_in[12];
    const float* grub  = (const float*)d_in[13];
    const float* Wd    = (const float*)d_in[14];
    const float* bd    = (const float*)d_in[15];
    const float* ln2g  = (const float*)d_in[16];
    const float* ln2b  = (const float*)d_in[17];
    float* out = (float*)d_out;

    char* base = (char*)d_ws;
    const size_t MB = 1024 * 1024;
    float*          Q0   = (float*)base;                      // 48 MB: qkv -> xpb/dout
    float*          R4   = (float*)(base + 48 * MB);          // 16 MB: x1
    unsigned short* S1   = (unsigned short*)(base + 64 * MB); // 8 MB: xb -> ctxb -> x1b -> goutb
    unsigned short* WT   = (unsigned short*)(base + 72 * MB); // 4 MB weights (wq|wk|wv|wo|gk|wd)
    unsigned short* wqkvT = WT;                 // [1536][512] = wq|wk|wv stacked
    unsigned short* woT  = WT + 768 * 1024;
    unsigned short* gkT  = WT + 1024 * 1024;    // 1536x512
    unsigned short* wdT  = WT + 1792 * 1024;
    unsigned short* hbuf = (unsigned short*)(base + 76 * MB); // 2*16*512 bf16 = 32 KB
    char*           Z    = base + 76 * MB + 64 * 1024;        // zeroed control zone (8 KB)
    unsigned int*   ctl  = (unsigned int*)(Z);                // 16 u32
    unsigned int*   steps= (unsigned int*)(Z + 1024);         // 32 x 128B-strided counters (4 KB)
    float*          bqkv = (float*)(base + 77 * MB);          // 1536 floats

    float* qkvf = Q0;                              // 8192x1536 f32 = 48 MB
    unsigned short* xpb = (unsigned short*)Q0;     // 8192x1536 bf16 = 24 MB (after qkv dead)
    float* dout  = (float*)(base + 24 * MB);       // 8192x512 f32 (after qkv dead)

    const dim3 blk(256);
    const dim3 g512(8192 / 128, 512 / 128);
    const dim3 g1536(8192 / 128, 1536 / 128);

    f2bf_kernel<<<dim3(4096), blk, 0, stream>>>(x, S1);
    concat3<<<dim3(6), blk, 0, stream>>>(bq, bk, bv, bqkv);
    transpose_bf16<<<dim3(16, 16), blk, 0, stream>>>(Wq, wqkvT, 512, 512);
    transpose_bf16<<<dim3(16, 16), blk, 0, stream>>>(Wk, wqkvT + 256 * 1024, 512, 512);
    transpose_bf16<<<dim3(16, 16), blk, 0, stream>>>(Wv, wqkvT + 512 * 1024, 512, 512);
    transpose_bf16<<<dim3(16, 16), blk, 0, stream>>>(Wo, woT, 512, 512);
    transpose_bf16<<<dim3(48, 16), blk, 0, stream>>>(gruk, gkT, 512, 1536);
    transpose_bf16<<<dim3(16, 16), blk, 0, stream>>>(Wd, wdT, 512, 512);
    // fused QKV projection: [8192][1536] f32
    gemm_bf16<<<g1536, blk, 0, stream>>>(S1, wqkvT, bqkv, nullptr, qkvf, nullptr, 8192, 1536, 512);
    attn_f32<<<dim3(1024), blk, 0, stream>>>(qkvf, S1);
    gemm_bf16<<<g512, blk, 0, stream>>>(S1, woT, bo, x, R4, nullptr, 8192, 512, 512);
    ln_f32<<<dim3(2048), blk, 0, stream>>>(R4, R4, ln1g, ln1b, S1);
    // xp = x1 @ gru_k + gru_b[0], bf16-only output
    gemm_bf16<<<g1536, blk, 0, stream>>>(S1, gkT, grub, nullptr, nullptr, xpb, 8192, 1536, 512);
    // persistent GRU (XCD-pinned, sharded L3 counters)
    hipMemsetAsync(hbuf, 0, 2 * 16 * 512 * sizeof(unsigned short), stream);
    hipMemsetAsync(Z, 0, 8192, stream);
    gru_persist<<<dim3(GRID_WGS), blk, 0, stream>>>(grurk, xpb, grub + 1536, hbuf, S1,
                                                    steps, ctl);
    gemm_bf16<<<g512, blk, 0, stream>>>(S1, wdT, bd, R4, dout, nullptr, 8192, 512, 512);
    ln_f32<<<dim3(2048), blk, 0, stream>>>(dout, out, ln2g, ln2b, nullptr);
}

// Round 10
// 2464.579 us; speedup vs baseline: 2050.8526x; 1.0944x over previous
//
#include <hip/hip_runtime.h>
#include <math.h>

// B=16, T=512, F=512, H=8, D=64; rows = B*T = 8192
#define GRID_WGS 128   // launched WGs for GRU; 8 elected (same XCD) participate

typedef __attribute__((ext_vector_type(8))) short bf16x8;
typedef __attribute__((ext_vector_type(4))) float f32x4;
typedef __attribute__((ext_vector_type(4))) unsigned short us4;

static __device__ __forceinline__ float sigmoidf_(float x) {
    return 1.0f / (1.0f + __expf(-x));
}
static __device__ __forceinline__ unsigned short f2bf(float f) {
    unsigned int u = __float_as_uint(f);
    u += 0x7fffu + ((u >> 16) & 1u);
    return (unsigned short)(u >> 16);
}
static __device__ __forceinline__ float bfbits2f(unsigned int b) {
    return __uint_as_float(b << 16);
}
static __device__ __forceinline__ void gload_lds16(const void* g, void* l) {
    __builtin_amdgcn_global_load_lds(
        (const __attribute__((address_space(1))) unsigned int*)g,
        (__attribute__((address_space(3))) unsigned int*)l, 16, 0, 0);
}

// ---------------- fp32 -> bf16 convert --------------------------------------------------------
__global__ __launch_bounds__(256)
void f2bf_kernel(const float* __restrict__ in, unsigned short* __restrict__ out)
{
    const int i = (blockIdx.x * 256 + threadIdx.x) * 4;
    const float4 v = *(const float4*)(in + i);
    const us4 o = {f2bf(v.x), f2bf(v.y), f2bf(v.z), f2bf(v.w)};
    *(us4*)(out + i) = o;
}

// ---------------- concat 3x512 bias vectors into one [1536] -----------------------------------
__global__ __launch_bounds__(256)
void concat3(const float* __restrict__ a, const float* __restrict__ b,
             const float* __restrict__ c, float* __restrict__ o)
{
    const int i = blockIdx.x * 256 + threadIdx.x;   // grid 6 -> 1536
    o[i] = (i < 512) ? a[i] : ((i < 1024) ? b[i - 512] : c[i - 1024]);
}

// ---------------- transpose+convert: in [K][N] f32 -> out [N][K] bf16 -------------------------
__global__ __launch_bounds__(256)
void transpose_bf16(const float* __restrict__ in, unsigned short* __restrict__ out,
                    int K, int N)
{
    __shared__ float tile[32][33];
    const int n0 = blockIdx.x * 32, k0 = blockIdx.y * 32;
    const int c = threadIdx.x & 31, r8 = threadIdx.x >> 5;
#pragma unroll
    for (int i = 0; i < 4; ++i) {
        const int k = r8 + i * 8;
        tile[k][c] = in[(size_t)(k0 + k) * N + n0 + c];
    }
    __syncthreads();
#pragma unroll
    for (int i = 0; i < 4; ++i) {
        const int n = r8 + i * 8;
        out[(size_t)(n0 + n) * K + k0 + c] = f2bf(tile[c][n]);
    }
}

// ---------------- bf16 MFMA GEMM: C=A@Bt (+bias)(+resid); f32 C and/or bf16 Cb outputs --------
__global__ __launch_bounds__(256)
void gemm_bf16(const unsigned short* __restrict__ A, const unsigned short* __restrict__ Bt,
               const float* __restrict__ bias, const float* __restrict__ resid,
               float* __restrict__ C, unsigned short* __restrict__ Cb,
               int M, int N, int K)
{
    __shared__ unsigned short As[128 * 64];
    __shared__ unsigned short Bs[128 * 64];
    const int tid = threadIdx.x;
    const int wave = tid >> 6, lane = tid & 63;
    const int bm = blockIdx.x * 128, bn = blockIdx.y * 128;
    const int wr = wave >> 1, wc = wave & 1;
    const int stR = lane >> 3;
    const int stC = (lane & 7) * 8;

    const unsigned short* Abase = A + (size_t)(bm + wave * 32 + stR) * K + stC;
    const unsigned short* Bbase = Bt + (size_t)(bn + wave * 32 + stR) * K + stC;
    unsigned short* AsW = As + wave * 2048;
    unsigned short* BsW = Bs + wave * 2048;

    f32x4 acc[4][4] = {};
    const int fr = lane & 15;
    const int fko = (lane >> 4) * 8;

    for (int k0 = 0; k0 < K; k0 += 64) {
#pragma unroll
        for (int i = 0; i < 4; ++i) {
            gload_lds16(Abase + (size_t)i * 8 * K + k0, AsW + i * 512);
            gload_lds16(Bbase + (size_t)i * 8 * K + k0, BsW + i * 512);
        }
        __syncthreads();
        bf16x8 af[4][2], bfr[4][2];
#pragma unroll
        for (int m = 0; m < 4; ++m) {
            const unsigned short* ap = As + (wr * 64 + m * 16 + fr) * 64 + fko;
            af[m][0] = *(const bf16x8*)(ap);
            af[m][1] = *(const bf16x8*)(ap + 32);
        }
#pragma unroll
        for (int n = 0; n < 4; ++n) {
            const unsigned short* bp = Bs + (wc * 64 + n * 16 + fr) * 64 + fko;
            bfr[n][0] = *(const bf16x8*)(bp);
            bfr[n][1] = *(const bf16x8*)(bp + 32);
        }
#pragma unroll
        for (int m = 0; m < 4; ++m)
#pragma unroll
            for (int n = 0; n < 4; ++n) {
                acc[m][n] = __builtin_amdgcn_mfma_f32_16x16x32_bf16(af[m][0], bfr[n][0], acc[m][n], 0, 0, 0);
                acc[m][n] = __builtin_amdgcn_mfma_f32_16x16x32_bf16(af[m][1], bfr[n][1], acc[m][n], 0, 0, 0);
            }
        __syncthreads();
    }
    const int fq = lane >> 4;
#pragma unroll
    for (int n = 0; n < 4; ++n) {
        const int col = bn + wc * 64 + n * 16 + fr;
        const float bv = bias ? bias[col] : 0.f;
#pragma unroll
        for (int m = 0; m < 4; ++m) {
#pragma unroll
            for (int j = 0; j < 4; ++j) {
                const int row = bm + wr * 64 + m * 16 + fq * 4 + j;
                float v = acc[m][n][j] + bv;
                if (resid) v += resid[(size_t)row * N + col];
                if (C)  C[(size_t)row * N + col] = v;
                if (Cb) Cb[(size_t)row * N + col] = f2bf(v);
            }
        }
    }
}

// ---------------- fused attention per (b, h, 64-row q tile); qkv fused buffer stride 1536 -----
__global__ __launch_bounds__(256)
void attn_f32(const float* __restrict__ qkv, unsigned short* __restrict__ ctxb)
{
    __shared__ float S[64][512];
    __shared__ float KV[64][68];
    const int tid = threadIdx.x;
    const int wg = blockIdx.x;
    const int qt = wg & 7, h = (wg >> 3) & 7, b = wg >> 6;
    const int r = tid >> 2, quad = tid & 3;
    const int t0 = qt * 64;

    float4 qreg[16];
    {
        const float* qrow = qkv + ((size_t)(b * 512 + t0 + r) * 1536) + h * 64;
#pragma unroll
        for (int i = 0; i < 16; ++i) {
            float4 t = *(const float4*)(qrow + i * 4);
            t.x *= 0.125f; t.y *= 0.125f; t.z *= 0.125f; t.w *= 0.125f;
            qreg[i] = t;
        }
    }
    for (int st = 0; st < 8; ++st) {
        {
            const int s = tid >> 2, d0 = quad * 16;
            const float* krow = qkv + ((size_t)(b * 512 + st * 64 + s) * 1536) + 512 + h * 64 + d0;
#pragma unroll
            for (int j = 0; j < 4; ++j)
                *(float4*)&KV[s][d0 + j * 4] = *(const float4*)(krow + j * 4);
        }
        __syncthreads();
        const int sbase = quad * 16;
#pragma unroll 4
        for (int sp = 0; sp < 16; ++sp) {
            const int s = sbase + sp;
            float accd = 0.f;
#pragma unroll
            for (int kk = 0; kk < 16; ++kk) {
                const float4 kv = *(const float4*)&KV[s][kk * 4];
                accd += qreg[kk].x * kv.x + qreg[kk].y * kv.y +
                        qreg[kk].z * kv.z + qreg[kk].w * kv.w;
            }
            S[r][st * 64 + s] = accd;
        }
        __syncthreads();
    }
    const int c0 = quad * 128;
    float mx = -1e30f;
    for (int c4 = 0; c4 < 32; ++c4) {
        const float4 sv = *(const float4*)&S[r][c0 + c4 * 4];
        mx = fmaxf(mx, fmaxf(fmaxf(sv.x, sv.y), fmaxf(sv.z, sv.w)));
    }
    mx = fmaxf(mx, __shfl_xor(mx, 1));
    mx = fmaxf(mx, __shfl_xor(mx, 2));
    float sum = 0.f;
    for (int c4 = 0; c4 < 32; ++c4) {
        float4 sv = *(const float4*)&S[r][c0 + c4 * 4];
        sv.x = __expf(sv.x - mx); sv.y = __expf(sv.y - mx);
        sv.z = __expf(sv.z - mx); sv.w = __expf(sv.w - mx);
        sum += sv.x + sv.y + sv.z + sv.w;
        *(float4*)&S[r][c0 + c4 * 4] = sv;
    }
    sum += __shfl_xor(sum, 1);
    sum += __shfl_xor(sum, 2);
    const float inv = 1.0f / sum;
    __syncthreads();
    float o[16] = {};
    const int d0 = quad * 16;
    for (int st = 0; st < 8; ++st) {
        {
            const int s = tid >> 2;
            const float* vrow = qkv + ((size_t)(b * 512 + st * 64 + s) * 1536) + 1024 + h * 64 + d0;
#pragma unroll
            for (int j = 0; j < 4; ++j)
                *(float4*)&KV[s][d0 + j * 4] = *(const float4*)(vrow + j * 4);
        }
        __syncthreads();
        for (int s4 = 0; s4 < 16; ++s4) {
            const float4 p = *(const float4*)&S[r][st * 64 + s4 * 4];
            const float pv[4] = {p.x, p.y, p.z, p.w};
#pragma unroll
            for (int jj = 0; jj < 4; ++jj) {
                const int s = s4 * 4 + jj;
#pragma unroll
                for (int i = 0; i < 4; ++i) {
                    const float4 vv = *(const float4*)&KV[s][d0 + i * 4];
                    o[i * 4 + 0] = fmaf(pv[jj], vv.x, o[i * 4 + 0]);
                    o[i * 4 + 1] = fmaf(pv[jj], vv.y, o[i * 4 + 1]);
                    o[i * 4 + 2] = fmaf(pv[jj], vv.z, o[i * 4 + 2]);
                    o[i * 4 + 3] = fmaf(pv[jj], vv.w, o[i * 4 + 3]);
                }
            }
        }
        __syncthreads();
    }
    unsigned short* crow = ctxb + ((size_t)(b * 512 + t0 + r) * 512) + h * 64 + d0;
#pragma unroll
    for (int i = 0; i < 4; ++i) {
        const us4 t = {f2bf(o[i * 4 + 0] * inv), f2bf(o[i * 4 + 1] * inv),
                       f2bf(o[i * 4 + 2] * inv), f2bf(o[i * 4 + 3] * inv)};
        *(us4*)(crow + i * 4) = t;
    }
}

// ---------------- layernorm (rows of 512), optional bf16 side output --------------------------
__global__ __launch_bounds__(256)
void ln_f32(const float* __restrict__ in, float* __restrict__ out,
            const float* __restrict__ g, const float* __restrict__ bb,
            unsigned short* __restrict__ outb)
{
    const int lane = threadIdx.x & 63;
    const int row = blockIdx.x * 4 + (threadIdx.x >> 6);
    const float* x = in + (size_t)row * 512;
    const float4 a = *(const float4*)(x + lane * 4);
    const float4 c = *(const float4*)(x + 256 + lane * 4);
    float s = a.x + a.y + a.z + a.w + c.x + c.y + c.z + c.w;
#pragma unroll
    for (int off = 1; off < 64; off <<= 1) s += __shfl_xor(s, off);
    const float mu = s * (1.0f / 512.0f);
    float vs = 0.f;
    vs += (a.x - mu) * (a.x - mu) + (a.y - mu) * (a.y - mu);
    vs += (a.z - mu) * (a.z - mu) + (a.w - mu) * (a.w - mu);
    vs += (c.x - mu) * (c.x - mu) + (c.y - mu) * (c.y - mu);
    vs += (c.z - mu) * (c.z - mu) + (c.w - mu) * (c.w - mu);
#pragma unroll
    for (int off = 1; off < 64; off <<= 1) vs += __shfl_xor(vs, off);
    const float rstd = rsqrtf(vs * (1.0f / 512.0f) + 1e-3f);
    const float4 g1 = *(const float4*)(g + lane * 4);
    const float4 g2 = *(const float4*)(g + 256 + lane * 4);
    const float4 b1 = *(const float4*)(bb + lane * 4);
    const float4 b2 = *(const float4*)(bb + 256 + lane * 4);
    float* y = out + (size_t)row * 512;
    const float4 o1 = {(a.x - mu) * rstd * g1.x + b1.x, (a.y - mu) * rstd * g1.y + b1.y,
                       (a.z - mu) * rstd * g1.z + b1.z, (a.w - mu) * rstd * g1.w + b1.w};
    const float4 o2 = {(c.x - mu) * rstd * g2.x + b2.x, (c.y - mu) * rstd * g2.y + b2.y,
                       (c.z - mu) * rstd * g2.z + b2.z, (c.w - mu) * rstd * g2.w + b2.w};
    *(float4*)(y + lane * 4) = o1;
    *(float4*)(y + 256 + lane * 4) = o2;
    if (outb) {
        unsigned short* yb = outb + (size_t)row * 512;
        const us4 p1 = {f2bf(o1.x), f2bf(o1.y), f2bf(o1.z), f2bf(o1.w)};
        const us4 p2 = {f2bf(o2.x), f2bf(o2.y), f2bf(o2.z), f2bf(o2.w)};
        *(us4*)(yb + lane * 4) = p1;
        *(us4*)(yb + 256 + lane * 4) = p2;
    }
}

// ---------------- persistent GRU, XCD-pinned: 8 WGs on ONE XCD -------------------------------
// Sync = r6 exact (proven fastest): syncthreads -> tid0 relaxed-agent arrive -> tid0
// relaxed-load poll -> syncthreads; RMW fallback.
// r10 change: CLEAN vmem queue at the poll. Per step, issue order (all inline asm):
//   A-loads(16, L2 sc0) -> xp(t+1) loads(12, HBM) -> gout(t-1) stores(4)
//   -> s_waitcnt vmcnt(16)  [in-order retirement => waits ONLY for the A-loads]
//   -> MFMA/gates/h-stores -> vmcnt(0) [all drained] -> barrier with empty queue.
// xp consumed one step later from regs (xn_ raw bits -> gates); gout lags one step.
__global__ __launch_bounds__(256, 1)
void gru_persist(const float* __restrict__ rk,      // gru_rk [512][1536] fp32
                 const unsigned short* __restrict__ xpb, // [8192][1536] bf16 (bias0 included)
                 const float* __restrict__ rb,      // recurrent bias [1536]
                 unsigned short* __restrict__ hbuf, // [2][16*512] bf16 (zeroed)
                 unsigned short* __restrict__ goutb,// [8192][512] bf16
                 unsigned int* __restrict__ bar,    // shared barrier counter (zeroed)
                 unsigned int* __restrict__ ctl)    // [16]: per-XCD rank + started (zeroed)
{
    __shared__ int sh_part, sh_memb;
    const int tid = threadIdx.x;

    if (tid == 0) {
        unsigned int xcc;
        asm("s_getreg_b32 %0, hwreg(HW_REG_XCC_ID)" : "=s"(xcc));
        xcc &= 7u;
        const unsigned int rank =
            __hip_atomic_fetch_add(&ctl[xcc], 1u, __ATOMIC_RELAXED, __HIP_MEMORY_SCOPE_AGENT);
        __hip_atomic_fetch_add(&ctl[8], 1u, __ATOMIC_ACQ_REL, __HIP_MEMORY_SCOPE_AGENT);
        unsigned int spins = 0;
        while (__hip_atomic_load(&ctl[8], __ATOMIC_ACQUIRE, __HIP_MEMORY_SCOPE_AGENT)
               < (unsigned)GRID_WGS) {
            __builtin_amdgcn_s_sleep(1);
            if (++spins > (1u << 20)) break;
        }
        unsigned int cnt[8];
#pragma unroll
        for (int i = 0; i < 8; ++i)
            cnt[i] = __hip_atomic_load(&ctl[i], __ATOMIC_ACQUIRE, __HIP_MEMORY_SCOPE_AGENT);
        int best = 0;
#pragma unroll
        for (int i = 1; i < 8; ++i)
            if (cnt[i] > cnt[best]) best = i;
        sh_part = (xcc == (unsigned)best && rank < 8u) ? 1 : 0;
        sh_memb = (int)rank;
    }
    __syncthreads();
    if (!sh_part) return;
    const int member = sh_memb;          // 0..7

    const int wv = tid >> 6, l = tid & 63;
    const int wgi = member * 4 + wv;     // global wave index 0..31
    const int lo16 = l & 15;
    const int hi4 = l >> 4;              // 0..3
    const int gc = wgi * 16 + lo16;      // this lane's output h-col

    // ---- preload B fragments: B[g][kt], lane slot j <-> k = kt*32 + hi4*8 + j
    bf16x8 B[3][16];
#pragma unroll
    for (int g = 0; g < 3; ++g)
#pragma unroll
        for (int kt = 0; kt < 16; ++kt) {
            bf16x8 bv;
#pragma unroll
            for (int j = 0; j < 8; ++j) {
                const int k = kt * 32 + hi4 * 8 + j;
                bv[j] = (short)f2bf(rk[(size_t)k * 1536 + g * 512 + gc]);
            }
            B[g][kt] = bv;
        }
    const float rbz = rb[gc], rbr = rb[512 + gc], rbh = rb[1024 + gc];
    float hst[4] = {0.f, 0.f, 0.f, 0.f};

    // current-step xp (floats) — prologue loads t=0 via plain C
    float xz[4], xr[4], xh[4];
#pragma unroll
    for (int j = 0; j < 4; ++j) {
        const unsigned short* xrow = xpb + ((size_t)((hi4 * 4 + j) * 512)) * 1536 + gc;
        xz[j] = bfbits2f(xrow[0]); xr[j] = bfbits2f(xrow[512]); xh[j] = bfbits2f(xrow[1024]);
    }
    unsigned int hnb[4] = {0u, 0u, 0u, 0u};   // previous-step hn as bf16 bits (t=0: zeros)

    // per-lane A base offsets within hbuf halves
    const unsigned short* ab0 = hbuf + lo16 * 512 + hi4 * 8;
    const unsigned short* ab1 = ab0 + 16 * 512;

    for (int t = 0; t < 512; ++t) {
        const unsigned short* abase = (t & 1) ? ab1 : ab0;
        unsigned short* hw = hbuf + (size_t)((t + 1) & 1) * (16 * 512);
        // ---- phase 1: A-loads (16 x dwordx4, sc0, offsets kt*64B)
        bf16x8 A[16];
        asm volatile(
            "global_load_dwordx4 %0,  %16, off sc0\n\t"
            "global_load_dwordx4 %1,  %16, off offset:64 sc0\n\t"
            "global_load_dwordx4 %2,  %16, off offset:128 sc0\n\t"
            "global_load_dwordx4 %3,  %16, off offset:192 sc0\n\t"
            "global_load_dwordx4 %4,  %16, off offset:256 sc0\n\t"
            "global_load_dwordx4 %5,  %16, off offset:320 sc0\n\t"
            "global_load_dwordx4 %6,  %16, off offset:384 sc0\n\t"
            "global_load_dwordx4 %7,  %16, off offset:448 sc0\n\t"
            "global_load_dwordx4 %8,  %16, off offset:512 sc0\n\t"
            "global_load_dwordx4 %9,  %16, off offset:576 sc0\n\t"
            "global_load_dwordx4 %10, %16, off offset:640 sc0\n\t"
            "global_load_dwordx4 %11, %16, off offset:704 sc0\n\t"
            "global_load_dwordx4 %12, %16, off offset:768 sc0\n\t"
            "global_load_dwordx4 %13, %16, off offset:832 sc0\n\t"
            "global_load_dwordx4 %14, %16, off offset:896 sc0\n\t"
            "global_load_dwordx4 %15, %16, off offset:960 sc0"
            : "=&v"(A[0]), "=&v"(A[1]), "=&v"(A[2]), "=&v"(A[3]),
              "=&v"(A[4]), "=&v"(A[5]), "=&v"(A[6]), "=&v"(A[7]),
              "=&v"(A[8]), "=&v"(A[9]), "=&v"(A[10]), "=&v"(A[11]),
              "=&v"(A[12]), "=&v"(A[13]), "=&v"(A[14]), "=&v"(A[15])
            : "v"(abase) : "memory");
        // ---- phase 2: xp(t+1) prefetch (12 ushort; t=511 reads junk, unused)
        unsigned int xnz[4], xnr[4], xnh[4];
        {
            const unsigned short* x0 = xpb + ((size_t)((hi4 * 4 + 0) * 512 + t + 1)) * 1536 + gc;
            const unsigned short* x1 = xpb + ((size_t)((hi4 * 4 + 1) * 512 + t + 1)) * 1536 + gc;
            const unsigned short* x2 = xpb + ((size_t)((hi4 * 4 + 2) * 512 + t + 1)) * 1536 + gc;
            const unsigned short* x3 = xpb + ((size_t)((hi4 * 4 + 3) * 512 + t + 1)) * 1536 + gc;
            asm volatile(
                "global_load_ushort %0,  %12, off\n\t"
                "global_load_ushort %1,  %12, off offset:1024\n\t"
                "global_load_ushort %2,  %12, off offset:2048\n\t"
                "global_load_ushort %3,  %13, off\n\t"
                "global_load_ushort %4,  %13, off offset:1024\n\t"
                "global_load_ushort %5,  %13, off offset:2048\n\t"
                "global_load_ushort %6,  %14, off\n\t"
                "global_load_ushort %7,  %14, off offset:1024\n\t"
                "global_load_ushort %8,  %14, off offset:2048\n\t"
                "global_load_ushort %9,  %15, off\n\t"
                "global_load_ushort %10, %15, off offset:1024\n\t"
                "global_load_ushort %11, %15, off offset:2048"
                : "=&v"(xnz[0]), "=&v"(xnr[0]), "=&v"(xnh[0]),
                  "=&v"(xnz[1]), "=&v"(xnr[1]), "=&v"(xnh[1]),
                  "=&v"(xnz[2]), "=&v"(xnr[2]), "=&v"(xnh[2]),
                  "=&v"(xnz[3]), "=&v"(xnr[3]), "=&v"(xnh[3])
                : "v"(x0), "v"(x1), "v"(x2), "v"(x3) : "memory");
        }
        // ---- phase 3: gout stores of hn(t-1) (t=0: zeros to row 0, overwritten at t=1)
        {
            const int grow = t ? t - 1 : 0;
            unsigned short* g0 = goutb + ((size_t)((hi4 * 4 + 0) * 512 + grow)) * 512 + gc;
            unsigned short* g1 = goutb + ((size_t)((hi4 * 4 + 1) * 512 + grow)) * 512 + gc;
            unsigned short* g2 = goutb + ((size_t)((hi4 * 4 + 2) * 512 + grow)) * 512 + gc;
            unsigned short* g3 = goutb + ((size_t)((hi4 * 4 + 3) * 512 + grow)) * 512 + gc;
            asm volatile(
                "global_store_short %0, %4, off\n\t"
                "global_store_short %1, %5, off\n\t"
                "global_store_short %2, %6, off\n\t"
                "global_store_short %3, %7, off"
                :: "v"(g0), "v"(g1), "v"(g2), "v"(g3),
                   "v"(hnb[0]), "v"(hnb[1]), "v"(hnb[2]), "v"(hnb[3]) : "memory");
        }
        // ---- phase 4: wait ONLY for the 16 A-loads (xp 12 + gout 4 = 16 still outstanding)
        asm volatile("s_waitcnt vmcnt(16)" ::: "memory");
        __builtin_amdgcn_sched_barrier(0);

        // ---- phase 5: MFMA
        f32x4 accz = {0.f, 0.f, 0.f, 0.f};
        f32x4 accr = {0.f, 0.f, 0.f, 0.f};
        f32x4 acch = {0.f, 0.f, 0.f, 0.f};
#pragma unroll
        for (int kt = 0; kt < 16; ++kt) {
            accz = __builtin_amdgcn_mfma_f32_16x16x32_bf16(A[kt], B[0][kt], accz, 0, 0, 0);
            accr = __builtin_amdgcn_mfma_f32_16x16x32_bf16(A[kt], B[1][kt], accr, 0, 0, 0);
            acch = __builtin_amdgcn_mfma_f32_16x16x32_bf16(A[kt], B[2][kt], acch, 0, 0, 0);
        }
        // ---- phase 6: gates + state update + h stores
#pragma unroll
        for (int j = 0; j < 4; ++j) {
            const int b = hi4 * 4 + j;
            const float z = sigmoidf_(xz[j] + accz[j] + rbz);
            const float r = sigmoidf_(xr[j] + accr[j] + rbr);
            const float hh = fmaxf(xh[j] + r * (acch[j] + rbh), 0.f);
            const float hnew = z * hst[j] + (1.f - z) * hh;
            hst[j] = hnew;
            const unsigned short hb = f2bf(hnew);
            hnb[j] = (unsigned int)hb;
            hw[b * 512 + gc] = hb;           // plain store -> shared XCD L2
        }
        // ---- phase 7: drain everything (h stores + xp + gout)
        asm volatile("s_waitcnt vmcnt(0)" ::: "memory");
        __builtin_amdgcn_sched_barrier(0);
        // ---- phase 8: rotate xp regs (bits -> floats for next step's gates)
#pragma unroll
        for (int j = 0; j < 4; ++j) {
            xz[j] = bfbits2f(xnz[j]); xr[j] = bfbits2f(xnr[j]); xh[j] = bfbits2f(xnh[j]);
        }
        // ---- phase 9: barrier (clean vmem queue)
        if (t < 511) {
            __syncthreads();
            if (tid == 0) {
                __hip_atomic_fetch_add(bar, 1u, __ATOMIC_RELAXED, __HIP_MEMORY_SCOPE_AGENT);
                const unsigned int target = 8u * (unsigned int)(t + 1);
                unsigned int it = 0;
                while (__hip_atomic_load(bar, __ATOMIC_RELAXED, __HIP_MEMORY_SCOPE_AGENT)
                       < target) {
                    if (++it > (1u << 14)) break;
                }
                if (it > (1u << 14)) {
                    unsigned int cur = 0, it2 = 0;
                    do {
                        asm volatile("global_atomic_add %0, %1, %2, off sc0\n\t"
                                     "s_waitcnt vmcnt(0)"
                                     : "=v"(cur) : "v"(bar), "v"(0u) : "memory");
                        if (++it2 > (1u << 15)) break;
                    } while (cur < target);
                }
            }
            __syncthreads();
        }
    }
    // tail: gout row 511
#pragma unroll
    for (int j = 0; j < 4; ++j)
        goutb[((size_t)((hi4 * 4 + j) * 512 + 511)) * 512 + gc] = (unsigned short)hnb[j];
}

extern "C" void kernel_launch(void* const* d_in, const int* in_sizes, int n_in,
                              void* d_out, int out_size, void* d_ws, size_t ws_size,
                              hipStream_t stream)
{
    const float* x     = (const float*)d_in[0];
    const float* Wq    = (const float*)d_in[1];
    const float* bq    = (const float*)d_in[2];
    const float* Wk    = (const float*)d_in[3];
    const float* bk    = (const float*)d_in[4];
    const float* Wv    = (const float*)d_in[5];
    const float* bv    = (const float*)d_in[6];
    const float* Wo    = (const float*)d_in[7];
    const float* bo    = (const float*)d_in[8];
    const float* ln1g  = (const float*)d_in[9];
    const float* ln1b  = (const float*)d_in[10];
    const float* gruk  = (const float*)d_in[11];
    const float* grurk = (const float*)d_in[12];
    const float* grub  = (const float*)d_in[13];
    const float* Wd    = (const float*)d_in[14];
    const float* bd    = (const float*)d_in[15];
    const float* ln2g  = (const float*)d_in[16];
    const float* ln2b  = (const float*)d_in[17];
    float* out = (float*)d_out;

    char* base = (char*)d_ws;
    const size_t MB = 1024 * 1024;
    float*          Q0   = (float*)base;                      // 48 MB: qkv -> xpb/dout
    float*          R4   = (float*)(base + 48 * MB);          // 16 MB: x1
    unsigned short* S1   = (unsigned short*)(base + 64 * MB); // 8 MB: xb -> ctxb -> x1b -> goutb
    unsigned short* WT   = (unsigned short*)(base + 72 * MB); // 4 MB weights (wqkv|wo|gk|wd)
    unsigned short* wqkvT = WT;                 // [1536][512] = wq|wk|wv stacked
    unsigned short* woT  = WT + 768 * 1024;
    unsigned short* gkT  = WT + 1024 * 1024;    // 1536x512
    unsigned short* wdT  = WT + 1792 * 1024;
    unsigned short* hbuf = (unsigned short*)(base + 76 * MB); // 2*16*512 bf16 = 32 KB
    char*           Z    = base + 76 * MB + 64 * 1024;        // zeroed control zone (8 KB)
    unsigned int*   ctl  = (unsigned int*)(Z);                // 16 u32
    unsigned int*   bar  = (unsigned int*)(Z + 256);          // shared barrier counter
    float*          bqkv = (float*)(base + 77 * MB);          // 1536 floats

    float* qkvf = Q0;                              // 8192x1536 f32 = 48 MB
    unsigned short* xpb = (unsigned short*)Q0;     // 8192x1536 bf16 = 24 MB (after qkv dead)
    float* dout  = (float*)(base + 24 * MB);       // 8192x512 f32 (after qkv dead)

    const dim3 blk(256);
    const dim3 g512(8192 / 128, 512 / 128);
    const dim3 g1536(8192 / 128, 1536 / 128);

    f2bf_kernel<<<dim3(4096), blk, 0, stream>>>(x, S1);
    concat3<<<dim3(6), blk, 0, stream>>>(bq, bk, bv, bqkv);
    transpose_bf16<<<dim3(16, 16), blk, 0, stream>>>(Wq, wqkvT, 512, 512);
    transpose_bf16<<<dim3(16, 16), blk, 0, stream>>>(Wk, wqkvT + 256 * 1024, 512, 512);
    transpose_bf16<<<dim3(16, 16), blk, 0, stream>>>(Wv, wqkvT + 512 * 1024, 512, 512);
    transpose_bf16<<<dim3(16, 16), blk, 0, stream>>>(Wo, woT, 512, 512);
    transpose_bf16<<<dim3(48, 16), blk, 0, stream>>>(gruk, gkT, 512, 1536);
    transpose_bf16<<<dim3(16, 16), blk, 0, stream>>>(Wd, wdT, 512, 512);
    // fused QKV projection: [8192][1536] f32
    gemm_bf16<<<g1536, blk, 0, stream>>>(S1, wqkvT, bqkv, nullptr, qkvf, nullptr, 8192, 1536, 512);
    attn_f32<<<dim3(1024), blk, 0, stream>>>(qkvf, S1);
    gemm_bf16<<<g512, blk, 0, stream>>>(S1, woT, bo, x, R4, nullptr, 8192, 512, 512);
    ln_f32<<<dim3(2048), blk, 0, stream>>>(R4, R4, ln1g, ln1b, S1);
    // xp = x1 @ gru_k + gru_b[0], bf16-only output
    gemm_bf16<<<g1536, blk, 0, stream>>>(S1, gkT, grub, nullptr, nullptr, xpb, 8192, 1536, 512);
    // persistent GRU (XCD-pinned, clean-queue barrier)
    hipMemsetAsync(hbuf, 0, 2 * 16 * 512 * sizeof(unsigned short), stream);
    hipMemsetAsync(Z, 0, 8192, stream);
    gru_persist<<<dim3(GRID_WGS), blk, 0, stream>>>(grurk, xpb, grub + 1536, hbuf, S1, bar, ctl);
    gemm_bf16<<<g512, blk, 0, stream>>>(S1, wdT, bd, R4, dout, nullptr, 8192, 512, 512);
    ln_f32<<<dim3(2048), blk, 0, stream>>>(dout, out, ln2g, ln2b, nullptr);
}

// Round 11
// 2333.239 us; speedup vs baseline: 2166.2965x; 1.0563x over previous
//
#include <hip/hip_runtime.h>
#include <math.h>

// B=16, T=512, F=512, H=8, D=64; rows = B*T = 8192
#define GRID_WGS 128   // launched WGs for GRU; 8 elected (same XCD) participate

typedef __attribute__((ext_vector_type(8))) short bf16x8;
typedef __attribute__((ext_vector_type(4))) float f32x4;
typedef __attribute__((ext_vector_type(4))) unsigned short us4;

static __device__ __forceinline__ float sigmoidf_(float x) {
    return 1.0f / (1.0f + __expf(-x));
}
static __device__ __forceinline__ unsigned short f2bf(float f) {
    unsigned int u = __float_as_uint(f);
    u += 0x7fffu + ((u >> 16) & 1u);
    return (unsigned short)(u >> 16);
}
static __device__ __forceinline__ float bfbits2f(unsigned int b) {
    return __uint_as_float(b << 16);
}
static __device__ __forceinline__ void gload_lds16(const void* g, void* l) {
    __builtin_amdgcn_global_load_lds(
        (const __attribute__((address_space(1))) unsigned int*)g,
        (__attribute__((address_space(3))) unsigned int*)l, 16, 0, 0);
}

// ---------------- prep: f2bf(x) + bias concat + 6 weight transposes + zero hbuf/Z -------------
// grid = 4096 (f2bf) + 6 (concat) + 2048 (transpose tiles) + 2 (zeroing) = 6152 blocks
__global__ __launch_bounds__(256)
void prep(const float* __restrict__ x, unsigned short* __restrict__ xb,
          const float* __restrict__ bq, const float* __restrict__ bk,
          const float* __restrict__ bv, float* __restrict__ bqkv,
          const float* __restrict__ Wq, const float* __restrict__ Wk,
          const float* __restrict__ Wv, const float* __restrict__ Wo,
          const float* __restrict__ gruk, const float* __restrict__ Wd,
          unsigned short* __restrict__ wqkvT, unsigned short* __restrict__ woT,
          unsigned short* __restrict__ gkT, unsigned short* __restrict__ wdT,
          unsigned int* __restrict__ hbufz, unsigned int* __restrict__ Z)
{
    __shared__ float tile[32][33];
    const int bid = blockIdx.x, tid = threadIdx.x;
    if (bid < 4096) {
        const int i = (bid * 256 + tid) * 4;
        const float4 v = *(const float4*)(x + i);
        const us4 o = {f2bf(v.x), f2bf(v.y), f2bf(v.z), f2bf(v.w)};
        *(us4*)(xb + i) = o;
    } else if (bid < 4102) {
        const int i = (bid - 4096) * 256 + tid;
        bqkv[i] = (i < 512) ? bq[i] : ((i < 1024) ? bk[i - 512] : bv[i - 1024]);
    } else if (bid < 6150) {
        int t = bid - 4102;
        const float* in; unsigned short* out; int N;
        if      (t < 256)  { in = Wq;   out = wqkvT;               N = 512;  }
        else if (t < 512)  { in = Wk;   out = wqkvT + 256 * 1024;  N = 512;  t -= 256;  }
        else if (t < 768)  { in = Wv;   out = wqkvT + 512 * 1024;  N = 512;  t -= 512;  }
        else if (t < 1024) { in = Wo;   out = woT;                 N = 512;  t -= 768;  }
        else if (t < 1792) { in = gruk; out = gkT;                 N = 1536; t -= 1024; }
        else               { in = Wd;   out = wdT;                 N = 512;  t -= 1792; }
        const int tilesx = N / 32;
        const int n0 = (t % tilesx) * 32, k0 = (t / tilesx) * 32;
        const int c = tid & 31, r8 = tid >> 5;
#pragma unroll
        for (int i = 0; i < 4; ++i) {
            const int k = r8 + i * 8;
            tile[k][c] = in[(size_t)(k0 + k) * N + n0 + c];
        }
        __syncthreads();
#pragma unroll
        for (int i = 0; i < 4; ++i) {
            const int n = r8 + i * 8;
            out[(size_t)(n0 + n) * 512 + k0 + c] = f2bf(tile[c][n]);
        }
    } else if (bid == 6150) {
        for (int i = tid; i < 8192; i += 256) hbufz[i] = 0u;   // 32 KB hbuf
    } else {
        for (int i = tid; i < 2048; i += 256) Z[i] = 0u;       // 8 KB ctl/bar zone
    }
}

// ---------------- bf16 MFMA GEMM: C=A@Bt (+bias)(+resid); f32 C and/or bf16 Cb outputs --------
__global__ __launch_bounds__(256)
void gemm_bf16(const unsigned short* __restrict__ A, const unsigned short* __restrict__ Bt,
               const float* __restrict__ bias, const float* __restrict__ resid,
               float* __restrict__ C, unsigned short* __restrict__ Cb,
               int M, int N, int K)
{
    __shared__ unsigned short As[128 * 64];
    __shared__ unsigned short Bs[128 * 64];
    const int tid = threadIdx.x;
    const int wave = tid >> 6, lane = tid & 63;
    const int bm = blockIdx.x * 128, bn = blockIdx.y * 128;
    const int wr = wave >> 1, wc = wave & 1;
    const int stR = lane >> 3;
    const int stC = (lane & 7) * 8;

    const unsigned short* Abase = A + (size_t)(bm + wave * 32 + stR) * K + stC;
    const unsigned short* Bbase = Bt + (size_t)(bn + wave * 32 + stR) * K + stC;
    unsigned short* AsW = As + wave * 2048;
    unsigned short* BsW = Bs + wave * 2048;

    f32x4 acc[4][4] = {};
    const int fr = lane & 15;
    const int fko = (lane >> 4) * 8;

    for (int k0 = 0; k0 < K; k0 += 64) {
#pragma unroll
        for (int i = 0; i < 4; ++i) {
            gload_lds16(Abase + (size_t)i * 8 * K + k0, AsW + i * 512);
            gload_lds16(Bbase + (size_t)i * 8 * K + k0, BsW + i * 512);
        }
        __syncthreads();
        bf16x8 af[4][2], bfr[4][2];
#pragma unroll
        for (int m = 0; m < 4; ++m) {
            const unsigned short* ap = As + (wr * 64 + m * 16 + fr) * 64 + fko;
            af[m][0] = *(const bf16x8*)(ap);
            af[m][1] = *(const bf16x8*)(ap + 32);
        }
#pragma unroll
        for (int n = 0; n < 4; ++n) {
            const unsigned short* bp = Bs + (wc * 64 + n * 16 + fr) * 64 + fko;
            bfr[n][0] = *(const bf16x8*)(bp);
            bfr[n][1] = *(const bf16x8*)(bp + 32);
        }
#pragma unroll
        for (int m = 0; m < 4; ++m)
#pragma unroll
            for (int n = 0; n < 4; ++n) {
                acc[m][n] = __builtin_amdgcn_mfma_f32_16x16x32_bf16(af[m][0], bfr[n][0], acc[m][n], 0, 0, 0);
                acc[m][n] = __builtin_amdgcn_mfma_f32_16x16x32_bf16(af[m][1], bfr[n][1], acc[m][n], 0, 0, 0);
            }
        __syncthreads();
    }
    const int fq = lane >> 4;
#pragma unroll
    for (int n = 0; n < 4; ++n) {
        const int col = bn + wc * 64 + n * 16 + fr;
        const float bv = bias ? bias[col] : 0.f;
#pragma unroll
        for (int m = 0; m < 4; ++m) {
#pragma unroll
            for (int j = 0; j < 4; ++j) {
                const int row = bm + wr * 64 + m * 16 + fq * 4 + j;
                float v = acc[m][n][j] + bv;
                if (resid) v += resid[(size_t)row * N + col];
                if (C)  C[(size_t)row * N + col] = v;
                if (Cb) Cb[(size_t)row * N + col] = f2bf(v);
            }
        }
    }
}

// ---------------- fused attention per (b, h, 64-row q tile); bf16 qkv in (stride 1536) --------
__global__ __launch_bounds__(256)
void attn_bf16(const unsigned short* __restrict__ qkv, unsigned short* __restrict__ ctxb)
{
    __shared__ float S[64][512];
    __shared__ float KV[64][68];
    const int tid = threadIdx.x;
    const int wg = blockIdx.x;
    const int qt = wg & 7, h = (wg >> 3) & 7, b = wg >> 6;
    const int r = tid >> 2, quad = tid & 3;
    const int t0 = qt * 64;

    float4 qreg[16];
    {
        const unsigned short* qrow = qkv + ((size_t)(b * 512 + t0 + r) * 1536) + h * 64;
#pragma unroll
        for (int i = 0; i < 8; ++i) {
            const bf16x8 v = *(const bf16x8*)(qrow + i * 8);
            qreg[2 * i] = {bfbits2f((unsigned short)v[0]) * 0.125f,
                           bfbits2f((unsigned short)v[1]) * 0.125f,
                           bfbits2f((unsigned short)v[2]) * 0.125f,
                           bfbits2f((unsigned short)v[3]) * 0.125f};
            qreg[2 * i + 1] = {bfbits2f((unsigned short)v[4]) * 0.125f,
                               bfbits2f((unsigned short)v[5]) * 0.125f,
                               bfbits2f((unsigned short)v[6]) * 0.125f,
                               bfbits2f((unsigned short)v[7]) * 0.125f};
        }
    }
    for (int st = 0; st < 8; ++st) {
        {
            const int s = tid >> 2, d0 = quad * 16;
            const unsigned short* krow =
                qkv + ((size_t)(b * 512 + st * 64 + s) * 1536) + 512 + h * 64 + d0;
            const bf16x8 v0 = *(const bf16x8*)(krow);
            const bf16x8 v1 = *(const bf16x8*)(krow + 8);
#pragma unroll
            for (int e = 0; e < 8; ++e) {
                KV[s][d0 + e] = bfbits2f((unsigned short)v0[e]);
                KV[s][d0 + 8 + e] = bfbits2f((unsigned short)v1[e]);
            }
        }
        __syncthreads();
        const int sbase = quad * 16;
#pragma unroll 4
        for (int sp = 0; sp < 16; ++sp) {
            const int s = sbase + sp;
            float accd = 0.f;
#pragma unroll
            for (int kk = 0; kk < 16; ++kk) {
                const float4 kv = *(const float4*)&KV[s][kk * 4];
                accd += qreg[kk].x * kv.x + qreg[kk].y * kv.y +
                        qreg[kk].z * kv.z + qreg[kk].w * kv.w;
            }
            S[r][st * 64 + s] = accd;
        }
        __syncthreads();
    }
    const int c0 = quad * 128;
    float mx = -1e30f;
    for (int c4 = 0; c4 < 32; ++c4) {
        const float4 sv = *(const float4*)&S[r][c0 + c4 * 4];
        mx = fmaxf(mx, fmaxf(fmaxf(sv.x, sv.y), fmaxf(sv.z, sv.w)));
    }
    mx = fmaxf(mx, __shfl_xor(mx, 1));
    mx = fmaxf(mx, __shfl_xor(mx, 2));
    float sum = 0.f;
    for (int c4 = 0; c4 < 32; ++c4) {
        float4 sv = *(const float4*)&S[r][c0 + c4 * 4];
        sv.x = __expf(sv.x - mx); sv.y = __expf(sv.y - mx);
        sv.z = __expf(sv.z - mx); sv.w = __expf(sv.w - mx);
        sum += sv.x + sv.y + sv.z + sv.w;
        *(float4*)&S[r][c0 + c4 * 4] = sv;
    }
    sum += __shfl_xor(sum, 1);
    sum += __shfl_xor(sum, 2);
    const float inv = 1.0f / sum;
    __syncthreads();
    float o[16] = {};
    const int d0 = quad * 16;
    for (int st = 0; st < 8; ++st) {
        {
            const int s = tid >> 2;
            const unsigned short* vrow =
                qkv + ((size_t)(b * 512 + st * 64 + s) * 1536) + 1024 + h * 64 + d0;
            const bf16x8 v0 = *(const bf16x8*)(vrow);
            const bf16x8 v1 = *(const bf16x8*)(vrow + 8);
#pragma unroll
            for (int e = 0; e < 8; ++e) {
                KV[s][d0 + e] = bfbits2f((unsigned short)v0[e]);
                KV[s][d0 + 8 + e] = bfbits2f((unsigned short)v1[e]);
            }
        }
        __syncthreads();
        for (int s4 = 0; s4 < 16; ++s4) {
            const float4 p = *(const float4*)&S[r][st * 64 + s4 * 4];
            const float pv[4] = {p.x, p.y, p.z, p.w};
#pragma unroll
            for (int jj = 0; jj < 4; ++jj) {
                const int s = s4 * 4 + jj;
#pragma unroll
                for (int i = 0; i < 4; ++i) {
                    const float4 vv = *(const float4*)&KV[s][d0 + i * 4];
                    o[i * 4 + 0] = fmaf(pv[jj], vv.x, o[i * 4 + 0]);
                    o[i * 4 + 1] = fmaf(pv[jj], vv.y, o[i * 4 + 1]);
                    o[i * 4 + 2] = fmaf(pv[jj], vv.z, o[i * 4 + 2]);
                    o[i * 4 + 3] = fmaf(pv[jj], vv.w, o[i * 4 + 3]);
                }
            }
        }
        __syncthreads();
    }
    unsigned short* crow = ctxb + ((size_t)(b * 512 + t0 + r) * 512) + h * 64 + d0;
#pragma unroll
    for (int i = 0; i < 4; ++i) {
        const us4 t = {f2bf(o[i * 4 + 0] * inv), f2bf(o[i * 4 + 1] * inv),
                       f2bf(o[i * 4 + 2] * inv), f2bf(o[i * 4 + 3] * inv)};
        *(us4*)(crow + i * 4) = t;
    }
}

// ---------------- layernorm (rows of 512), optional bf16 side output --------------------------
__global__ __launch_bounds__(256)
void ln_f32(const float* __restrict__ in, float* __restrict__ out,
            const float* __restrict__ g, const float* __restrict__ bb,
            unsigned short* __restrict__ outb)
{
    const int lane = threadIdx.x & 63;
    const int row = blockIdx.x * 4 + (threadIdx.x >> 6);
    const float* x = in + (size_t)row * 512;
    const float4 a = *(const float4*)(x + lane * 4);
    const float4 c = *(const float4*)(x + 256 + lane * 4);
    float s = a.x + a.y + a.z + a.w + c.x + c.y + c.z + c.w;
#pragma unroll
    for (int off = 1; off < 64; off <<= 1) s += __shfl_xor(s, off);
    const float mu = s * (1.0f / 512.0f);
    float vs = 0.f;
    vs += (a.x - mu) * (a.x - mu) + (a.y - mu) * (a.y - mu);
    vs += (a.z - mu) * (a.z - mu) + (a.w - mu) * (a.w - mu);
    vs += (c.x - mu) * (c.x - mu) + (c.y - mu) * (c.y - mu);
    vs += (c.z - mu) * (c.z - mu) + (c.w - mu) * (c.w - mu);
#pragma unroll
    for (int off = 1; off < 64; off <<= 1) vs += __shfl_xor(vs, off);
    const float rstd = rsqrtf(vs * (1.0f / 512.0f) + 1e-3f);
    const float4 g1 = *(const float4*)(g + lane * 4);
    const float4 g2 = *(const float4*)(g + 256 + lane * 4);
    const float4 b1 = *(const float4*)(bb + lane * 4);
    const float4 b2 = *(const float4*)(bb + 256 + lane * 4);
    float* y = out + (size_t)row * 512;
    const float4 o1 = {(a.x - mu) * rstd * g1.x + b1.x, (a.y - mu) * rstd * g1.y + b1.y,
                       (a.z - mu) * rstd * g1.z + b1.z, (a.w - mu) * rstd * g1.w + b1.w};
    const float4 o2 = {(c.x - mu) * rstd * g2.x + b2.x, (c.y - mu) * rstd * g2.y + b2.y,
                       (c.z - mu) * rstd * g2.z + b2.z, (c.w - mu) * rstd * g2.w + b2.w};
    *(float4*)(y + lane * 4) = o1;
    *(float4*)(y + 256 + lane * 4) = o2;
    if (outb) {
        unsigned short* yb = outb + (size_t)row * 512;
        const us4 p1 = {f2bf(o1.x), f2bf(o1.y), f2bf(o1.z), f2bf(o1.w)};
        const us4 p2 = {f2bf(o2.x), f2bf(o2.y), f2bf(o2.z), f2bf(o2.w)};
        *(us4*)(yb + lane * 4) = p1;
        *(us4*)(yb + 256 + lane * 4) = p2;
    }
}

// ---------------- persistent GRU, XCD-pinned: 8 WGs on ONE XCD -------------------------------
// Sync = r6/r10 (proven floor ~3.2us/step). r11 change: xp(t+1) issues AFTER the store drain,
// so its HBM latency hides entirely under the barrier wait; consumed from regs next step.
// Step order: A-loads -> vmcnt(0) [A + prior xp, already done] -> rotate xp bits -> MFMA ->
// gates + h/gout stores -> vmcnt(0) [stores] -> issue xp(t+1) -> barrier.
__global__ __launch_bounds__(256, 1)
void gru_persist(const float* __restrict__ rk,      // gru_rk [512][1536] fp32
                 const unsigned short* __restrict__ xpb, // [8192][1536] bf16 (bias0 included)
                 const float* __restrict__ rb,      // recurrent bias [1536]
                 unsigned short* __restrict__ hbuf, // [2][16*512] bf16 (zeroed)
                 unsigned short* __restrict__ goutb,// [8192][512] bf16
                 unsigned int* __restrict__ bar,    // shared barrier counter (zeroed)
                 unsigned int* __restrict__ ctl)    // [16]: per-XCD rank + started (zeroed)
{
    __shared__ int sh_part, sh_memb;
    const int tid = threadIdx.x;

    if (tid == 0) {
        unsigned int xcc;
        asm("s_getreg_b32 %0, hwreg(HW_REG_XCC_ID)" : "=s"(xcc));
        xcc &= 7u;
        const unsigned int rank =
            __hip_atomic_fetch_add(&ctl[xcc], 1u, __ATOMIC_RELAXED, __HIP_MEMORY_SCOPE_AGENT);
        __hip_atomic_fetch_add(&ctl[8], 1u, __ATOMIC_ACQ_REL, __HIP_MEMORY_SCOPE_AGENT);
        unsigned int spins = 0;
        while (__hip_atomic_load(&ctl[8], __ATOMIC_ACQUIRE, __HIP_MEMORY_SCOPE_AGENT)
               < (unsigned)GRID_WGS) {
            __builtin_amdgcn_s_sleep(1);
            if (++spins > (1u << 20)) break;
        }
        unsigned int cnt[8];
#pragma unroll
        for (int i = 0; i < 8; ++i)
            cnt[i] = __hip_atomic_load(&ctl[i], __ATOMIC_ACQUIRE, __HIP_MEMORY_SCOPE_AGENT);
        int best = 0;
#pragma unroll
        for (int i = 1; i < 8; ++i)
            if (cnt[i] > cnt[best]) best = i;
        sh_part = (xcc == (unsigned)best && rank < 8u) ? 1 : 0;
        sh_memb = (int)rank;
    }
    __syncthreads();
    if (!sh_part) return;
    const int member = sh_memb;          // 0..7

    const int wv = tid >> 6, l = tid & 63;
    const int wgi = member * 4 + wv;     // global wave index 0..31
    const int lo16 = l & 15;
    const int hi4 = l >> 4;              // 0..3
    const int gc = wgi * 16 + lo16;      // this lane's output h-col

    // ---- preload B fragments: B[g][kt], lane slot j <-> k = kt*32 + hi4*8 + j
    bf16x8 B[3][16];
#pragma unroll
    for (int g = 0; g < 3; ++g)
#pragma unroll
        for (int kt = 0; kt < 16; ++kt) {
            bf16x8 bv;
#pragma unroll
            for (int j = 0; j < 8; ++j) {
                const int k = kt * 32 + hi4 * 8 + j;
                bv[j] = (short)f2bf(rk[(size_t)k * 1536 + g * 512 + gc]);
            }
            B[g][kt] = bv;
        }
    const float rbz = rb[gc], rbr = rb[512 + gc], rbh = rb[1024 + gc];
    float hst[4] = {0.f, 0.f, 0.f, 0.f};

    // xp bits double-buffer: prologue fills with xp(0) via plain loads
    unsigned int xnz[4], xnr[4], xnh[4];
#pragma unroll
    for (int j = 0; j < 4; ++j) {
        const unsigned short* xrow = xpb + ((size_t)((hi4 * 4 + j) * 512)) * 1536 + gc;
        xnz[j] = xrow[0]; xnr[j] = xrow[512]; xnh[j] = xrow[1024];
    }

    const unsigned short* ab0 = hbuf + lo16 * 512 + hi4 * 8;
    const unsigned short* ab1 = ab0 + 16 * 512;

    for (int t = 0; t < 512; ++t) {
        const unsigned short* abase = (t & 1) ? ab1 : ab0;
        unsigned short* hw = hbuf + (size_t)((t + 1) & 1) * (16 * 512);
        // ---- A-loads (16 x dwordx4, sc0, offsets kt*64B)
        bf16x8 A[16];
        asm volatile(
            "global_load_dwordx4 %0,  %16, off sc0\n\t"
            "global_load_dwordx4 %1,  %16, off offset:64 sc0\n\t"
            "global_load_dwordx4 %2,  %16, off offset:128 sc0\n\t"
            "global_load_dwordx4 %3,  %16, off offset:192 sc0\n\t"
            "global_load_dwordx4 %4,  %16, off offset:256 sc0\n\t"
            "global_load_dwordx4 %5,  %16, off offset:320 sc0\n\t"
            "global_load_dwordx4 %6,  %16, off offset:384 sc0\n\t"
            "global_load_dwordx4 %7,  %16, off offset:448 sc0\n\t"
            "global_load_dwordx4 %8,  %16, off offset:512 sc0\n\t"
            "global_load_dwordx4 %9,  %16, off offset:576 sc0\n\t"
            "global_load_dwordx4 %10, %16, off offset:640 sc0\n\t"
            "global_load_dwordx4 %11, %16, off offset:704 sc0\n\t"
            "global_load_dwordx4 %12, %16, off offset:768 sc0\n\t"
            "global_load_dwordx4 %13, %16, off offset:832 sc0\n\t"
            "global_load_dwordx4 %14, %16, off offset:896 sc0\n\t"
            "global_load_dwordx4 %15, %16, off offset:960 sc0"
            : "=&v"(A[0]), "=&v"(A[1]), "=&v"(A[2]), "=&v"(A[3]),
              "=&v"(A[4]), "=&v"(A[5]), "=&v"(A[6]), "=&v"(A[7]),
              "=&v"(A[8]), "=&v"(A[9]), "=&v"(A[10]), "=&v"(A[11]),
              "=&v"(A[12]), "=&v"(A[13]), "=&v"(A[14]), "=&v"(A[15])
            : "v"(abase) : "memory");
        // ---- wait: prior-step xp loads (done during barrier) + A loads (L2)
        asm volatile("s_waitcnt vmcnt(0)" ::: "memory");
        __builtin_amdgcn_sched_barrier(0);
        // rotate xp bits -> floats for this step's gates
        float xz[4], xr[4], xh[4];
#pragma unroll
        for (int j = 0; j < 4; ++j) {
            xz[j] = bfbits2f(xnz[j]); xr[j] = bfbits2f(xnr[j]); xh[j] = bfbits2f(xnh[j]);
        }
        // ---- MFMA
        f32x4 accz = {0.f, 0.f, 0.f, 0.f};
        f32x4 accr = {0.f, 0.f, 0.f, 0.f};
        f32x4 acch = {0.f, 0.f, 0.f, 0.f};
#pragma unroll
        for (int kt = 0; kt < 16; ++kt) {
            accz = __builtin_amdgcn_mfma_f32_16x16x32_bf16(A[kt], B[0][kt], accz, 0, 0, 0);
            accr = __builtin_amdgcn_mfma_f32_16x16x32_bf16(A[kt], B[1][kt], accr, 0, 0, 0);
            acch = __builtin_amdgcn_mfma_f32_16x16x32_bf16(A[kt], B[2][kt], acch, 0, 0, 0);
        }
        // ---- gates + state update + h/gout stores
#pragma unroll
        for (int j = 0; j < 4; ++j) {
            const int b = hi4 * 4 + j;
            const float z = sigmoidf_(xz[j] + accz[j] + rbz);
            const float r = sigmoidf_(xr[j] + accr[j] + rbr);
            const float hh = fmaxf(xh[j] + r * (acch[j] + rbh), 0.f);
            const float hnew = z * hst[j] + (1.f - z) * hh;
            hst[j] = hnew;
            const unsigned short hb = f2bf(hnew);
            hw[b * 512 + gc] = hb;                                  // -> shared XCD L2
            goutb[((size_t)(b * 512 + t)) * 512 + gc] = hb;
        }
        // ---- drain stores
        asm volatile("s_waitcnt vmcnt(0)" ::: "memory");
        __builtin_amdgcn_sched_barrier(0);
        if (t < 511) {
            // ---- issue xp(t+1) loads; they fly during the barrier
            {
                const unsigned short* x0 = xpb + ((size_t)((hi4 * 4 + 0) * 512 + t + 1)) * 1536 + gc;
                const unsigned short* x1 = xpb + ((size_t)((hi4 * 4 + 1) * 512 + t + 1)) * 1536 + gc;
                const unsigned short* x2 = xpb + ((size_t)((hi4 * 4 + 2) * 512 + t + 1)) * 1536 + gc;
                const unsigned short* x3 = xpb + ((size_t)((hi4 * 4 + 3) * 512 + t + 1)) * 1536 + gc;
                asm volatile(
                    "global_load_ushort %0,  %12, off\n\t"
                    "global_load_ushort %1,  %12, off offset:1024\n\t"
                    "global_load_ushort %2,  %12, off offset:2048\n\t"
                    "global_load_ushort %3,  %13, off\n\t"
                    "global_load_ushort %4,  %13, off offset:1024\n\t"
                    "global_load_ushort %5,  %13, off offset:2048\n\t"
                    "global_load_ushort %6,  %14, off\n\t"
                    "global_load_ushort %7,  %14, off offset:1024\n\t"
                    "global_load_ushort %8,  %14, off offset:2048\n\t"
                    "global_load_ushort %9,  %15, off\n\t"
                    "global_load_ushort %10, %15, off offset:1024\n\t"
                    "global_load_ushort %11, %15, off offset:2048"
                    : "=&v"(xnz[0]), "=&v"(xnr[0]), "=&v"(xnh[0]),
                      "=&v"(xnz[1]), "=&v"(xnr[1]), "=&v"(xnh[1]),
                      "=&v"(xnz[2]), "=&v"(xnr[2]), "=&v"(xnh[2]),
                      "=&v"(xnz[3]), "=&v"(xnr[3]), "=&v"(xnh[3])
                    : "v"(x0), "v"(x1), "v"(x2), "v"(x3) : "memory");
            }
            // ---- barrier (r6 proven)
            __syncthreads();
            if (tid == 0) {
                __hip_atomic_fetch_add(bar, 1u, __ATOMIC_RELAXED, __HIP_MEMORY_SCOPE_AGENT);
                const unsigned int target = 8u * (unsigned int)(t + 1);
                unsigned int it = 0;
                while (__hip_atomic_load(bar, __ATOMIC_RELAXED, __HIP_MEMORY_SCOPE_AGENT)
                       < target) {
                    if (++it > (1u << 14)) break;
                }
                if (it > (1u << 14)) {
                    unsigned int cur = 0, it2 = 0;
                    do {
                        asm volatile("global_atomic_add %0, %1, %2, off sc0\n\t"
                                     "s_waitcnt vmcnt(0)"
                                     : "=v"(cur) : "v"(bar), "v"(0u) : "memory");
                        if (++it2 > (1u << 15)) break;
                    } while (cur < target);
                }
            }
            __syncthreads();
        }
    }
}

extern "C" void kernel_launch(void* const* d_in, const int* in_sizes, int n_in,
                              void* d_out, int out_size, void* d_ws, size_t ws_size,
                              hipStream_t stream)
{
    const float* x     = (const float*)d_in[0];
    const float* Wq    = (const float*)d_in[1];
    const float* bq    = (const float*)d_in[2];
    const float* Wk    = (const float*)d_in[3];
    const float* bk    = (const float*)d_in[4];
    const float* Wv    = (const float*)d_in[5];
    const float* bv    = (const float*)d_in[6];
    const float* Wo    = (const float*)d_in[7];
    const float* bo    = (const float*)d_in[8];
    const float* ln1g  = (const float*)d_in[9];
    const float* ln1b  = (const float*)d_in[10];
    const float* gruk  = (const float*)d_in[11];
    const float* grurk = (const float*)d_in[12];
    const float* grub  = (const float*)d_in[13];
    const float* Wd    = (const float*)d_in[14];
    const float* bd    = (const float*)d_in[15];
    const float* ln2g  = (const float*)d_in[16];
    const float* ln2b  = (const float*)d_in[17];
    float* out = (float*)d_out;

    char* base = (char*)d_ws;
    const size_t MB = 1024 * 1024;
    unsigned short* qkvb = (unsigned short*)base;              // 24 MB bf16 qkv -> xpb reuse
    unsigned short* xpb  = (unsigned short*)base;              // 24 MB (after qkv dead)
    float*          dout = (float*)(base + 24 * MB);           // 16 MB
    float*          R4   = (float*)(base + 48 * MB);           // 16 MB: x1
    unsigned short* S1   = (unsigned short*)(base + 64 * MB);  // 8 MB: xb->ctxb->x1b->goutb
    unsigned short* WT   = (unsigned short*)(base + 72 * MB);  // 4 MB weights
    unsigned short* wqkvT = WT;                 // [1536][512]
    unsigned short* woT  = WT + 768 * 1024;
    unsigned short* gkT  = WT + 1024 * 1024;    // [1536][512]
    unsigned short* wdT  = WT + 1792 * 1024;
    unsigned short* hbuf = (unsigned short*)(base + 76 * MB);  // 32 KB
    char*           Z    = base + 76 * MB + 64 * 1024;         // 8 KB control zone
    unsigned int*   ctl  = (unsigned int*)(Z);
    unsigned int*   bar  = (unsigned int*)(Z + 256);
    float*          bqkv = (float*)(base + 77 * MB);           // 1536 floats

    const dim3 blk(256);
    const dim3 g512(8192 / 128, 512 / 128);
    const dim3 g1536(8192 / 128, 1536 / 128);

    // one fused prep: f2bf(x), bias concat, 6 transposes, zero hbuf + control zone
    prep<<<dim3(6152), blk, 0, stream>>>(x, S1, bq, bk, bv, bqkv,
                                         Wq, Wk, Wv, Wo, gruk, Wd,
                                         wqkvT, woT, gkT, wdT,
                                         (unsigned int*)hbuf, (unsigned int*)Z);
    // fused QKV projection, bf16 output only
    gemm_bf16<<<g1536, blk, 0, stream>>>(S1, wqkvT, bqkv, nullptr, nullptr, qkvb, 8192, 1536, 512);
    attn_bf16<<<dim3(1024), blk, 0, stream>>>(qkvb, S1);
    gemm_bf16<<<g512, blk, 0, stream>>>(S1, woT, bo, x, R4, nullptr, 8192, 512, 512);
    ln_f32<<<dim3(2048), blk, 0, stream>>>(R4, R4, ln1g, ln1b, S1);
    // xp = x1 @ gru_k + gru_b[0], bf16-only output
    gemm_bf16<<<g1536, blk, 0, stream>>>(S1, gkT, grub, nullptr, nullptr, xpb, 8192, 1536, 512);
    // persistent GRU (XCD-pinned)
    gru_persist<<<dim3(GRID_WGS), blk, 0, stream>>>(grurk, xpb, grub + 1536, hbuf, S1, bar, ctl);
    gemm_bf16<<<g512, blk, 0, stream>>>(S1, wdT, bd, R4, dout, nullptr, 8192, 512, 512);
    ln_f32<<<dim3(2048), blk, 0, stream>>>(dout, out, ln2g, ln2b, nullptr);
}

// Round 12
// 2317.340 us; speedup vs baseline: 2181.1598x; 1.0069x over previous
//
#include <hip/hip_runtime.h>
#include <math.h>

// B=16, T=512, F=512, H=8, D=64; rows = B*T = 8192
#define GRID_WGS 128   // launched WGs for GRU; 8 elected (same XCD) participate

typedef __attribute__((ext_vector_type(8))) short bf16x8;
typedef __attribute__((ext_vector_type(4))) float f32x4;
typedef __attribute__((ext_vector_type(4))) unsigned short us4;

static __device__ __forceinline__ float sigmoidf_(float x) {
    return 1.0f / (1.0f + __expf(-x));
}
static __device__ __forceinline__ unsigned short f2bf(float f) {
    unsigned int u = __float_as_uint(f);
    u += 0x7fffu + ((u >> 16) & 1u);
    return (unsigned short)(u >> 16);
}
static __device__ __forceinline__ float bfbits2f(unsigned int b) {
    return __uint_as_float(b << 16);
}
static __device__ __forceinline__ void gload_lds16(const void* g, void* l) {
    __builtin_amdgcn_global_load_lds(
        (const __attribute__((address_space(1))) unsigned int*)g,
        (__attribute__((address_space(3))) unsigned int*)l, 16, 0, 0);
}

// ---------------- prep: f2bf(x) + bias concat + 6 weight transposes + zero hbuf/Z -------------
__global__ __launch_bounds__(256)
void prep(const float* __restrict__ x, unsigned short* __restrict__ xb,
          const float* __restrict__ bq, const float* __restrict__ bk,
          const float* __restrict__ bv, float* __restrict__ bqkv,
          const float* __restrict__ Wq, const float* __restrict__ Wk,
          const float* __restrict__ Wv, const float* __restrict__ Wo,
          const float* __restrict__ gruk, const float* __restrict__ Wd,
          unsigned short* __restrict__ wqkvT, unsigned short* __restrict__ woT,
          unsigned short* __restrict__ gkT, unsigned short* __restrict__ wdT,
          unsigned int* __restrict__ hbufz, unsigned int* __restrict__ Z)
{
    __shared__ float tile[32][33];
    const int bid = blockIdx.x, tid = threadIdx.x;
    if (bid < 4096) {
        const int i = (bid * 256 + tid) * 4;
        const float4 v = *(const float4*)(x + i);
        const us4 o = {f2bf(v.x), f2bf(v.y), f2bf(v.z), f2bf(v.w)};
        *(us4*)(xb + i) = o;
    } else if (bid < 4102) {
        const int i = (bid - 4096) * 256 + tid;
        bqkv[i] = (i < 512) ? bq[i] : ((i < 1024) ? bk[i - 512] : bv[i - 1024]);
    } else if (bid < 6150) {
        int t = bid - 4102;
        const float* in; unsigned short* out; int N;
        if      (t < 256)  { in = Wq;   out = wqkvT;               N = 512;  }
        else if (t < 512)  { in = Wk;   out = wqkvT + 256 * 1024;  N = 512;  t -= 256;  }
        else if (t < 768)  { in = Wv;   out = wqkvT + 512 * 1024;  N = 512;  t -= 512;  }
        else if (t < 1024) { in = Wo;   out = woT;                 N = 512;  t -= 768;  }
        else if (t < 1792) { in = gruk; out = gkT;                 N = 1536; t -= 1024; }
        else               { in = Wd;   out = wdT;                 N = 512;  t -= 1792; }
        const int tilesx = N / 32;
        const int n0 = (t % tilesx) * 32, k0 = (t / tilesx) * 32;
        const int c = tid & 31, r8 = tid >> 5;
#pragma unroll
        for (int i = 0; i < 4; ++i) {
            const int k = r8 + i * 8;
            tile[k][c] = in[(size_t)(k0 + k) * N + n0 + c];
        }
        __syncthreads();
#pragma unroll
        for (int i = 0; i < 4; ++i) {
            const int n = r8 + i * 8;
            out[(size_t)(n0 + n) * 512 + k0 + c] = f2bf(tile[c][n]);
        }
    } else if (bid == 6150) {
        for (int i = tid; i < 8192; i += 256) hbufz[i] = 0u;
    } else {
        for (int i = tid; i < 2048; i += 256) Z[i] = 0u;
    }
}

// ---------------- bf16 MFMA GEMM: C=A@Bt (+bias)(+resid); f32 C and/or bf16 Cb outputs --------
__global__ __launch_bounds__(256)
void gemm_bf16(const unsigned short* __restrict__ A, const unsigned short* __restrict__ Bt,
               const float* __restrict__ bias, const float* __restrict__ resid,
               float* __restrict__ C, unsigned short* __restrict__ Cb,
               int M, int N, int K)
{
    __shared__ unsigned short As[128 * 64];
    __shared__ unsigned short Bs[128 * 64];
    const int tid = threadIdx.x;
    const int wave = tid >> 6, lane = tid & 63;
    const int bm = blockIdx.x * 128, bn = blockIdx.y * 128;
    const int wr = wave >> 1, wc = wave & 1;
    const int stR = lane >> 3;
    const int stC = (lane & 7) * 8;

    const unsigned short* Abase = A + (size_t)(bm + wave * 32 + stR) * K + stC;
    const unsigned short* Bbase = Bt + (size_t)(bn + wave * 32 + stR) * K + stC;
    unsigned short* AsW = As + wave * 2048;
    unsigned short* BsW = Bs + wave * 2048;

    f32x4 acc[4][4] = {};
    const int fr = lane & 15;
    const int fko = (lane >> 4) * 8;

    for (int k0 = 0; k0 < K; k0 += 64) {
#pragma unroll
        for (int i = 0; i < 4; ++i) {
            gload_lds16(Abase + (size_t)i * 8 * K + k0, AsW + i * 512);
            gload_lds16(Bbase + (size_t)i * 8 * K + k0, BsW + i * 512);
        }
        __syncthreads();
        bf16x8 af[4][2], bfr[4][2];
#pragma unroll
        for (int m = 0; m < 4; ++m) {
            const unsigned short* ap = As + (wr * 64 + m * 16 + fr) * 64 + fko;
            af[m][0] = *(const bf16x8*)(ap);
            af[m][1] = *(const bf16x8*)(ap + 32);
        }
#pragma unroll
        for (int n = 0; n < 4; ++n) {
            const unsigned short* bp = Bs + (wc * 64 + n * 16 + fr) * 64 + fko;
            bfr[n][0] = *(const bf16x8*)(bp);
            bfr[n][1] = *(const bf16x8*)(bp + 32);
        }
#pragma unroll
        for (int m = 0; m < 4; ++m)
#pragma unroll
            for (int n = 0; n < 4; ++n) {
                acc[m][n] = __builtin_amdgcn_mfma_f32_16x16x32_bf16(af[m][0], bfr[n][0], acc[m][n], 0, 0, 0);
                acc[m][n] = __builtin_amdgcn_mfma_f32_16x16x32_bf16(af[m][1], bfr[n][1], acc[m][n], 0, 0, 0);
            }
        __syncthreads();
    }
    const int fq = lane >> 4;
#pragma unroll
    for (int n = 0; n < 4; ++n) {
        const int col = bn + wc * 64 + n * 16 + fr;
        const float bv = bias ? bias[col] : 0.f;
#pragma unroll
        for (int m = 0; m < 4; ++m) {
#pragma unroll
            for (int j = 0; j < 4; ++j) {
                const int row = bm + wr * 64 + m * 16 + fq * 4 + j;
                float v = acc[m][n][j] + bv;
                if (resid) v += resid[(size_t)row * N + col];
                if (C)  C[(size_t)row * N + col] = v;
                if (Cb) Cb[(size_t)row * N + col] = f2bf(v);
            }
        }
    }
}

// ---------------- attention, 32-row q tiles, bf16 S (49.7 KB LDS -> 3 WGs/CU) -----------------
// grid 2048 = b(16) x h(8) x qt(16); 256 thr; r = tid>>3 (q row), oct = tid&7.
// KV pad 69: 8 threads/row stride 8*69 mod 32 = 8 -> 2-way bank alias (free, m136).
__global__ __launch_bounds__(256)
void attn_bf16(const unsigned short* __restrict__ qkv, unsigned short* __restrict__ ctxb)
{
    __shared__ unsigned short S[32][512];   // 32 KB (scores / P as bf16)
    __shared__ float KV[64][69];            // 17.7 KB
    const int tid = threadIdx.x;
    const int wg = blockIdx.x;
    const int qt = wg & 15, h = (wg >> 4) & 7, b = wg >> 7;
    const int r = tid >> 3, oct = tid & 7;
    const int t0 = qt * 32;
    const int ss = tid >> 2, d4 = (tid & 3) * 16;   // staging indices

    float4 qreg[16];
    {
        const unsigned short* qrow = qkv + ((size_t)(b * 512 + t0 + r) * 1536) + h * 64;
#pragma unroll
        for (int i = 0; i < 8; ++i) {
            const bf16x8 v = *(const bf16x8*)(qrow + i * 8);
            qreg[2 * i] = {bfbits2f((unsigned short)v[0]) * 0.125f,
                           bfbits2f((unsigned short)v[1]) * 0.125f,
                           bfbits2f((unsigned short)v[2]) * 0.125f,
                           bfbits2f((unsigned short)v[3]) * 0.125f};
            qreg[2 * i + 1] = {bfbits2f((unsigned short)v[4]) * 0.125f,
                               bfbits2f((unsigned short)v[5]) * 0.125f,
                               bfbits2f((unsigned short)v[6]) * 0.125f,
                               bfbits2f((unsigned short)v[7]) * 0.125f};
        }
    }
    // phase 1: scores
    for (int st = 0; st < 8; ++st) {
        {
            const unsigned short* krow =
                qkv + ((size_t)(b * 512 + st * 64 + ss) * 1536) + 512 + h * 64 + d4;
            const bf16x8 v0 = *(const bf16x8*)(krow);
            const bf16x8 v1 = *(const bf16x8*)(krow + 8);
#pragma unroll
            for (int e = 0; e < 8; ++e) {
                KV[ss][d4 + e] = bfbits2f((unsigned short)v0[e]);
                KV[ss][d4 + 8 + e] = bfbits2f((unsigned short)v1[e]);
            }
        }
        __syncthreads();
        float accd[8] = {};
#pragma unroll 4
        for (int kk = 0; kk < 16; ++kk) {
            const float4 qv = qreg[kk];
#pragma unroll
            for (int i = 0; i < 8; ++i) {
                const float4 kv = *(const float4*)&KV[oct * 8 + i][kk * 4];
                accd[i] += qv.x * kv.x + qv.y * kv.y + qv.z * kv.z + qv.w * kv.w;
            }
        }
#pragma unroll
        for (int i = 0; i < 8; ++i)
            S[r][st * 64 + oct * 8 + i] = f2bf(accd[i]);
        __syncthreads();
    }
    // phase 2: softmax over row r (8 threads x 64 cols each)
    const int c0 = oct * 64;
    float mx = -1e30f;
#pragma unroll
    for (int c8 = 0; c8 < 8; ++c8) {
        const bf16x8 sv = *(const bf16x8*)&S[r][c0 + c8 * 8];
#pragma unroll
        for (int e = 0; e < 8; ++e) mx = fmaxf(mx, bfbits2f((unsigned short)sv[e]));
    }
    mx = fmaxf(mx, __shfl_xor(mx, 1));
    mx = fmaxf(mx, __shfl_xor(mx, 2));
    mx = fmaxf(mx, __shfl_xor(mx, 4));
    float sum = 0.f;
#pragma unroll
    for (int c8 = 0; c8 < 8; ++c8) {
        const bf16x8 sv = *(const bf16x8*)&S[r][c0 + c8 * 8];
        us4 o1, o2;
#pragma unroll
        for (int e = 0; e < 8; ++e) {
            const float p = __expf(bfbits2f((unsigned short)sv[e]) - mx);
            sum += p;
            if (e < 4) o1[e] = f2bf(p); else o2[e - 4] = f2bf(p);
        }
        *(us4*)&S[r][c0 + c8 * 8] = o1;
        *(us4*)&S[r][c0 + c8 * 8 + 4] = o2;
    }
    sum += __shfl_xor(sum, 1);
    sum += __shfl_xor(sum, 2);
    sum += __shfl_xor(sum, 4);
    const float inv = 1.0f / sum;
    __syncthreads();
    // phase 3: O[r][oct*8..+8] = P @ V
    float o[8] = {};
    for (int st = 0; st < 8; ++st) {
        {
            const unsigned short* vrow =
                qkv + ((size_t)(b * 512 + st * 64 + ss) * 1536) + 1024 + h * 64 + d4;
            const bf16x8 v0 = *(const bf16x8*)(vrow);
            const bf16x8 v1 = *(const bf16x8*)(vrow + 8);
#pragma unroll
            for (int e = 0; e < 8; ++e) {
                KV[ss][d4 + e] = bfbits2f((unsigned short)v0[e]);
                KV[ss][d4 + 8 + e] = bfbits2f((unsigned short)v1[e]);
            }
        }
        __syncthreads();
#pragma unroll 2
        for (int s8 = 0; s8 < 8; ++s8) {
            const bf16x8 pv = *(const bf16x8*)&S[r][st * 64 + s8 * 8];   // broadcast
#pragma unroll
            for (int e = 0; e < 8; ++e) {
                const float p = bfbits2f((unsigned short)pv[e]);
                const float4 k0 = *(const float4*)&KV[s8 * 8 + e][oct * 8];
                const float4 k1 = *(const float4*)&KV[s8 * 8 + e][oct * 8 + 4];
                o[0] = fmaf(p, k0.x, o[0]); o[1] = fmaf(p, k0.y, o[1]);
                o[2] = fmaf(p, k0.z, o[2]); o[3] = fmaf(p, k0.w, o[3]);
                o[4] = fmaf(p, k1.x, o[4]); o[5] = fmaf(p, k1.y, o[5]);
                o[6] = fmaf(p, k1.z, o[6]); o[7] = fmaf(p, k1.w, o[7]);
            }
        }
        __syncthreads();
    }
    unsigned short* crow = ctxb + ((size_t)(b * 512 + t0 + r) * 512) + h * 64 + oct * 8;
    const us4 t1 = {f2bf(o[0] * inv), f2bf(o[1] * inv), f2bf(o[2] * inv), f2bf(o[3] * inv)};
    const us4 t2 = {f2bf(o[4] * inv), f2bf(o[5] * inv), f2bf(o[6] * inv), f2bf(o[7] * inv)};
    *(us4*)(crow) = t1;
    *(us4*)(crow + 4) = t2;
}

// ---------------- layernorm (rows of 512), optional bf16 side output --------------------------
__global__ __launch_bounds__(256)
void ln_f32(const float* __restrict__ in, float* __restrict__ out,
            const float* __restrict__ g, const float* __restrict__ bb,
            unsigned short* __restrict__ outb)
{
    const int lane = threadIdx.x & 63;
    const int row = blockIdx.x * 4 + (threadIdx.x >> 6);
    const float* x = in + (size_t)row * 512;
    const float4 a = *(const float4*)(x + lane * 4);
    const float4 c = *(const float4*)(x + 256 + lane * 4);
    float s = a.x + a.y + a.z + a.w + c.x + c.y + c.z + c.w;
#pragma unroll
    for (int off = 1; off < 64; off <<= 1) s += __shfl_xor(s, off);
    const float mu = s * (1.0f / 512.0f);
    float vs = 0.f;
    vs += (a.x - mu) * (a.x - mu) + (a.y - mu) * (a.y - mu);
    vs += (a.z - mu) * (a.z - mu) + (a.w - mu) * (a.w - mu);
    vs += (c.x - mu) * (c.x - mu) + (c.y - mu) * (c.y - mu);
    vs += (c.z - mu) * (c.z - mu) + (c.w - mu) * (c.w - mu);
#pragma unroll
    for (int off = 1; off < 64; off <<= 1) vs += __shfl_xor(vs, off);
    const float rstd = rsqrtf(vs * (1.0f / 512.0f) + 1e-3f);
    const float4 g1 = *(const float4*)(g + lane * 4);
    const float4 g2 = *(const float4*)(g + 256 + lane * 4);
    const float4 b1 = *(const float4*)(bb + lane * 4);
    const float4 b2 = *(const float4*)(bb + 256 + lane * 4);
    float* y = out + (size_t)row * 512;
    const float4 o1 = {(a.x - mu) * rstd * g1.x + b1.x, (a.y - mu) * rstd * g1.y + b1.y,
                       (a.z - mu) * rstd * g1.z + b1.z, (a.w - mu) * rstd * g1.w + b1.w};
    const float4 o2 = {(c.x - mu) * rstd * g2.x + b2.x, (c.y - mu) * rstd * g2.y + b2.y,
                       (c.z - mu) * rstd * g2.z + b2.z, (c.w - mu) * rstd * g2.w + b2.w};
    *(float4*)(y + lane * 4) = o1;
    *(float4*)(y + 256 + lane * 4) = o2;
    if (outb) {
        unsigned short* yb = outb + (size_t)row * 512;
        const us4 p1 = {f2bf(o1.x), f2bf(o1.y), f2bf(o1.z), f2bf(o1.w)};
        const us4 p2 = {f2bf(o2.x), f2bf(o2.y), f2bf(o2.z), f2bf(o2.w)};
        *(us4*)(yb + lane * 4) = p1;
        *(us4*)(yb + 256 + lane * 4) = p2;
    }
}

// ---------------- persistent GRU, XCD-pinned (r10 exact: proven 1666 us) ----------------------
__global__ __launch_bounds__(256, 1)
void gru_persist(const float* __restrict__ rk,
                 const unsigned short* __restrict__ xpb,
                 const float* __restrict__ rb,
                 unsigned short* __restrict__ hbuf,
                 unsigned short* __restrict__ goutb,
                 unsigned int* __restrict__ bar,
                 unsigned int* __restrict__ ctl)
{
    __shared__ int sh_part, sh_memb;
    const int tid = threadIdx.x;

    if (tid == 0) {
        unsigned int xcc;
        asm("s_getreg_b32 %0, hwreg(HW_REG_XCC_ID)" : "=s"(xcc));
        xcc &= 7u;
        const unsigned int rank =
            __hip_atomic_fetch_add(&ctl[xcc], 1u, __ATOMIC_RELAXED, __HIP_MEMORY_SCOPE_AGENT);
        __hip_atomic_fetch_add(&ctl[8], 1u, __ATOMIC_ACQ_REL, __HIP_MEMORY_SCOPE_AGENT);
        unsigned int spins = 0;
        while (__hip_atomic_load(&ctl[8], __ATOMIC_ACQUIRE, __HIP_MEMORY_SCOPE_AGENT)
               < (unsigned)GRID_WGS) {
            __builtin_amdgcn_s_sleep(1);
            if (++spins > (1u << 20)) break;
        }
        unsigned int cnt[8];
#pragma unroll
        for (int i = 0; i < 8; ++i)
            cnt[i] = __hip_atomic_load(&ctl[i], __ATOMIC_ACQUIRE, __HIP_MEMORY_SCOPE_AGENT);
        int best = 0;
#pragma unroll
        for (int i = 1; i < 8; ++i)
            if (cnt[i] > cnt[best]) best = i;
        sh_part = (xcc == (unsigned)best && rank < 8u) ? 1 : 0;
        sh_memb = (int)rank;
    }
    __syncthreads();
    if (!sh_part) return;
    const int member = sh_memb;

    const int wv = tid >> 6, l = tid & 63;
    const int wgi = member * 4 + wv;
    const int lo16 = l & 15;
    const int hi4 = l >> 4;
    const int gc = wgi * 16 + lo16;

    bf16x8 B[3][16];
#pragma unroll
    for (int g = 0; g < 3; ++g)
#pragma unroll
        for (int kt = 0; kt < 16; ++kt) {
            bf16x8 bv;
#pragma unroll
            for (int j = 0; j < 8; ++j) {
                const int k = kt * 32 + hi4 * 8 + j;
                bv[j] = (short)f2bf(rk[(size_t)k * 1536 + g * 512 + gc]);
            }
            B[g][kt] = bv;
        }
    const float rbz = rb[gc], rbr = rb[512 + gc], rbh = rb[1024 + gc];
    float hst[4] = {0.f, 0.f, 0.f, 0.f};

    float xz[4], xr[4], xh[4];
#pragma unroll
    for (int j = 0; j < 4; ++j) {
        const unsigned short* xrow = xpb + ((size_t)((hi4 * 4 + j) * 512)) * 1536 + gc;
        xz[j] = bfbits2f(xrow[0]); xr[j] = bfbits2f(xrow[512]); xh[j] = bfbits2f(xrow[1024]);
    }
    unsigned int hnb[4] = {0u, 0u, 0u, 0u};

    const unsigned short* ab0 = hbuf + lo16 * 512 + hi4 * 8;
    const unsigned short* ab1 = ab0 + 16 * 512;

    for (int t = 0; t < 512; ++t) {
        const unsigned short* abase = (t & 1) ? ab1 : ab0;
        unsigned short* hw = hbuf + (size_t)((t + 1) & 1) * (16 * 512);
        bf16x8 A[16];
        asm volatile(
            "global_load_dwordx4 %0,  %16, off sc0\n\t"
            "global_load_dwordx4 %1,  %16, off offset:64 sc0\n\t"
            "global_load_dwordx4 %2,  %16, off offset:128 sc0\n\t"
            "global_load_dwordx4 %3,  %16, off offset:192 sc0\n\t"
            "global_load_dwordx4 %4,  %16, off offset:256 sc0\n\t"
            "global_load_dwordx4 %5,  %16, off offset:320 sc0\n\t"
            "global_load_dwordx4 %6,  %16, off offset:384 sc0\n\t"
            "global_load_dwordx4 %7,  %16, off offset:448 sc0\n\t"
            "global_load_dwordx4 %8,  %16, off offset:512 sc0\n\t"
            "global_load_dwordx4 %9,  %16, off offset:576 sc0\n\t"
            "global_load_dwordx4 %10, %16, off offset:640 sc0\n\t"
            "global_load_dwordx4 %11, %16, off offset:704 sc0\n\t"
            "global_load_dwordx4 %12, %16, off offset:768 sc0\n\t"
            "global_load_dwordx4 %13, %16, off offset:832 sc0\n\t"
            "global_load_dwordx4 %14, %16, off offset:896 sc0\n\t"
            "global_load_dwordx4 %15, %16, off offset:960 sc0"
            : "=&v"(A[0]), "=&v"(A[1]), "=&v"(A[2]), "=&v"(A[3]),
              "=&v"(A[4]), "=&v"(A[5]), "=&v"(A[6]), "=&v"(A[7]),
              "=&v"(A[8]), "=&v"(A[9]), "=&v"(A[10]), "=&v"(A[11]),
              "=&v"(A[12]), "=&v"(A[13]), "=&v"(A[14]), "=&v"(A[15])
            : "v"(abase) : "memory");
        unsigned int xnz[4], xnr[4], xnh[4];
        {
            const unsigned short* x0 = xpb + ((size_t)((hi4 * 4 + 0) * 512 + t + 1)) * 1536 + gc;
            const unsigned short* x1 = xpb + ((size_t)((hi4 * 4 + 1) * 512 + t + 1)) * 1536 + gc;
            const unsigned short* x2 = xpb + ((size_t)((hi4 * 4 + 2) * 512 + t + 1)) * 1536 + gc;
            const unsigned short* x3 = xpb + ((size_t)((hi4 * 4 + 3) * 512 + t + 1)) * 1536 + gc;
            asm volatile(
                "global_load_ushort %0,  %12, off\n\t"
                "global_load_ushort %1,  %12, off offset:1024\n\t"
                "global_load_ushort %2,  %12, off offset:2048\n\t"
                "global_load_ushort %3,  %13, off\n\t"
                "global_load_ushort %4,  %13, off offset:1024\n\t"
                "global_load_ushort %5,  %13, off offset:2048\n\t"
                "global_load_ushort %6,  %14, off\n\t"
                "global_load_ushort %7,  %14, off offset:1024\n\t"
                "global_load_ushort %8,  %14, off offset:2048\n\t"
                "global_load_ushort %9,  %15, off\n\t"
                "global_load_ushort %10, %15, off offset:1024\n\t"
                "global_load_ushort %11, %15, off offset:2048"
                : "=&v"(xnz[0]), "=&v"(xnr[0]), "=&v"(xnh[0]),
                  "=&v"(xnz[1]), "=&v"(xnr[1]), "=&v"(xnh[1]),
                  "=&v"(xnz[2]), "=&v"(xnr[2]), "=&v"(xnh[2]),
                  "=&v"(xnz[3]), "=&v"(xnr[3]), "=&v"(xnh[3])
                : "v"(x0), "v"(x1), "v"(x2), "v"(x3) : "memory");
        }
        {
            const int grow = t ? t - 1 : 0;
            unsigned short* g0 = goutb + ((size_t)((hi4 * 4 + 0) * 512 + grow)) * 512 + gc;
            unsigned short* g1 = goutb + ((size_t)((hi4 * 4 + 1) * 512 + grow)) * 512 + gc;
            unsigned short* g2 = goutb + ((size_t)((hi4 * 4 + 2) * 512 + grow)) * 512 + gc;
            unsigned short* g3 = goutb + ((size_t)((hi4 * 4 + 3) * 512 + grow)) * 512 + gc;
            asm volatile(
                "global_store_short %0, %4, off\n\t"
                "global_store_short %1, %5, off\n\t"
                "global_store_short %2, %6, off\n\t"
                "global_store_short %3, %7, off"
                :: "v"(g0), "v"(g1), "v"(g2), "v"(g3),
                   "v"(hnb[0]), "v"(hnb[1]), "v"(hnb[2]), "v"(hnb[3]) : "memory");
        }
        asm volatile("s_waitcnt vmcnt(16)" ::: "memory");
        __builtin_amdgcn_sched_barrier(0);

        f32x4 accz = {0.f, 0.f, 0.f, 0.f};
        f32x4 accr = {0.f, 0.f, 0.f, 0.f};
        f32x4 acch = {0.f, 0.f, 0.f, 0.f};
#pragma unroll
        for (int kt = 0; kt < 16; ++kt) {
            accz = __builtin_amdgcn_mfma_f32_16x16x32_bf16(A[kt], B[0][kt], accz, 0, 0, 0);
            accr = __builtin_amdgcn_mfma_f32_16x16x32_bf16(A[kt], B[1][kt], accr, 0, 0, 0);
            acch = __builtin_amdgcn_mfma_f32_16x16x32_bf16(A[kt], B[2][kt], acch, 0, 0, 0);
        }
#pragma unroll
        for (int j = 0; j < 4; ++j) {
            const int b = hi4 * 4 + j;
            const float z = sigmoidf_(xz[j] + accz[j] + rbz);
            const float r = sigmoidf_(xr[j] + accr[j] + rbr);
            const float hh = fmaxf(xh[j] + r * (acch[j] + rbh), 0.f);
            const float hnew = z * hst[j] + (1.f - z) * hh;
            hst[j] = hnew;
            const unsigned short hb = f2bf(hnew);
            hnb[j] = (unsigned int)hb;
            hw[b * 512 + gc] = hb;
        }
        asm volatile("s_waitcnt vmcnt(0)" ::: "memory");
        __builtin_amdgcn_sched_barrier(0);
#pragma unroll
        for (int j = 0; j < 4; ++j) {
            xz[j] = bfbits2f(xnz[j]); xr[j] = bfbits2f(xnr[j]); xh[j] = bfbits2f(xnh[j]);
        }
        if (t < 511) {
            __syncthreads();
            if (tid == 0) {
                __hip_atomic_fetch_add(bar, 1u, __ATOMIC_RELAXED, __HIP_MEMORY_SCOPE_AGENT);
                const unsigned int target = 8u * (unsigned int)(t + 1);
                unsigned int it = 0;
                while (__hip_atomic_load(bar, __ATOMIC_RELAXED, __HIP_MEMORY_SCOPE_AGENT)
                       < target) {
                    if (++it > (1u << 14)) break;
                }
                if (it > (1u << 14)) {
                    unsigned int cur = 0, it2 = 0;
                    do {
                        asm volatile("global_atomic_add %0, %1, %2, off sc0\n\t"
                                     "s_waitcnt vmcnt(0)"
                                     : "=v"(cur) : "v"(bar), "v"(0u) : "memory");
                        if (++it2 > (1u << 15)) break;
                    } while (cur < target);
                }
            }
            __syncthreads();
        }
    }
#pragma unroll
    for (int j = 0; j < 4; ++j)
        goutb[((size_t)((hi4 * 4 + j) * 512 + 511)) * 512 + gc] = (unsigned short)hnb[j];
}

extern "C" void kernel_launch(void* const* d_in, const int* in_sizes, int n_in,
                              void* d_out, int out_size, void* d_ws, size_t ws_size,
                              hipStream_t stream)
{
    const float* x     = (const float*)d_in[0];
    const float* Wq    = (const float*)d_in[1];
    const float* bq    = (const float*)d_in[2];
    const float* Wk    = (const float*)d_in[3];
    const float* bk    = (const float*)d_in[4];
    const float* Wv    = (const float*)d_in[5];
    const float* bv    = (const float*)d_in[6];
    const float* Wo    = (const float*)d_in[7];
    const float* bo    = (const float*)d_in[8];
    const float* ln1g  = (const float*)d_in[9];
    const float* ln1b  = (const float*)d_in[10];
    const float* gruk  = (const float*)d_in[11];
    const float* grurk = (const float*)d_in[12];
    const float* grub  = (const float*)d_in[13];
    const float* Wd    = (const float*)d_in[14];
    const float* bd    = (const float*)d_in[15];
    const float* ln2g  = (const float*)d_in[16];
    const float* ln2b  = (const float*)d_in[17];
    float* out = (float*)d_out;

    char* base = (char*)d_ws;
    const size_t MB = 1024 * 1024;
    unsigned short* qkvb = (unsigned short*)base;              // 24 MB bf16 qkv -> xpb reuse
    unsigned short* xpb  = (unsigned short*)base;
    float*          dout = (float*)(base + 24 * MB);
    float*          R4   = (float*)(base + 48 * MB);           // x1
    unsigned short* S1   = (unsigned short*)(base + 64 * MB);  // xb->ctxb->x1b->goutb
    unsigned short* WT   = (unsigned short*)(base + 72 * MB);
    unsigned short* wqkvT = WT;
    unsigned short* woT  = WT + 768 * 1024;
    unsigned short* gkT  = WT + 1024 * 1024;
    unsigned short* wdT  = WT + 1792 * 1024;
    unsigned short* hbuf = (unsigned short*)(base + 76 * MB);
    char*           Z    = base + 76 * MB + 64 * 1024;
    unsigned int*   ctl  = (unsigned int*)(Z);
    unsigned int*   bar  = (unsigned int*)(Z + 256);
    float*          bqkv = (float*)(base + 77 * MB);

    const dim3 blk(256);
    const dim3 g512(8192 / 128, 512 / 128);
    const dim3 g1536(8192 / 128, 1536 / 128);

    prep<<<dim3(6152), blk, 0, stream>>>(x, S1, bq, bk, bv, bqkv,
                                         Wq, Wk, Wv, Wo, gruk, Wd,
                                         wqkvT, woT, gkT, wdT,
                                         (unsigned int*)hbuf, (unsigned int*)Z);
    gemm_bf16<<<g1536, blk, 0, stream>>>(S1, wqkvT, bqkv, nullptr, nullptr, qkvb, 8192, 1536, 512);
    attn_bf16<<<dim3(2048), blk, 0, stream>>>(qkvb, S1);
    gemm_bf16<<<g512, blk, 0, stream>>>(S1, woT, bo, x, R4, nullptr, 8192, 512, 512);
    ln_f32<<<dim3(2048), blk, 0, stream>>>(R4, R4, ln1g, ln1b, S1);
    gemm_bf16<<<g1536, blk, 0, stream>>>(S1, gkT, grub, nullptr, nullptr, xpb, 8192, 1536, 512);
    gru_persist<<<dim3(GRID_WGS), blk, 0, stream>>>(grurk, xpb, grub + 1536, hbuf, S1, bar, ctl);
    gemm_bf16<<<g512, blk, 0, stream>>>(S1, wdT, bd, R4, dout, nullptr, 8192, 512, 512);
    ln_f32<<<dim3(2048), blk, 0, stream>>>(dout, out, ln2g, ln2b, nullptr);
}

// Round 13
// 1968.896 us; speedup vs baseline: 2567.1692x; 1.1770x over previous
//
#include <hip/hip_runtime.h>
#include <math.h>

// B=16, T=512, F=512, H=8, D=64; rows = B*T = 8192
#define GRID_WGS 128   // launched WGs for GRU; 8 elected (same XCD) participate

typedef __attribute__((ext_vector_type(8))) short bf16x8;
typedef __attribute__((ext_vector_type(4))) float f32x4;
typedef __attribute__((ext_vector_type(4))) unsigned short us4;

static __device__ __forceinline__ float sigmoidf_(float x) {
    return 1.0f / (1.0f + __expf(-x));
}
static __device__ __forceinline__ unsigned short f2bf(float f) {
    unsigned int u = __float_as_uint(f);
    u += 0x7fffu + ((u >> 16) & 1u);
    return (unsigned short)(u >> 16);
}
static __device__ __forceinline__ float bfbits2f(unsigned int b) {
    return __uint_as_float(b << 16);
}
static __device__ __forceinline__ void gload_lds16(const void* g, void* l) {
    __builtin_amdgcn_global_load_lds(
        (const __attribute__((address_space(1))) unsigned int*)g,
        (__attribute__((address_space(3))) unsigned int*)l, 16, 0, 0);
}

// ---------------- prep: f2bf(x) + bias concat + 6 weight transposes + zero hbuf/Z -------------
__global__ __launch_bounds__(256)
void prep(const float* __restrict__ x, unsigned short* __restrict__ xb,
          const float* __restrict__ bq, const float* __restrict__ bk,
          const float* __restrict__ bv, float* __restrict__ bqkv,
          const float* __restrict__ Wq, const float* __restrict__ Wk,
          const float* __restrict__ Wv, const float* __restrict__ Wo,
          const float* __restrict__ gruk, const float* __restrict__ Wd,
          unsigned short* __restrict__ wqkvT, unsigned short* __restrict__ woT,
          unsigned short* __restrict__ gkT, unsigned short* __restrict__ wdT,
          unsigned int* __restrict__ hbufz, unsigned int* __restrict__ Z)
{
    __shared__ float tile[32][33];
    const int bid = blockIdx.x, tid = threadIdx.x;
    if (bid < 4096) {
        const int i = (bid * 256 + tid) * 4;
        const float4 v = *(const float4*)(x + i);
        const us4 o = {f2bf(v.x), f2bf(v.y), f2bf(v.z), f2bf(v.w)};
        *(us4*)(xb + i) = o;
    } else if (bid < 4102) {
        const int i = (bid - 4096) * 256 + tid;
        bqkv[i] = (i < 512) ? bq[i] : ((i < 1024) ? bk[i - 512] : bv[i - 1024]);
    } else if (bid < 6150) {
        int t = bid - 4102;
        const float* in; unsigned short* out; int N;
        if      (t < 256)  { in = Wq;   out = wqkvT;               N = 512;  }
        else if (t < 512)  { in = Wk;   out = wqkvT + 256 * 1024;  N = 512;  t -= 256;  }
        else if (t < 768)  { in = Wv;   out = wqkvT + 512 * 1024;  N = 512;  t -= 512;  }
        else if (t < 1024) { in = Wo;   out = woT;                 N = 512;  t -= 768;  }
        else if (t < 1792) { in = gruk; out = gkT;                 N = 1536; t -= 1024; }
        else               { in = Wd;   out = wdT;                 N = 512;  t -= 1792; }
        const int tilesx = N / 32;
        const int n0 = (t % tilesx) * 32, k0 = (t / tilesx) * 32;
        const int c = tid & 31, r8 = tid >> 5;
#pragma unroll
        for (int i = 0; i < 4; ++i) {
            const int k = r8 + i * 8;
            tile[k][c] = in[(size_t)(k0 + k) * N + n0 + c];
        }
        __syncthreads();
#pragma unroll
        for (int i = 0; i < 4; ++i) {
            const int n = r8 + i * 8;
            out[(size_t)(n0 + n) * 512 + k0 + c] = f2bf(tile[c][n]);
        }
    } else if (bid == 6150) {
        for (int i = tid; i < 8192; i += 256) hbufz[i] = 0u;
    } else {
        for (int i = tid; i < 2048; i += 256) Z[i] = 0u;
    }
}

// ---------------- bf16 MFMA GEMM: C=A@Bt (+bias)(+resid); f32 C and/or bf16 Cb outputs --------
__global__ __launch_bounds__(256)
void gemm_bf16(const unsigned short* __restrict__ A, const unsigned short* __restrict__ Bt,
               const float* __restrict__ bias, const float* __restrict__ resid,
               float* __restrict__ C, unsigned short* __restrict__ Cb,
               int M, int N, int K)
{
    __shared__ unsigned short As[128 * 64];
    __shared__ unsigned short Bs[128 * 64];
    const int tid = threadIdx.x;
    const int wave = tid >> 6, lane = tid & 63;
    const int bm = blockIdx.x * 128, bn = blockIdx.y * 128;
    const int wr = wave >> 1, wc = wave & 1;
    const int stR = lane >> 3;
    const int stC = (lane & 7) * 8;

    const unsigned short* Abase = A + (size_t)(bm + wave * 32 + stR) * K + stC;
    const unsigned short* Bbase = Bt + (size_t)(bn + wave * 32 + stR) * K + stC;
    unsigned short* AsW = As + wave * 2048;
    unsigned short* BsW = Bs + wave * 2048;

    f32x4 acc[4][4] = {};
    const int fr = lane & 15;
    const int fko = (lane >> 4) * 8;

    for (int k0 = 0; k0 < K; k0 += 64) {
#pragma unroll
        for (int i = 0; i < 4; ++i) {
            gload_lds16(Abase + (size_t)i * 8 * K + k0, AsW + i * 512);
            gload_lds16(Bbase + (size_t)i * 8 * K + k0, BsW + i * 512);
        }
        __syncthreads();
        bf16x8 af[4][2], bfr[4][2];
#pragma unroll
        for (int m = 0; m < 4; ++m) {
            const unsigned short* ap = As + (wr * 64 + m * 16 + fr) * 64 + fko;
            af[m][0] = *(const bf16x8*)(ap);
            af[m][1] = *(const bf16x8*)(ap + 32);
        }
#pragma unroll
        for (int n = 0; n < 4; ++n) {
            const unsigned short* bp = Bs + (wc * 64 + n * 16 + fr) * 64 + fko;
            bfr[n][0] = *(const bf16x8*)(bp);
            bfr[n][1] = *(const bf16x8*)(bp + 32);
        }
#pragma unroll
        for (int m = 0; m < 4; ++m)
#pragma unroll
            for (int n = 0; n < 4; ++n) {
                acc[m][n] = __builtin_amdgcn_mfma_f32_16x16x32_bf16(af[m][0], bfr[n][0], acc[m][n], 0, 0, 0);
                acc[m][n] = __builtin_amdgcn_mfma_f32_16x16x32_bf16(af[m][1], bfr[n][1], acc[m][n], 0, 0, 0);
            }
        __syncthreads();
    }
    const int fq = lane >> 4;
#pragma unroll
    for (int n = 0; n < 4; ++n) {
        const int col = bn + wc * 64 + n * 16 + fr;
        const float bv = bias ? bias[col] : 0.f;
#pragma unroll
        for (int m = 0; m < 4; ++m) {
#pragma unroll
            for (int j = 0; j < 4; ++j) {
                const int row = bm + wr * 64 + m * 16 + fq * 4 + j;
                float v = acc[m][n][j] + bv;
                if (resid) v += resid[(size_t)row * N + col];
                if (C)  C[(size_t)row * N + col] = v;
                if (Cb) Cb[(size_t)row * N + col] = f2bf(v);
            }
        }
    }
}

// ---------------- MFMA attention: 32 q-rows/block, 2 waves, bf16 throughout -------------------
// grid 2048 = b(16) x h(8) x qt(16), 128 threads. Fragment recipe identical to gemm_bf16
// (proven): A lane lo16=row/slot=k8; B lane lo16=col (row of K^T / V^T); D col=lane&15,
// row=(lane>>4)*4+j. QK^T: B-frags from K rows staged [64][72]. PV: B-frags from V^T staged
// via register transpose. P (raw scores, then probs) in LDS bf16 (bf16-S proven r12).
__global__ __launch_bounds__(128)
void attn_mfma(const unsigned short* __restrict__ qkv, unsigned short* __restrict__ ctxb)
{
    __shared__ unsigned short P[32][520];     // 33.3 KB
    __shared__ unsigned short KV[64][72];     // 9.2 KB: K tile, then V^T tile
    __shared__ float invs[32];
    const int tid = threadIdx.x;
    const int wg = blockIdx.x;
    const int qt = wg & 15, h = (wg >> 4) & 7, b = wg >> 7;
    const int t0 = qt * 32;
    const int w = tid >> 6, lane = tid & 63;
    const int lo16 = lane & 15, hi4 = lane >> 4;

    // Q A-frags (kt = 0,1 over d=64 contraction)
    bf16x8 Aq0, Aq1;
    {
        const unsigned short* qrow =
            qkv + ((size_t)(b * 512 + t0 + w * 16 + lo16)) * 1536 + h * 64 + hi4 * 8;
        Aq0 = *(const bf16x8*)(qrow);
        Aq1 = *(const bf16x8*)(qrow + 32);
    }
    const int ss = tid >> 1, sh = tid & 1;    // staging: key/value row, d-half

    // ---- phase 1: S = Q K^T -> P (raw scores bf16)
    for (int st = 0; st < 8; ++st) {
        {
            const unsigned short* krow =
                qkv + ((size_t)(b * 512 + st * 64 + ss)) * 1536 + 512 + h * 64 + sh * 32;
            *(bf16x8*)&KV[ss][sh * 32]      = *(const bf16x8*)(krow);
            *(bf16x8*)&KV[ss][sh * 32 + 8]  = *(const bf16x8*)(krow + 8);
            *(bf16x8*)&KV[ss][sh * 32 + 16] = *(const bf16x8*)(krow + 16);
            *(bf16x8*)&KV[ss][sh * 32 + 24] = *(const bf16x8*)(krow + 24);
        }
        __syncthreads();
#pragma unroll
        for (int n = 0; n < 4; ++n) {
            const bf16x8 b0 = *(const bf16x8*)&KV[n * 16 + lo16][hi4 * 8];
            const bf16x8 b1 = *(const bf16x8*)&KV[n * 16 + lo16][32 + hi4 * 8];
            f32x4 acc = {0.f, 0.f, 0.f, 0.f};
            acc = __builtin_amdgcn_mfma_f32_16x16x32_bf16(Aq0, b0, acc, 0, 0, 0);
            acc = __builtin_amdgcn_mfma_f32_16x16x32_bf16(Aq1, b1, acc, 0, 0, 0);
#pragma unroll
            for (int j = 0; j < 4; ++j)
                P[w * 16 + hi4 * 4 + j][st * 64 + n * 16 + lo16] = f2bf(acc[j]);
        }
        __syncthreads();
    }
    // ---- phase 2: softmax rows (4 threads/row x 128 cols; scale 0.125 folded in)
    {
        const int r = tid >> 2, quad = tid & 3;
        const int c0 = quad * 128;
        float mx = -1e30f;
#pragma unroll
        for (int c8 = 0; c8 < 16; ++c8) {
            const bf16x8 sv = *(const bf16x8*)&P[r][c0 + c8 * 8];
#pragma unroll
            for (int e = 0; e < 8; ++e) mx = fmaxf(mx, bfbits2f((unsigned short)sv[e]));
        }
        mx = fmaxf(mx, __shfl_xor(mx, 1));
        mx = fmaxf(mx, __shfl_xor(mx, 2));
        mx *= 0.125f;
        float sum = 0.f;
#pragma unroll
        for (int c8 = 0; c8 < 16; ++c8) {
            const bf16x8 sv = *(const bf16x8*)&P[r][c0 + c8 * 8];
            us4 o1, o2;
#pragma unroll
            for (int e = 0; e < 8; ++e) {
                const float p = __expf(bfbits2f((unsigned short)sv[e]) * 0.125f - mx);
                sum += p;
                if (e < 4) o1[e] = f2bf(p); else o2[e - 4] = f2bf(p);
            }
            *(us4*)&P[r][c0 + c8 * 8] = o1;
            *(us4*)&P[r][c0 + c8 * 8 + 4] = o2;
        }
        sum += __shfl_xor(sum, 1);
        sum += __shfl_xor(sum, 2);
        if (quad == 0) invs[r] = 1.0f / sum;
    }
    __syncthreads();
    // ---- phase 3: O = P @ V (V^T staged via register transpose)
    f32x4 oac[4] = {};
    for (int st = 0; st < 8; ++st) {
        {
            const unsigned short* vrow =
                qkv + ((size_t)(b * 512 + st * 64 + ss)) * 1536 + 1024 + h * 64 + sh * 32;
            const bf16x8 v0 = *(const bf16x8*)(vrow);
            const bf16x8 v1 = *(const bf16x8*)(vrow + 8);
            const bf16x8 v2 = *(const bf16x8*)(vrow + 16);
            const bf16x8 v3 = *(const bf16x8*)(vrow + 24);
#pragma unroll
            for (int e = 0; e < 8; ++e) {
                KV[sh * 32 + e][ss]      = (unsigned short)v0[e];
                KV[sh * 32 + 8 + e][ss]  = (unsigned short)v1[e];
                KV[sh * 32 + 16 + e][ss] = (unsigned short)v2[e];
                KV[sh * 32 + 24 + e][ss] = (unsigned short)v3[e];
            }
        }
        __syncthreads();
        const bf16x8 pa0 = *(const bf16x8*)&P[w * 16 + lo16][st * 64 + hi4 * 8];
        const bf16x8 pa1 = *(const bf16x8*)&P[w * 16 + lo16][st * 64 + 32 + hi4 * 8];
#pragma unroll
        for (int n = 0; n < 4; ++n) {
            const bf16x8 b0 = *(const bf16x8*)&KV[n * 16 + lo16][hi4 * 8];
            const bf16x8 b1 = *(const bf16x8*)&KV[n * 16 + lo16][32 + hi4 * 8];
            oac[n] = __builtin_amdgcn_mfma_f32_16x16x32_bf16(pa0, b0, oac[n], 0, 0, 0);
            oac[n] = __builtin_amdgcn_mfma_f32_16x16x32_bf16(pa1, b1, oac[n], 0, 0, 0);
        }
        __syncthreads();
    }
    // ---- epilogue: scale by 1/sum, write ctx bf16
#pragma unroll
    for (int n = 0; n < 4; ++n) {
#pragma unroll
        for (int j = 0; j < 4; ++j) {
            const int q = w * 16 + hi4 * 4 + j;
            ctxb[((size_t)(b * 512 + t0 + q)) * 512 + h * 64 + n * 16 + lo16] =
                f2bf(oac[n][j] * invs[q]);
        }
    }
}

// ---------------- layernorm (rows of 512), optional bf16 side output --------------------------
__global__ __launch_bounds__(256)
void ln_f32(const float* __restrict__ in, float* __restrict__ out,
            const float* __restrict__ g, const float* __restrict__ bb,
            unsigned short* __restrict__ outb)
{
    const int lane = threadIdx.x & 63;
    const int row = blockIdx.x * 4 + (threadIdx.x >> 6);
    const float* x = in + (size_t)row * 512;
    const float4 a = *(const float4*)(x + lane * 4);
    const float4 c = *(const float4*)(x + 256 + lane * 4);
    float s = a.x + a.y + a.z + a.w + c.x + c.y + c.z + c.w;
#pragma unroll
    for (int off = 1; off < 64; off <<= 1) s += __shfl_xor(s, off);
    const float mu = s * (1.0f / 512.0f);
    float vs = 0.f;
    vs += (a.x - mu) * (a.x - mu) + (a.y - mu) * (a.y - mu);
    vs += (a.z - mu) * (a.z - mu) + (a.w - mu) * (a.w - mu);
    vs += (c.x - mu) * (c.x - mu) + (c.y - mu) * (c.y - mu);
    vs += (c.z - mu) * (c.z - mu) + (c.w - mu) * (c.w - mu);
#pragma unroll
    for (int off = 1; off < 64; off <<= 1) vs += __shfl_xor(vs, off);
    const float rstd = rsqrtf(vs * (1.0f / 512.0f) + 1e-3f);
    const float4 g1 = *(const float4*)(g + lane * 4);
    const float4 g2 = *(const float4*)(g + 256 + lane * 4);
    const float4 b1 = *(const float4*)(bb + lane * 4);
    const float4 b2 = *(const float4*)(bb + 256 + lane * 4);
    float* y = out + (size_t)row * 512;
    const float4 o1 = {(a.x - mu) * rstd * g1.x + b1.x, (a.y - mu) * rstd * g1.y + b1.y,
                       (a.z - mu) * rstd * g1.z + b1.z, (a.w - mu) * rstd * g1.w + b1.w};
    const float4 o2 = {(c.x - mu) * rstd * g2.x + b2.x, (c.y - mu) * rstd * g2.y + b2.y,
                       (c.z - mu) * rstd * g2.z + b2.z, (c.w - mu) * rstd * g2.w + b2.w};
    *(float4*)(y + lane * 4) = o1;
    *(float4*)(y + 256 + lane * 4) = o2;
    if (outb) {
        unsigned short* yb = outb + (size_t)row * 512;
        const us4 p1 = {f2bf(o1.x), f2bf(o1.y), f2bf(o1.z), f2bf(o1.w)};
        const us4 p2 = {f2bf(o2.x), f2bf(o2.y), f2bf(o2.z), f2bf(o2.w)};
        *(us4*)(yb + lane * 4) = p1;
        *(us4*)(yb + 256 + lane * 4) = p2;
    }
}

// ---------------- persistent GRU, XCD-pinned (r10 exact: proven 1666 us) ----------------------
__global__ __launch_bounds__(256, 1)
void gru_persist(const float* __restrict__ rk,
                 const unsigned short* __restrict__ xpb,
                 const float* __restrict__ rb,
                 unsigned short* __restrict__ hbuf,
                 unsigned short* __restrict__ goutb,
                 unsigned int* __restrict__ bar,
                 unsigned int* __restrict__ ctl)
{
    __shared__ int sh_part, sh_memb;
    const int tid = threadIdx.x;

    if (tid == 0) {
        unsigned int xcc;
        asm("s_getreg_b32 %0, hwreg(HW_REG_XCC_ID)" : "=s"(xcc));
        xcc &= 7u;
        const unsigned int rank =
            __hip_atomic_fetch_add(&ctl[xcc], 1u, __ATOMIC_RELAXED, __HIP_MEMORY_SCOPE_AGENT);
        __hip_atomic_fetch_add(&ctl[8], 1u, __ATOMIC_ACQ_REL, __HIP_MEMORY_SCOPE_AGENT);
        unsigned int spins = 0;
        while (__hip_atomic_load(&ctl[8], __ATOMIC_ACQUIRE, __HIP_MEMORY_SCOPE_AGENT)
               < (unsigned)GRID_WGS) {
            __builtin_amdgcn_s_sleep(1);
            if (++spins > (1u << 20)) break;
        }
        unsigned int cnt[8];
#pragma unroll
        for (int i = 0; i < 8; ++i)
            cnt[i] = __hip_atomic_load(&ctl[i], __ATOMIC_ACQUIRE, __HIP_MEMORY_SCOPE_AGENT);
        int best = 0;
#pragma unroll
        for (int i = 1; i < 8; ++i)
            if (cnt[i] > cnt[best]) best = i;
        sh_part = (xcc == (unsigned)best && rank < 8u) ? 1 : 0;
        sh_memb = (int)rank;
    }
    __syncthreads();
    if (!sh_part) return;
    const int member = sh_memb;

    const int wv = tid >> 6, l = tid & 63;
    const int wgi = member * 4 + wv;
    const int lo16 = l & 15;
    const int hi4 = l >> 4;
    const int gc = wgi * 16 + lo16;

    bf16x8 B[3][16];
#pragma unroll
    for (int g = 0; g < 3; ++g)
#pragma unroll
        for (int kt = 0; kt < 16; ++kt) {
            bf16x8 bv;
#pragma unroll
            for (int j = 0; j < 8; ++j) {
                const int k = kt * 32 + hi4 * 8 + j;
                bv[j] = (short)f2bf(rk[(size_t)k * 1536 + g * 512 + gc]);
            }
            B[g][kt] = bv;
        }
    const float rbz = rb[gc], rbr = rb[512 + gc], rbh = rb[1024 + gc];
    float hst[4] = {0.f, 0.f, 0.f, 0.f};

    float xz[4], xr[4], xh[4];
#pragma unroll
    for (int j = 0; j < 4; ++j) {
        const unsigned short* xrow = xpb + ((size_t)((hi4 * 4 + j) * 512)) * 1536 + gc;
        xz[j] = bfbits2f(xrow[0]); xr[j] = bfbits2f(xrow[512]); xh[j] = bfbits2f(xrow[1024]);
    }
    unsigned int hnb[4] = {0u, 0u, 0u, 0u};

    const unsigned short* ab0 = hbuf + lo16 * 512 + hi4 * 8;
    const unsigned short* ab1 = ab0 + 16 * 512;

    for (int t = 0; t < 512; ++t) {
        const unsigned short* abase = (t & 1) ? ab1 : ab0;
        unsigned short* hw = hbuf + (size_t)((t + 1) & 1) * (16 * 512);
        bf16x8 A[16];
        asm volatile(
            "global_load_dwordx4 %0,  %16, off sc0\n\t"
            "global_load_dwordx4 %1,  %16, off offset:64 sc0\n\t"
            "global_load_dwordx4 %2,  %16, off offset:128 sc0\n\t"
            "global_load_dwordx4 %3,  %16, off offset:192 sc0\n\t"
            "global_load_dwordx4 %4,  %16, off offset:256 sc0\n\t"
            "global_load_dwordx4 %5,  %16, off offset:320 sc0\n\t"
            "global_load_dwordx4 %6,  %16, off offset:384 sc0\n\t"
            "global_load_dwordx4 %7,  %16, off offset:448 sc0\n\t"
            "global_load_dwordx4 %8,  %16, off offset:512 sc0\n\t"
            "global_load_dwordx4 %9,  %16, off offset:576 sc0\n\t"
            "global_load_dwordx4 %10, %16, off offset:640 sc0\n\t"
            "global_load_dwordx4 %11, %16, off offset:704 sc0\n\t"
            "global_load_dwordx4 %12, %16, off offset:768 sc0\n\t"
            "global_load_dwordx4 %13, %16, off offset:832 sc0\n\t"
            "global_load_dwordx4 %14, %16, off offset:896 sc0\n\t"
            "global_load_dwordx4 %15, %16, off offset:960 sc0"
            : "=&v"(A[0]), "=&v"(A[1]), "=&v"(A[2]), "=&v"(A[3]),
              "=&v"(A[4]), "=&v"(A[5]), "=&v"(A[6]), "=&v"(A[7]),
              "=&v"(A[8]), "=&v"(A[9]), "=&v"(A[10]), "=&v"(A[11]),
              "=&v"(A[12]), "=&v"(A[13]), "=&v"(A[14]), "=&v"(A[15])
            : "v"(abase) : "memory");
        unsigned int xnz[4], xnr[4], xnh[4];
        {
            const unsigned short* x0 = xpb + ((size_t)((hi4 * 4 + 0) * 512 + t + 1)) * 1536 + gc;
            const unsigned short* x1 = xpb + ((size_t)((hi4 * 4 + 1) * 512 + t + 1)) * 1536 + gc;
            const unsigned short* x2 = xpb + ((size_t)((hi4 * 4 + 2) * 512 + t + 1)) * 1536 + gc;
            const unsigned short* x3 = xpb + ((size_t)((hi4 * 4 + 3) * 512 + t + 1)) * 1536 + gc;
            asm volatile(
                "global_load_ushort %0,  %12, off\n\t"
                "global_load_ushort %1,  %12, off offset:1024\n\t"
                "global_load_ushort %2,  %12, off offset:2048\n\t"
                "global_load_ushort %3,  %13, off\n\t"
                "global_load_ushort %4,  %13, off offset:1024\n\t"
                "global_load_ushort %5,  %13, off offset:2048\n\t"
                "global_load_ushort %6,  %14, off\n\t"
                "global_load_ushort %7,  %14, off offset:1024\n\t"
                "global_load_ushort %8,  %14, off offset:2048\n\t"
                "global_load_ushort %9,  %15, off\n\t"
                "global_load_ushort %10, %15, off offset:1024\n\t"
                "global_load_ushort %11, %15, off offset:2048"
                : "=&v"(xnz[0]), "=&v"(xnr[0]), "=&v"(xnh[0]),
                  "=&v"(xnz[1]), "=&v"(xnr[1]), "=&v"(xnh[1]),
                  "=&v"(xnz[2]), "=&v"(xnr[2]), "=&v"(xnh[2]),
                  "=&v"(xnz[3]), "=&v"(xnr[3]), "=&v"(xnh[3])
                : "v"(x0), "v"(x1), "v"(x2), "v"(x3) : "memory");
        }
        {
            const int grow = t ? t - 1 : 0;
            unsigned short* g0 = goutb + ((size_t)((hi4 * 4 + 0) * 512 + grow)) * 512 + gc;
            unsigned short* g1 = goutb + ((size_t)((hi4 * 4 + 1) * 512 + grow)) * 512 + gc;
            unsigned short* g2 = goutb + ((size_t)((hi4 * 4 + 2) * 512 + grow)) * 512 + gc;
            unsigned short* g3 = goutb + ((size_t)((hi4 * 4 + 3) * 512 + grow)) * 512 + gc;
            asm volatile(
                "global_store_short %0, %4, off\n\t"
                "global_store_short %1, %5, off\n\t"
                "global_store_short %2, %6, off\n\t"
                "global_store_short %3, %7, off"
                :: "v"(g0), "v"(g1), "v"(g2), "v"(g3),
                   "v"(hnb[0]), "v"(hnb[1]), "v"(hnb[2]), "v"(hnb[3]) : "memory");
        }
        asm volatile("s_waitcnt vmcnt(16)" ::: "memory");
        __builtin_amdgcn_sched_barrier(0);

        f32x4 accz = {0.f, 0.f, 0.f, 0.f};
        f32x4 accr = {0.f, 0.f, 0.f, 0.f};
        f32x4 acch = {0.f, 0.f, 0.f, 0.f};
#pragma unroll
        for (int kt = 0; kt < 16; ++kt) {
            accz = __builtin_amdgcn_mfma_f32_16x16x32_bf16(A[kt], B[0][kt], accz, 0, 0, 0);
            accr = __builtin_amdgcn_mfma_f32_16x16x32_bf16(A[kt], B[1][kt], accr, 0, 0, 0);
            acch = __builtin_amdgcn_mfma_f32_16x16x32_bf16(A[kt], B[2][kt], acch, 0, 0, 0);
        }
#pragma unroll
        for (int j = 0; j < 4; ++j) {
            const int b = hi4 * 4 + j;
            const float z = sigmoidf_(xz[j] + accz[j] + rbz);
            const float r = sigmoidf_(xr[j] + accr[j] + rbr);
            const float hh = fmaxf(xh[j] + r * (acch[j] + rbh), 0.f);
            const float hnew = z * hst[j] + (1.f - z) * hh;
            hst[j] = hnew;
            const unsigned short hb = f2bf(hnew);
            hnb[j] = (unsigned int)hb;
            hw[b * 512 + gc] = hb;
        }
        asm volatile("s_waitcnt vmcnt(0)" ::: "memory");
        __builtin_amdgcn_sched_barrier(0);
#pragma unroll
        for (int j = 0; j < 4; ++j) {
            xz[j] = bfbits2f(xnz[j]); xr[j] = bfbits2f(xnr[j]); xh[j] = bfbits2f(xnh[j]);
        }
        if (t < 511) {
            __syncthreads();
            if (tid == 0) {
                __hip_atomic_fetch_add(bar, 1u, __ATOMIC_RELAXED, __HIP_MEMORY_SCOPE_AGENT);
                const unsigned int target = 8u * (unsigned int)(t + 1);
                unsigned int it = 0;
                while (__hip_atomic_load(bar, __ATOMIC_RELAXED, __HIP_MEMORY_SCOPE_AGENT)
                       < target) {
                    if (++it > (1u << 14)) break;
                }
                if (it > (1u << 14)) {
                    unsigned int cur = 0, it2 = 0;
                    do {
                        asm volatile("global_atomic_add %0, %1, %2, off sc0\n\t"
                                     "s_waitcnt vmcnt(0)"
                                     : "=v"(cur) : "v"(bar), "v"(0u) : "memory");
                        if (++it2 > (1u << 15)) break;
                    } while (cur < target);
                }
            }
            __syncthreads();
        }
    }
#pragma unroll
    for (int j = 0; j < 4; ++j)
        goutb[((size_t)((hi4 * 4 + j) * 512 + 511)) * 512 + gc] = (unsigned short)hnb[j];
}

extern "C" void kernel_launch(void* const* d_in, const int* in_sizes, int n_in,
                              void* d_out, int out_size, void* d_ws, size_t ws_size,
                              hipStream_t stream)
{
    const float* x     = (const float*)d_in[0];
    const float* Wq    = (const float*)d_in[1];
    const float* bq    = (const float*)d_in[2];
    const float* Wk    = (const float*)d_in[3];
    const float* bk    = (const float*)d_in[4];
    const float* Wv    = (const float*)d_in[5];
    const float* bv    = (const float*)d_in[6];
    const float* Wo    = (const float*)d_in[7];
    const float* bo    = (const float*)d_in[8];
    const float* ln1g  = (const float*)d_in[9];
    const float* ln1b  = (const float*)d_in[10];
    const float* gruk  = (const float*)d_in[11];
    const float* grurk = (const float*)d_in[12];
    const float* grub  = (const float*)d_in[13];
    const float* Wd    = (const float*)d_in[14];
    const float* bd    = (const float*)d_in[15];
    const float* ln2g  = (const float*)d_in[16];
    const float* ln2b  = (const float*)d_in[17];
    float* out = (float*)d_out;

    char* base = (char*)d_ws;
    const size_t MB = 1024 * 1024;
    unsigned short* qkvb = (unsigned short*)base;              // 24 MB bf16 qkv -> xpb reuse
    unsigned short* xpb  = (unsigned short*)base;
    float*          dout = (float*)(base + 24 * MB);
    float*          R4   = (float*)(base + 48 * MB);           // x1
    unsigned short* S1   = (unsigned short*)(base + 64 * MB);  // xb->ctxb->x1b->goutb
    unsigned short* WT   = (unsigned short*)(base + 72 * MB);
    unsigned short* wqkvT = WT;
    unsigned short* woT  = WT + 768 * 1024;
    unsigned short* gkT  = WT + 1024 * 1024;
    unsigned short* wdT  = WT + 1792 * 1024;
    unsigned short* hbuf = (unsigned short*)(base + 76 * MB);
    char*           Z    = base + 76 * MB + 64 * 1024;
    unsigned int*   ctl  = (unsigned int*)(Z);
    unsigned int*   bar  = (unsigned int*)(Z + 256);
    float*          bqkv = (float*)(base + 77 * MB);

    const dim3 blk(256);
    const dim3 g512(8192 / 128, 512 / 128);
    const dim3 g1536(8192 / 128, 1536 / 128);

    prep<<<dim3(6152), blk, 0, stream>>>(x, S1, bq, bk, bv, bqkv,
                                         Wq, Wk, Wv, Wo, gruk, Wd,
                                         wqkvT, woT, gkT, wdT,
                                         (unsigned int*)hbuf, (unsigned int*)Z);
    gemm_bf16<<<g1536, blk, 0, stream>>>(S1, wqkvT, bqkv, nullptr, nullptr, qkvb, 8192, 1536, 512);
    attn_mfma<<<dim3(2048), dim3(128), 0, stream>>>(qkvb, S1);
    gemm_bf16<<<g512, blk, 0, stream>>>(S1, woT, bo, x, R4, nullptr, 8192, 512, 512);
    ln_f32<<<dim3(2048), blk, 0, stream>>>(R4, R4, ln1g, ln1b, S1);
    gemm_bf16<<<g1536, blk, 0, stream>>>(S1, gkT, grub, nullptr, nullptr, xpb, 8192, 1536, 512);
    gru_persist<<<dim3(GRID_WGS), blk, 0, stream>>>(grurk, xpb, grub + 1536, hbuf, S1, bar, ctl);
    gemm_bf16<<<g512, blk, 0, stream>>>(S1, wdT, bd, R4, dout, nullptr, 8192, 512, 512);
    ln_f32<<<dim3(2048), blk, 0, stream>>>(dout, out, ln2g, ln2b, nullptr);
}